// Round 6
// baseline (1746.220 us; speedup 1.0000x reference)
//
#include <hip/hip_runtime.h>

#define NN 100000
#define NPAD 100096   // 782 * 128, padded row count for guard-free GEMM
#define NE 600000
#define EMB 128

typedef unsigned short u16;
typedef unsigned int u32;
typedef unsigned long long u64;
typedef short short8 __attribute__((ext_vector_type(8)));
typedef float f32x4 __attribute__((ext_vector_type(4)));

__device__ __forceinline__ float4 ld4(const float* p) { return *(const float4*)p; }
__device__ __forceinline__ u16 f2bf(float x) {  // RTNE f32 -> bf16
  u32 u = __float_as_uint(x);
  u += 0x7FFFu + ((u >> 16) & 1u);
  return (u16)(u >> 16);
}
__device__ __forceinline__ float bf2f(u16 h) { return __uint_as_float(((u32)h) << 16); }

// ---------------- node embedding init: hf(f32) + hb(bf16) = emb1[x0] + emb2[x1] ----------------
__global__ __launch_bounds__(256) void node_init_kernel(
    const int* __restrict__ x, const float* __restrict__ emb1,
    const float* __restrict__ emb2, float* __restrict__ hf, u16* __restrict__ hb) {
  int tid = blockIdx.x * blockDim.x + threadIdx.x;
  int n = tid >> 4;
  if (n >= NN) return;
  int kc = tid & 15;
  int x0 = min(max(x[2 * n], 0), 118);
  int x1 = min(max(x[2 * n + 1], 0), 2);  // x[:,1] sampled 0..118 -> clip to NUM_CHIR-1
  const float* p1 = emb1 + (size_t)x0 * EMB + kc * 8;
  const float* p2 = emb2 + (size_t)x1 * EMB + kc * 8;
  float v[8];
#pragma unroll
  for (int j = 0; j < 8; ++j) v[j] = p1[j] + p2[j];
  float* df = hf + (size_t)n * EMB + kc * 8;
  *(float4*)df = make_float4(v[0], v[1], v[2], v[3]);
  *(float4*)(df + 4) = make_float4(v[4], v[5], v[6], v[7]);
  u16 o[8];
#pragma unroll
  for (int j = 0; j < 8; ++j) o[j] = f2bf(v[j]);
  *(ulonglong2*)(hb + (size_t)n * EMB + kc * 8) = *(ulonglong2*)o;
}

// ---------------- CSR build ----------------
__global__ __launch_bounds__(256) void hist_kernel(const int* __restrict__ ei,
                                                   int* __restrict__ deg) {
  int e = blockIdx.x * blockDim.x + threadIdx.x;
  if (e >= NE) return;
  atomicAdd(&deg[ei[NE + e]], 1);
}

__global__ __launch_bounds__(256) void scan1_kernel(const int* __restrict__ deg,
                                                    int* __restrict__ off,
                                                    int* __restrict__ bsum) {
  __shared__ int s[256];
  int t = threadIdx.x;
  int base = blockIdx.x * 1024 + t * 4;
  int v[4];
#pragma unroll
  for (int j = 0; j < 4; ++j) {
    int idx = base + j;
    v[j] = (idx < NN) ? deg[idx] : 0;
  }
  int tsum = v[0] + v[1] + v[2] + v[3];
  s[t] = tsum;
  __syncthreads();
  for (int d = 1; d < 256; d <<= 1) {
    int add = (t >= d) ? s[t - d] : 0;
    __syncthreads();
    s[t] += add;
    __syncthreads();
  }
  int run = s[t] - tsum;
#pragma unroll
  for (int j = 0; j < 4; ++j) {
    int idx = base + j;
    if (idx < NN) off[idx] = run;
    run += v[j];
  }
  if (t == 255) bsum[blockIdx.x] = s[255];
}

__global__ void scan2_kernel(int* __restrict__ bsum, int* __restrict__ off, int nb) {
  if (threadIdx.x == 0) {
    int run = 0;
    for (int b = 0; b < nb; ++b) {
      int v = bsum[b];
      bsum[b] = run;
      run += v;
    }
    off[NN] = run;
  }
}

__global__ __launch_bounds__(256) void scan3_kernel(int* __restrict__ off,
                                                    const int* __restrict__ bsum) {
  int idx = blockIdx.x * blockDim.x + threadIdx.x;
  if (idx < NN) off[idx] += bsum[idx >> 10];
}

__global__ __launch_bounds__(256) void scatter_kernel(
    const int* __restrict__ ei, const int* __restrict__ ea,
    const int* __restrict__ off, int* __restrict__ cnt, int* __restrict__ csr) {
  int e = blockIdx.x * blockDim.x + threadIdx.x;
  if (e >= NE) return;
  int d = ei[NE + e];
  int s = ei[e];
  int a0 = min(max(ea[2 * e], 0), 4);
  int a1 = min(max(ea[2 * e + 1], 0), 2);
  int code = a0 * 3 + a1;  // [0,14]
  int r = atomicAdd(&cnt[d], 1);
  csr[off[d] + r] = s | (code << 20);
}

// combos[l][code][f] = ee1[l][code/3][f] + ee2[l][code%3][f]
__global__ __launch_bounds__(256) void combo_kernel(const float* __restrict__ ee1,
                                                    const float* __restrict__ ee2,
                                                    float* __restrict__ combos) {
  int idx = blockIdx.x * blockDim.x + threadIdx.x;
  if (idx >= 5 * 15 * 128) return;
  int l = idx / (15 * 128);
  int rem = idx % (15 * 128);
  int code = rem / 128;
  int f = rem % 128;
  combos[idx] = ee1[(l * 5 + code / 3) * 128 + f] + ee2[(l * 3 + code % 3) * 128 + f];
}

// ---------------- weight prep: frag-ordered split-bf16 (hi+lo) copies of W1/W2 ----------------
// Layout is lane-symmetric: serves as B-operand (n=lane&15) or A-operand (m=lane&15).
__global__ __launch_bounds__(256) void prep_w_kernel(
    const float* __restrict__ W1g, const float* __restrict__ W2g,
    u16* __restrict__ W1h, u16* __restrict__ W1l,
    u16* __restrict__ W2h, u16* __restrict__ W2l) {
  int idx = blockIdx.x * blockDim.x + threadIdx.x;
  if (idx >= 40960) return;
  u16 oh[8], ol[8];
  if (idx < 20480) {
    int lane = idx & 63;
    int r = idx >> 6;             // l*64 + c*16 + kt*4 + nt
    int nt = r & 3, kt = (r >> 2) & 3, c = (r >> 4) & 3, l = r >> 6;
    int n = c * 64 + nt * 16 + (lane & 15);
    int kb = kt * 32 + (lane >> 4) * 8;
#pragma unroll
    for (int j = 0; j < 8; ++j) {
      float w = W1g[((size_t)l * 128 + kb + j) * 256 + n];
      oh[j] = f2bf(w);
      ol[j] = f2bf(w - bf2f(oh[j]));
    }
    *(ulonglong2*)(W1h + (size_t)idx * 8) = *(ulonglong2*)oh;
    *(ulonglong2*)(W1l + (size_t)idx * 8) = *(ulonglong2*)ol;
  } else {
    int i2 = idx - 20480;
    int lane = i2 & 63;
    int r = i2 >> 6;              // l*64 + c*16 + ktl*8 + nt
    int nt = r & 7, ktl = (r >> 3) & 1, c = (r >> 4) & 3, l = r >> 6;
    int n = nt * 16 + (lane & 15);
    int kb = c * 64 + ktl * 32 + (lane >> 4) * 8;
#pragma unroll
    for (int j = 0; j < 8; ++j) {
      float w = W2g[((size_t)l * 256 + kb + j) * 128 + n];
      oh[j] = f2bf(w);
      ol[j] = f2bf(w - bf2f(oh[j]));
    }
    *(ulonglong2*)(W2h + (size_t)i2 * 8) = *(ulonglong2*)oh;
    *(ulonglong2*)(W2l + (size_t)i2 * 8) = *(ulonglong2*)ol;
  }
}

// ---------------- agg: A = (1+eps)*hf + relu(hf+c0) + sum relu(hb[src]+c), split hi/lo ----------------
__global__ __launch_bounds__(256) void agg_kernel(
    const float* __restrict__ hf, const u16* __restrict__ hb,
    const int* __restrict__ off, const int* __restrict__ csr,
    const float* __restrict__ cb, const float* __restrict__ epsp,
    u16* __restrict__ Ah, u16* __restrict__ Al) {
  int tid = blockIdx.x * blockDim.x + threadIdx.x;
  int g = tid >> 4;
  int kc = tid & 15;
  float av[8] = {0.f, 0.f, 0.f, 0.f, 0.f, 0.f, 0.f, 0.f};
  if (g < NN) {
    const float eps1 = 1.0f + *epsp;
    const float* hp = hf + (size_t)g * EMB + kc * 8;
    float4 va = ld4(hp), vb = ld4(hp + 4);
    float hv[8] = {va.x, va.y, va.z, va.w, vb.x, vb.y, vb.z, vb.w};
    float4 ca = ld4(cb + kc * 8), cbv = ld4(cb + kc * 8 + 4);
    float cs[8] = {ca.x, ca.y, ca.z, ca.w, cbv.x, cbv.y, cbv.z, cbv.w};
#pragma unroll
    for (int j = 0; j < 8; ++j) av[j] = eps1 * hv[j] + fmaxf(hv[j] + cs[j], 0.f);
    int s0 = off[g], s1 = off[g + 1];
    int e = s0;
    for (; e + 1 < s1; e += 2) {  // unroll x2: two independent gather chains in flight
      int p0 = csr[e], p1 = csr[e + 1];
      ulonglong2 r0 = *(const ulonglong2*)(hb + (size_t)(p0 & 0xFFFFF) * EMB + kc * 8);
      ulonglong2 r1 = *(const ulonglong2*)(hb + (size_t)(p1 & 0xFFFFF) * EMB + kc * 8);
      const float* c0p = cb + (size_t)(p0 >> 20) * EMB + kc * 8;
      const float* c1p = cb + (size_t)(p1 >> 20) * EMB + kc * 8;
      float4 c0a = ld4(c0p), c0b = ld4(c0p + 4);
      float4 c1a = ld4(c1p), c1b = ld4(c1p + 4);
      float cc0[8] = {c0a.x, c0a.y, c0a.z, c0a.w, c0b.x, c0b.y, c0b.z, c0b.w};
      float cc1[8] = {c1a.x, c1a.y, c1a.z, c1a.w, c1b.x, c1b.y, c1b.z, c1b.w};
      u16* s0p = (u16*)&r0;
      u16* s1p = (u16*)&r1;
#pragma unroll
      for (int j = 0; j < 8; ++j) {
        av[j] += fmaxf(bf2f(s0p[j]) + cc0[j], 0.f);
        av[j] += fmaxf(bf2f(s1p[j]) + cc1[j], 0.f);
      }
    }
    if (e < s1) {
      int p0 = csr[e];
      ulonglong2 r0 = *(const ulonglong2*)(hb + (size_t)(p0 & 0xFFFFF) * EMB + kc * 8);
      const float* c0p = cb + (size_t)(p0 >> 20) * EMB + kc * 8;
      float4 c0a = ld4(c0p), c0b = ld4(c0p + 4);
      float cc0[8] = {c0a.x, c0a.y, c0a.z, c0a.w, c0b.x, c0b.y, c0b.z, c0b.w};
      u16* s0p = (u16*)&r0;
#pragma unroll
      for (int j = 0; j < 8; ++j) av[j] += fmaxf(bf2f(s0p[j]) + cc0[j], 0.f);
    }
  }
  u16 oh[8], ol[8];
#pragma unroll
  for (int j = 0; j < 8; ++j) {
    oh[j] = f2bf(av[j]);
    ol[j] = f2bf(av[j] - bf2f(oh[j]));
  }
  *(ulonglong2*)(Ah + (size_t)g * EMB + kc * 8) = *(ulonglong2*)oh;  // zeros for pad rows
  *(ulonglong2*)(Al + (size_t)g * EMB + kc * 8) = *(ulonglong2*)ol;
}

// ---------------- mlp: TRANSPOSED split-bf16 GEMMs; hpre + BN partials ----------------
// D[m=col][n=node]: W frags are the A-operand, node-row frags the B-operand.
// Stage-1 output (lane&15=node, row=4 consecutive hmid cols) -> vectorized b64 LDS
// writes; stage-2 B-frags are b128 LDS reads; final store is float4.
#define HSTRIDE 72  // u16 per node row in LDS (64 cols + 8 pad: bank-balanced)
__global__ __launch_bounds__(256) void mlp_kernel(
    const u16* __restrict__ Ah, const u16* __restrict__ Al,
    const u16* __restrict__ W1h, const u16* __restrict__ W1l,
    const u16* __restrict__ W2h, const u16* __restrict__ W2l,
    const float* __restrict__ b1g, const float* __restrict__ b2g,
    float* __restrict__ hpre, float* __restrict__ sums) {
  __shared__ __align__(16) u16 Hsh[128 * HSTRIDE];  // hmid chunk hi, [node][col]
  __shared__ __align__(16) u16 Hsl[128 * HSTRIDE];  // hmid chunk lo

  const int t = threadIdx.x;
  const int m0 = blockIdx.x * 128;
  const int w = t >> 6;
  const int lane = t & 63;
  const int quad = lane >> 4, l15 = lane & 15;
  const int wr = w >> 1, wc = w & 1;

  f32x4 oacc[4][4];
#pragma unroll
  for (int a = 0; a < 4; ++a)
#pragma unroll
    for (int b = 0; b < 4; ++b) oacc[a][b] = (f32x4){0.f, 0.f, 0.f, 0.f};

  for (int c = 0; c < 4; ++c) {
    // ---- stage 1 (transposed): hmidT[col][node] for chunk cols c*64..c*64+63 ----
    // wave w: node tiles {2w,2w+1}, all 4 col tiles.
    f32x4 hacc[2][4];
#pragma unroll
    for (int a = 0; a < 2; ++a)
#pragma unroll
      for (int b = 0; b < 4; ++b) hacc[a][b] = (f32x4){0.f, 0.f, 0.f, 0.f};
#pragma unroll
    for (int kt = 0; kt < 4; ++kt) {
      short8 ah[2], al[2];
#pragma unroll
      for (int mi = 0; mi < 2; ++mi) {  // A-row frags reloaded per chunk (L1-hot)
        size_t base = (size_t)(m0 + (2 * w + mi) * 16 + l15) * EMB + kt * 32 + quad * 8;
        ah[mi] = *(const short8*)(Ah + base);
        al[mi] = *(const short8*)(Al + base);
      }
#pragma unroll
      for (int colt = 0; colt < 4; ++colt) {
        size_t wb = (((size_t)(c * 4 + kt) * 4 + colt) * 64 + lane) * 8;
        short8 bh = *(const short8*)(W1h + wb);  // A-operand (m = hmid col)
        short8 bl = *(const short8*)(W1l + wb);
#pragma unroll
        for (int mi = 0; mi < 2; ++mi) {
          hacc[mi][colt] = __builtin_amdgcn_mfma_f32_16x16x32_bf16(bh, ah[mi], hacc[mi][colt], 0, 0, 0);
          hacc[mi][colt] = __builtin_amdgcn_mfma_f32_16x16x32_bf16(bh, al[mi], hacc[mi][colt], 0, 0, 0);
          hacc[mi][colt] = __builtin_amdgcn_mfma_f32_16x16x32_bf16(bl, ah[mi], hacc[mi][colt], 0, 0, 0);
        }
      }
    }
    __syncthreads();  // prev chunk's stage-2 reads of Hs are complete
    // epilogue: +b1, relu, split hi/lo, b64 writes of 4 consecutive cols
#pragma unroll
    for (int colt = 0; colt < 4; ++colt) {
      float4 b1v = ld4(b1g + c * 64 + colt * 16 + quad * 4);
      float bb[4] = {b1v.x, b1v.y, b1v.z, b1v.w};
#pragma unroll
      for (int mi = 0; mi < 2; ++mi) {
        int nodeloc = (2 * w + mi) * 16 + l15;
        u64 ph = 0, pl = 0;
#pragma unroll
        for (int reg = 0; reg < 4; ++reg) {
          float v = fmaxf(hacc[mi][colt][reg] + bb[reg], 0.f);
          u16 hi = f2bf(v);
          u16 lo = f2bf(v - bf2f(hi));
          ph |= ((u64)hi) << (16 * reg);
          pl |= ((u64)lo) << (16 * reg);
        }
        int ofs = nodeloc * HSTRIDE + colt * 16 + quad * 4;
        *(u64*)&Hsh[ofs] = ph;
        *(u64*)&Hsl[ofs] = pl;
      }
    }
    __syncthreads();

    // ---- stage 2 (transposed): outT += W2T[c-chunk] . hmidT; wave (wr,wc) ----
#pragma unroll
    for (int ktl = 0; ktl < 2; ++ktl) {
      short8 a2h[4], a2l[4];
#pragma unroll
      for (int mi = 0; mi < 4; ++mi) {  // B-operand: lane&15 = node, b128 reads
        int ofs = ((4 * wr + mi) * 16 + l15) * HSTRIDE + ktl * 32 + quad * 8;
        a2h[mi] = *(const short8*)&Hsh[ofs];
        a2l[mi] = *(const short8*)&Hsl[ofs];
      }
#pragma unroll
      for (int nt = 0; nt < 4; ++nt) {
        size_t wb = (((size_t)(c * 2 + ktl) * 8 + wc * 4 + nt) * 64 + lane) * 8;
        short8 bh = *(const short8*)(W2h + wb);  // A-operand (m = out col)
        short8 bl = *(const short8*)(W2l + wb);
#pragma unroll
        for (int mi = 0; mi < 4; ++mi) {
          oacc[mi][nt] = __builtin_amdgcn_mfma_f32_16x16x32_bf16(bh, a2h[mi], oacc[mi][nt], 0, 0, 0);
          oacc[mi][nt] = __builtin_amdgcn_mfma_f32_16x16x32_bf16(bh, a2l[mi], oacc[mi][nt], 0, 0, 0);
          oacc[mi][nt] = __builtin_amdgcn_mfma_f32_16x16x32_bf16(bl, a2h[mi], oacc[mi][nt], 0, 0, 0);
        }
      }
    }
  }

  // ---- final epilogue: +b2, float4 store to hpre, BN partial sums ----
#pragma unroll
  for (int nt = 0; nt < 4; ++nt) {
    int ocb = wc * 64 + nt * 16 + quad * 4;  // 4 consecutive out cols per lane
    float4 b2v = ld4(b2g + ocb);
    float bb[4] = {b2v.x, b2v.y, b2v.z, b2v.w};
    f32x4 s = (f32x4){0.f, 0.f, 0.f, 0.f};
    f32x4 s2 = (f32x4){0.f, 0.f, 0.f, 0.f};
#pragma unroll
    for (int mi = 0; mi < 4; ++mi) {
      int node = m0 + (4 * wr + mi) * 16 + l15;
      if (node < NN) {
        float4 v;
        v.x = oacc[mi][nt][0] + bb[0];
        v.y = oacc[mi][nt][1] + bb[1];
        v.z = oacc[mi][nt][2] + bb[2];
        v.w = oacc[mi][nt][3] + bb[3];
        *(float4*)(hpre + (size_t)node * EMB + ocb) = v;
        s[0] += v.x; s[1] += v.y; s[2] += v.z; s[3] += v.w;
        s2[0] += v.x * v.x; s2[1] += v.y * v.y; s2[2] += v.z * v.z; s2[3] += v.w * v.w;
      }
    }
    // reduce over the 16 node-lanes (xor 1,2,4,8 stays within quad group)
#pragma unroll
    for (int d = 1; d < 16; d <<= 1) {
#pragma unroll
      for (int r = 0; r < 4; ++r) {
        s[r] += __shfl_xor(s[r], d);
        s2[r] += __shfl_xor(s2[r], d);
      }
    }
    if (l15 == 0) {
#pragma unroll
      for (int r = 0; r < 4; ++r) {
        atomicAdd(&sums[ocb + r], s[r]);
        atomicAdd(&sums[128 + ocb + r], s2[r]);
      }
    }
  }
}

// ---------------- BN apply (stats recomputed inline from sums; L2-hot) ----------------
template <bool LAST>
__global__ __launch_bounds__(256) void bn_apply_kernel(
    const float* __restrict__ hp, const float* __restrict__ sums,
    const float* __restrict__ gamma, const float* __restrict__ beta,
    float* __restrict__ hf, u16* __restrict__ hb, float* __restrict__ out) {
  int tid = blockIdx.x * blockDim.x + threadIdx.x;
  int n = tid >> 4;
  if (n >= NN) return;
  int kc = tid & 15;
  const float* p = hp + (size_t)n * EMB + kc * 8;
  float4 va = ld4(p), vb = ld4(p + 4);
  float v[8] = {va.x, va.y, va.z, va.w, vb.x, vb.y, vb.z, vb.w};
  float4 sa = ld4(sums + kc * 8), sb = ld4(sums + kc * 8 + 4);
  float4 qa = ld4(sums + 128 + kc * 8), qb = ld4(sums + 128 + kc * 8 + 4);
  float4 ga = ld4(gamma + kc * 8), gb = ld4(gamma + kc * 8 + 4);
  float4 ba = ld4(beta + kc * 8), bb = ld4(beta + kc * 8 + 4);
  float sm[8] = {sa.x, sa.y, sa.z, sa.w, sb.x, sb.y, sb.z, sb.w};
  float sq[8] = {qa.x, qa.y, qa.z, qa.w, qb.x, qb.y, qb.z, qb.w};
  float gm[8] = {ga.x, ga.y, ga.z, ga.w, gb.x, gb.y, gb.z, gb.w};
  float bt[8] = {ba.x, ba.y, ba.z, ba.w, bb.x, bb.y, bb.z, bb.w};
#pragma unroll
  for (int j = 0; j < 8; ++j) {
    float mean = sm[j] * (1.0f / NN);
    float var = sq[j] * (1.0f / NN) - mean * mean;  // biased
    float sc = gm[j] * rsqrtf(var + 1e-5f);
    v[j] = (v[j] - mean) * sc + bt[j];
  }
  if (LAST) {
    float* d = out + (size_t)n * EMB + kc * 8;
    *(float4*)d = make_float4(v[0], v[1], v[2], v[3]);
    *(float4*)(d + 4) = make_float4(v[4], v[5], v[6], v[7]);
  } else {
#pragma unroll
    for (int j = 0; j < 8; ++j) v[j] = fmaxf(v[j], 0.f);
    float* df = hf + (size_t)n * EMB + kc * 8;
    *(float4*)df = make_float4(v[0], v[1], v[2], v[3]);
    *(float4*)(df + 4) = make_float4(v[4], v[5], v[6], v[7]);
    u16 o[8];
#pragma unroll
    for (int j = 0; j < 8; ++j) o[j] = f2bf(v[j]);
    *(ulonglong2*)(hb + (size_t)n * EMB + kc * 8) = *(ulonglong2*)o;
  }
}

// ---------------- launch ----------------
extern "C" void kernel_launch(void* const* d_in, const int* in_sizes, int n_in,
                              void* d_out, int out_size, void* d_ws, size_t ws_size,
                              hipStream_t stream) {
  const int* x = (const int*)d_in[0];
  const int* ei = (const int*)d_in[1];
  const int* ea = (const int*)d_in[2];
  const float* x_emb1 = (const float*)d_in[3];
  const float* x_emb2 = (const float*)d_in[4];
  const float* ee1 = (const float*)d_in[5];
  const float* ee2 = (const float*)d_in[6];
  const float* W1 = (const float*)d_in[7];
  const float* b1 = (const float*)d_in[8];
  const float* W2 = (const float*)d_in[9];
  const float* b2 = (const float*)d_in[10];
  const float* eps = (const float*)d_in[11];
  const float* gamma = (const float*)d_in[12];
  const float* beta = (const float*)d_in[13];
  float* out = (float*)d_out;

  // workspace layout (16B-aligned sections)
  float* hpre = (float*)d_ws;                   // NN*128 f32
  float* hf = hpre + (size_t)NN * EMB;          // NN*128 f32
  float* sums = hf + (size_t)NN * EMB;          // 5*256 (per-layer BN partials)
  float* combos = sums + 5 * 256;               // 9600
  u16* Ah = (u16*)(combos + 9600);              // NPAD*128 bf16
  u16* Al = Ah + (size_t)NPAD * EMB;            // NPAD*128 bf16
  u16* hb = Al + (size_t)NPAD * EMB;            // NN*128 bf16
  u16* W1h = hb + (size_t)NN * EMB;             // 5*32768
  u16* W1l = W1h + 5 * 32768;                   // 5*32768
  u16* W2h = W1l + 5 * 32768;                   // 5*32768
  u16* W2l = W2h + 5 * 32768;                   // 5*32768
  int* deg = (int*)(W2l + 5 * 32768);           // NN
  int* off = deg + NN;                          // NN+1
  int* csr = off + NN + 1;                      // NE
  int* bsum = csr + NE;                         // 128

  const int NB_SCAN = (NN + 1023) / 1024;

  // one-time per launch: CSR + combo tables + frag-ordered split-bf16 weights
  hipMemsetAsync(deg, 0, NN * sizeof(int), stream);
  hipMemsetAsync(sums, 0, 5 * 256 * sizeof(float), stream);
  hist_kernel<<<(NE + 255) / 256, 256, 0, stream>>>(ei, deg);
  scan1_kernel<<<NB_SCAN, 256, 0, stream>>>(deg, off, bsum);
  scan2_kernel<<<1, 64, 0, stream>>>(bsum, off, NB_SCAN);
  scan3_kernel<<<(NN + 255) / 256, 256, 0, stream>>>(off, bsum);
  hipMemsetAsync(deg, 0, NN * sizeof(int), stream);
  scatter_kernel<<<(NE + 255) / 256, 256, 0, stream>>>(ei, ea, off, deg, csr);
  combo_kernel<<<(5 * 15 * 128 + 255) / 256, 256, 0, stream>>>(ee1, ee2, combos);
  prep_w_kernel<<<160, 256, 0, stream>>>(W1, W2, W1h, W1l, W2h, W2l);
  node_init_kernel<<<NN * 16 / 256 + 1, 256, 0, stream>>>(x, x_emb1, x_emb2, hf, hb);

  const int NBLK = NPAD / 128;  // 782
  for (int i = 0; i < 5; ++i) {
    agg_kernel<<<NPAD * 16 / 256, 256, 0, stream>>>(
        hf, hb, off, csr, combos + (size_t)i * 15 * EMB, eps + i, Ah, Al);
    mlp_kernel<<<NBLK, 256, 0, stream>>>(
        Ah, Al, W1h + (size_t)i * 32768, W1l + (size_t)i * 32768,
        W2h + (size_t)i * 32768, W2l + (size_t)i * 32768,
        b1 + (size_t)i * 256, b2 + (size_t)i * 128, hpre, sums + i * 256);
    if (i < 4)
      bn_apply_kernel<false><<<NN * 16 / 256 + 1, 256, 0, stream>>>(
          hpre, sums + i * 256, gamma + (size_t)i * EMB, beta + (size_t)i * EMB,
          hf, hb, nullptr);
    else
      bn_apply_kernel<true><<<NN * 16 / 256 + 1, 256, 0, stream>>>(
          hpre, sums + i * 256, gamma + (size_t)i * EMB, beta + (size_t)i * EMB,
          nullptr, nullptr, out);
  }
}

// Round 7
// 1125.364 us; speedup vs baseline: 1.5517x; 1.5517x over previous
//
#include <hip/hip_runtime.h>

#define NN 100000
#define NPAD 100096   // 3128 * 32, padded row count for guard-free GEMM
#define NE 600000
#define EMB 128

typedef unsigned short u16;
typedef unsigned int u32;
typedef unsigned long long u64;
typedef short short8 __attribute__((ext_vector_type(8)));
typedef float f32x4 __attribute__((ext_vector_type(4)));

__device__ __forceinline__ float4 ld4(const float* p) { return *(const float4*)p; }
__device__ __forceinline__ u16 f2bf(float x) {  // RTNE f32 -> bf16
  u32 u = __float_as_uint(x);
  u += 0x7FFFu + ((u >> 16) & 1u);
  return (u16)(u >> 16);
}
__device__ __forceinline__ float bf2f(u16 h) { return __uint_as_float(((u32)h) << 16); }

// ---------------- node embedding init: hf(f32) + hb(bf16) = emb1[x0] + emb2[x1] ----------------
__global__ __launch_bounds__(256) void node_init_kernel(
    const int* __restrict__ x, const float* __restrict__ emb1,
    const float* __restrict__ emb2, float* __restrict__ hf, u16* __restrict__ hb) {
  int tid = blockIdx.x * blockDim.x + threadIdx.x;
  int n = tid >> 4;
  if (n >= NN) return;
  int kc = tid & 15;
  int x0 = min(max(x[2 * n], 0), 118);
  int x1 = min(max(x[2 * n + 1], 0), 2);  // x[:,1] sampled 0..118 -> clip to NUM_CHIR-1
  const float* p1 = emb1 + (size_t)x0 * EMB + kc * 8;
  const float* p2 = emb2 + (size_t)x1 * EMB + kc * 8;
  float v[8];
#pragma unroll
  for (int j = 0; j < 8; ++j) v[j] = p1[j] + p2[j];
  float* df = hf + (size_t)n * EMB + kc * 8;
  *(float4*)df = make_float4(v[0], v[1], v[2], v[3]);
  *(float4*)(df + 4) = make_float4(v[4], v[5], v[6], v[7]);
  u16 o[8];
#pragma unroll
  for (int j = 0; j < 8; ++j) o[j] = f2bf(v[j]);
  *(ulonglong2*)(hb + (size_t)n * EMB + kc * 8) = *(ulonglong2*)o;
}

// ---------------- CSR build ----------------
__global__ __launch_bounds__(256) void hist_kernel(const int* __restrict__ ei,
                                                   int* __restrict__ deg) {
  int e = blockIdx.x * blockDim.x + threadIdx.x;
  if (e >= NE) return;
  atomicAdd(&deg[ei[NE + e]], 1);
}

__global__ __launch_bounds__(256) void scan1_kernel(const int* __restrict__ deg,
                                                    int* __restrict__ off,
                                                    int* __restrict__ bsum) {
  __shared__ int s[256];
  int t = threadIdx.x;
  int base = blockIdx.x * 1024 + t * 4;
  int v[4];
#pragma unroll
  for (int j = 0; j < 4; ++j) {
    int idx = base + j;
    v[j] = (idx < NN) ? deg[idx] : 0;
  }
  int tsum = v[0] + v[1] + v[2] + v[3];
  s[t] = tsum;
  __syncthreads();
  for (int d = 1; d < 256; d <<= 1) {
    int add = (t >= d) ? s[t - d] : 0;
    __syncthreads();
    s[t] += add;
    __syncthreads();
  }
  int run = s[t] - tsum;
#pragma unroll
  for (int j = 0; j < 4; ++j) {
    int idx = base + j;
    if (idx < NN) off[idx] = run;
    run += v[j];
  }
  if (t == 255) bsum[blockIdx.x] = s[255];
}

__global__ void scan2_kernel(int* __restrict__ bsum, int* __restrict__ off, int nb) {
  if (threadIdx.x == 0) {
    int run = 0;
    for (int b = 0; b < nb; ++b) {
      int v = bsum[b];
      bsum[b] = run;
      run += v;
    }
    off[NN] = run;
  }
}

__global__ __launch_bounds__(256) void scan3_kernel(int* __restrict__ off,
                                                    const int* __restrict__ bsum) {
  int idx = blockIdx.x * blockDim.x + threadIdx.x;
  if (idx < NN) off[idx] += bsum[idx >> 10];
}

__global__ __launch_bounds__(256) void scatter_kernel(
    const int* __restrict__ ei, const int* __restrict__ ea,
    const int* __restrict__ off, int* __restrict__ cnt, int* __restrict__ csr) {
  int e = blockIdx.x * blockDim.x + threadIdx.x;
  if (e >= NE) return;
  int d = ei[NE + e];
  int s = ei[e];
  int a0 = min(max(ea[2 * e], 0), 4);
  int a1 = min(max(ea[2 * e + 1], 0), 2);
  int code = a0 * 3 + a1;  // [0,14]
  int r = atomicAdd(&cnt[d], 1);
  csr[off[d] + r] = s | (code << 20);
}

// combos[l][code][f] = ee1[l][code/3][f] + ee2[l][code%3][f]
__global__ __launch_bounds__(256) void combo_kernel(const float* __restrict__ ee1,
                                                    const float* __restrict__ ee2,
                                                    float* __restrict__ combos) {
  int idx = blockIdx.x * blockDim.x + threadIdx.x;
  if (idx >= 5 * 15 * 128) return;
  int l = idx / (15 * 128);
  int rem = idx % (15 * 128);
  int code = rem / 128;
  int f = rem % 128;
  combos[idx] = ee1[(l * 5 + code / 3) * 128 + f] + ee2[(l * 3 + code % 3) * 128 + f];
}

// ---------------- weight prep: frag-ordered split-bf16 (hi+lo) copies of W1/W2 ----------------
// Used as MFMA A-operand (m = lane&15 = output col, k = quad*8+j).
__global__ __launch_bounds__(256) void prep_w_kernel(
    const float* __restrict__ W1g, const float* __restrict__ W2g,
    u16* __restrict__ W1h, u16* __restrict__ W1l,
    u16* __restrict__ W2h, u16* __restrict__ W2l) {
  int idx = blockIdx.x * blockDim.x + threadIdx.x;
  if (idx >= 40960) return;
  u16 oh[8], ol[8];
  if (idx < 20480) {
    int lane = idx & 63;
    int r = idx >> 6;             // l*64 + c*16 + kt*4 + colt
    int nt = r & 3, kt = (r >> 2) & 3, c = (r >> 4) & 3, l = r >> 6;
    int n = c * 64 + nt * 16 + (lane & 15);
    int kb = kt * 32 + (lane >> 4) * 8;
#pragma unroll
    for (int j = 0; j < 8; ++j) {
      float w = W1g[((size_t)l * 128 + kb + j) * 256 + n];
      oh[j] = f2bf(w);
      ol[j] = f2bf(w - bf2f(oh[j]));
    }
    *(ulonglong2*)(W1h + (size_t)idx * 8) = *(ulonglong2*)oh;
    *(ulonglong2*)(W1l + (size_t)idx * 8) = *(ulonglong2*)ol;
  } else {
    int i2 = idx - 20480;
    int lane = i2 & 63;
    int r = i2 >> 6;              // l*64 + c*16 + ktl*8 + nt
    int nt = r & 7, ktl = (r >> 3) & 1, c = (r >> 4) & 3, l = r >> 6;
    int n = nt * 16 + (lane & 15);
    int kb = c * 64 + ktl * 32 + (lane >> 4) * 8;
#pragma unroll
    for (int j = 0; j < 8; ++j) {
      float w = W2g[((size_t)l * 256 + kb + j) * 128 + n];
      oh[j] = f2bf(w);
      ol[j] = f2bf(w - bf2f(oh[j]));
    }
    *(ulonglong2*)(W2h + (size_t)i2 * 8) = *(ulonglong2*)oh;
    *(ulonglong2*)(W2l + (size_t)i2 * 8) = *(ulonglong2*)ol;
  }
}

// ---------------- agg: A = (1+eps)*hf + relu(hf+c0) + sum relu(hb[src]+c), split hi/lo ----------------
__global__ __launch_bounds__(256) void agg_kernel(
    const float* __restrict__ hf, const u16* __restrict__ hb,
    const int* __restrict__ off, const int* __restrict__ csr,
    const float* __restrict__ cb, const float* __restrict__ epsp,
    u16* __restrict__ Ah, u16* __restrict__ Al) {
  int tid = blockIdx.x * blockDim.x + threadIdx.x;
  int g = tid >> 4;
  int kc = tid & 15;
  float av[8] = {0.f, 0.f, 0.f, 0.f, 0.f, 0.f, 0.f, 0.f};
  if (g < NN) {
    const float eps1 = 1.0f + *epsp;
    const float* hp = hf + (size_t)g * EMB + kc * 8;
    float4 va = ld4(hp), vb = ld4(hp + 4);
    float hv[8] = {va.x, va.y, va.z, va.w, vb.x, vb.y, vb.z, vb.w};
    float4 ca = ld4(cb + kc * 8), cbv = ld4(cb + kc * 8 + 4);
    float cs[8] = {ca.x, ca.y, ca.z, ca.w, cbv.x, cbv.y, cbv.z, cbv.w};
#pragma unroll
    for (int j = 0; j < 8; ++j) av[j] = eps1 * hv[j] + fmaxf(hv[j] + cs[j], 0.f);
    int s0 = off[g], s1 = off[g + 1];
    int e = s0;
    for (; e + 1 < s1; e += 2) {  // unroll x2: two independent gather chains in flight
      int p0 = csr[e], p1 = csr[e + 1];
      ulonglong2 r0 = *(const ulonglong2*)(hb + (size_t)(p0 & 0xFFFFF) * EMB + kc * 8);
      ulonglong2 r1 = *(const ulonglong2*)(hb + (size_t)(p1 & 0xFFFFF) * EMB + kc * 8);
      const float* c0p = cb + (size_t)(p0 >> 20) * EMB + kc * 8;
      const float* c1p = cb + (size_t)(p1 >> 20) * EMB + kc * 8;
      float4 c0a = ld4(c0p), c0b = ld4(c0p + 4);
      float4 c1a = ld4(c1p), c1b = ld4(c1p + 4);
      float cc0[8] = {c0a.x, c0a.y, c0a.z, c0a.w, c0b.x, c0b.y, c0b.z, c0b.w};
      float cc1[8] = {c1a.x, c1a.y, c1a.z, c1a.w, c1b.x, c1b.y, c1b.z, c1b.w};
      u16* s0p = (u16*)&r0;
      u16* s1p = (u16*)&r1;
#pragma unroll
      for (int j = 0; j < 8; ++j) {
        av[j] += fmaxf(bf2f(s0p[j]) + cc0[j], 0.f);
        av[j] += fmaxf(bf2f(s1p[j]) + cc1[j], 0.f);
      }
    }
    if (e < s1) {
      int p0 = csr[e];
      ulonglong2 r0 = *(const ulonglong2*)(hb + (size_t)(p0 & 0xFFFFF) * EMB + kc * 8);
      const float* c0p = cb + (size_t)(p0 >> 20) * EMB + kc * 8;
      float4 c0a = ld4(c0p), c0b = ld4(c0p + 4);
      float cc0[8] = {c0a.x, c0a.y, c0a.z, c0a.w, c0b.x, c0b.y, c0b.z, c0b.w};
      u16* s0p = (u16*)&r0;
#pragma unroll
      for (int j = 0; j < 8; ++j) av[j] += fmaxf(bf2f(s0p[j]) + cc0[j], 0.f);
    }
  }
  u16 oh[8], ol[8];
#pragma unroll
  for (int j = 0; j < 8; ++j) {
    oh[j] = f2bf(av[j]);
    ol[j] = f2bf(av[j] - bf2f(oh[j]));
  }
  *(ulonglong2*)(Ah + (size_t)g * EMB + kc * 8) = *(ulonglong2*)oh;  // zeros for pad rows
  *(ulonglong2*)(Al + (size_t)g * EMB + kc * 8) = *(ulonglong2*)ol;
}

// ---------------- mlp: barrier-free, LDS-free; 1 wave = 32 nodes ----------------
// Transposed GEMMs D[m=col][n=node]; stage-1 C-layout -> stage-2 B-operand via
// in-register quad permutation (__shfl within 16-lane groups). BN partials into
// 32 contention slots.
__global__ __launch_bounds__(256) void mlp_kernel(
    const u16* __restrict__ Ah, const u16* __restrict__ Al,
    const u16* __restrict__ W1h, const u16* __restrict__ W1l,
    const u16* __restrict__ W2h, const u16* __restrict__ W2l,
    const float* __restrict__ b1g, const float* __restrict__ b2g,
    float* __restrict__ hpre, float* __restrict__ slots) {
  const int t = threadIdx.x;
  const int w = t >> 6;
  const int lane = t & 63;
  const int q = lane >> 4, l15 = lane & 15;
  const int gw = blockIdx.x * 4 + w;   // global wave id, 0..3127
  const int n0 = gw * 32;              // 32 nodes per wave
  float* sums = slots + (size_t)(gw & 31) * 256;

  f32x4 oacc[8][2];  // [out col tile][node tile]
#pragma unroll
  for (int a = 0; a < 8; ++a)
#pragma unroll
    for (int b = 0; b < 2; ++b) oacc[a][b] = (f32x4){0.f, 0.f, 0.f, 0.f};

  const int srcA = ((q & 1) * 2) * 16 + l15;  // quad permutation sources
  const int srcB = srcA + 16;
  const bool sel = (q >> 1) != 0;

  for (int c = 0; c < 4; ++c) {
    // ---- stage 1: hmidT[col c*64+colt*16+q*4+r][node l15] ----
    f32x4 hacc[4][2];  // [colt][mi]
#pragma unroll
    for (int a = 0; a < 4; ++a)
#pragma unroll
      for (int b = 0; b < 2; ++b) hacc[a][b] = (f32x4){0.f, 0.f, 0.f, 0.f};
#pragma unroll
    for (int kt = 0; kt < 4; ++kt) {
      short8 nh[2], nl[2];
#pragma unroll
      for (int mi = 0; mi < 2; ++mi) {  // node B-frags (L1/L2-hot after chunk 0)
        size_t base = (size_t)(n0 + mi * 16 + l15) * EMB + kt * 32 + q * 8;
        nh[mi] = *(const short8*)(Ah + base);
        nl[mi] = *(const short8*)(Al + base);
      }
#pragma unroll
      for (int colt = 0; colt < 4; ++colt) {
        size_t wb = (((size_t)(c * 4 + kt) * 4 + colt) * 64 + lane) * 8;
        short8 wh = *(const short8*)(W1h + wb);
        short8 wl = *(const short8*)(W1l + wb);
#pragma unroll
        for (int mi = 0; mi < 2; ++mi) {
          hacc[colt][mi] = __builtin_amdgcn_mfma_f32_16x16x32_bf16(wh, nh[mi], hacc[colt][mi], 0, 0, 0);
          hacc[colt][mi] = __builtin_amdgcn_mfma_f32_16x16x32_bf16(wh, nl[mi], hacc[colt][mi], 0, 0, 0);
          hacc[colt][mi] = __builtin_amdgcn_mfma_f32_16x16x32_bf16(wl, nh[mi], hacc[colt][mi], 0, 0, 0);
        }
      }
    }
    // ---- bias + relu + split + pack (2 bf16/dword, k-ascending) ----
    u32 P01h[4][2], P23h[4][2], P01l[4][2], P23l[4][2];  // [colt][mi]
#pragma unroll
    for (int colt = 0; colt < 4; ++colt) {
      float4 b1v = ld4(b1g + c * 64 + colt * 16 + q * 4);
      float bb[4] = {b1v.x, b1v.y, b1v.z, b1v.w};
#pragma unroll
      for (int mi = 0; mi < 2; ++mi) {
        u16 hi[4], lo[4];
#pragma unroll
        for (int r = 0; r < 4; ++r) {
          float v = fmaxf(hacc[colt][mi][r] + bb[r], 0.f);
          hi[r] = f2bf(v);
          lo[r] = f2bf(v - bf2f(hi[r]));
        }
        P01h[colt][mi] = (u32)hi[0] | ((u32)hi[1] << 16);
        P23h[colt][mi] = (u32)hi[2] | ((u32)hi[3] << 16);
        P01l[colt][mi] = (u32)lo[0] | ((u32)lo[1] << 16);
        P23l[colt][mi] = (u32)lo[2] | ((u32)lo[3] << 16);
      }
    }
    // ---- stage 2: quad-permute hmid into B-frags, multiply with W2 ----
#pragma unroll
    for (int ktl = 0; ktl < 2; ++ktl) {
      short8 bh[2], bl[2];
#pragma unroll
      for (int mi = 0; mi < 2; ++mi) {
        union { u32 d[4]; short8 s; } uh, ul;
        int c0 = 2 * ktl, c1 = 2 * ktl + 1;
        u32 a0, a1;
        a0 = (u32)__shfl((int)P01h[c0][mi], srcA); a1 = (u32)__shfl((int)P01h[c1][mi], srcA);
        uh.d[0] = sel ? a1 : a0;
        a0 = (u32)__shfl((int)P23h[c0][mi], srcA); a1 = (u32)__shfl((int)P23h[c1][mi], srcA);
        uh.d[1] = sel ? a1 : a0;
        a0 = (u32)__shfl((int)P01h[c0][mi], srcB); a1 = (u32)__shfl((int)P01h[c1][mi], srcB);
        uh.d[2] = sel ? a1 : a0;
        a0 = (u32)__shfl((int)P23h[c0][mi], srcB); a1 = (u32)__shfl((int)P23h[c1][mi], srcB);
        uh.d[3] = sel ? a1 : a0;
        a0 = (u32)__shfl((int)P01l[c0][mi], srcA); a1 = (u32)__shfl((int)P01l[c1][mi], srcA);
        ul.d[0] = sel ? a1 : a0;
        a0 = (u32)__shfl((int)P23l[c0][mi], srcA); a1 = (u32)__shfl((int)P23l[c1][mi], srcA);
        ul.d[1] = sel ? a1 : a0;
        a0 = (u32)__shfl((int)P01l[c0][mi], srcB); a1 = (u32)__shfl((int)P01l[c1][mi], srcB);
        ul.d[2] = sel ? a1 : a0;
        a0 = (u32)__shfl((int)P23l[c0][mi], srcB); a1 = (u32)__shfl((int)P23l[c1][mi], srcB);
        ul.d[3] = sel ? a1 : a0;
        bh[mi] = uh.s;
        bl[mi] = ul.s;
      }
#pragma unroll
      for (int nt = 0; nt < 8; ++nt) {
        size_t wb = (((size_t)(c * 2 + ktl) * 8 + nt) * 64 + lane) * 8;
        short8 wh = *(const short8*)(W2h + wb);
        short8 wl = *(const short8*)(W2l + wb);
#pragma unroll
        for (int mi = 0; mi < 2; ++mi) {
          oacc[nt][mi] = __builtin_amdgcn_mfma_f32_16x16x32_bf16(wh, bh[mi], oacc[nt][mi], 0, 0, 0);
          oacc[nt][mi] = __builtin_amdgcn_mfma_f32_16x16x32_bf16(wh, bl[mi], oacc[nt][mi], 0, 0, 0);
          oacc[nt][mi] = __builtin_amdgcn_mfma_f32_16x16x32_bf16(wl, bh[mi], oacc[nt][mi], 0, 0, 0);
        }
      }
    }
  }

  // ---- epilogue: +b2, float4 store, BN partials into slot ----
#pragma unroll
  for (int nt = 0; nt < 8; ++nt) {
    int ocb = nt * 16 + q * 4;  // 4 consecutive out cols per lane
    float4 b2v = ld4(b2g + ocb);
    float bb[4] = {b2v.x, b2v.y, b2v.z, b2v.w};
    f32x4 s = (f32x4){0.f, 0.f, 0.f, 0.f};
    f32x4 s2 = (f32x4){0.f, 0.f, 0.f, 0.f};
#pragma unroll
    for (int mi = 0; mi < 2; ++mi) {
      int node = n0 + mi * 16 + l15;
      if (node < NN) {
        float4 v;
        v.x = oacc[nt][mi][0] + bb[0];
        v.y = oacc[nt][mi][1] + bb[1];
        v.z = oacc[nt][mi][2] + bb[2];
        v.w = oacc[nt][mi][3] + bb[3];
        *(float4*)(hpre + (size_t)node * EMB + ocb) = v;
        s[0] += v.x; s[1] += v.y; s[2] += v.z; s[3] += v.w;
        s2[0] += v.x * v.x; s2[1] += v.y * v.y; s2[2] += v.z * v.z; s2[3] += v.w * v.w;
      }
    }
#pragma unroll
    for (int d = 1; d < 16; d <<= 1) {
#pragma unroll
      for (int r = 0; r < 4; ++r) {
        s[r] += __shfl_xor(s[r], d);
        s2[r] += __shfl_xor(s2[r], d);
      }
    }
    if (l15 == 0) {
#pragma unroll
      for (int r = 0; r < 4; ++r) {
        atomicAdd(&sums[ocb + r], s[r]);
        atomicAdd(&sums[128 + ocb + r], s2[r]);
      }
    }
  }
}

// ---------------- reduce 32 BN slots -> sums[256] ----------------
__global__ void sums_reduce_kernel(const float* __restrict__ slots,
                                   float* __restrict__ sums) {
  int f = threadIdx.x;  // 256
  float s = 0.f;
#pragma unroll 8
  for (int k = 0; k < 32; ++k) s += slots[k * 256 + f];
  sums[f] = s;
}

// ---------------- BN apply (stats recomputed inline from sums; L2-hot) ----------------
template <bool LAST>
__global__ __launch_bounds__(256) void bn_apply_kernel(
    const float* __restrict__ hp, const float* __restrict__ sums,
    const float* __restrict__ gamma, const float* __restrict__ beta,
    float* __restrict__ hf, u16* __restrict__ hb, float* __restrict__ out) {
  int tid = blockIdx.x * blockDim.x + threadIdx.x;
  int n = tid >> 4;
  if (n >= NN) return;
  int kc = tid & 15;
  const float* p = hp + (size_t)n * EMB + kc * 8;
  float4 va = ld4(p), vb = ld4(p + 4);
  float v[8] = {va.x, va.y, va.z, va.w, vb.x, vb.y, vb.z, vb.w};
  float4 sa = ld4(sums + kc * 8), sb = ld4(sums + kc * 8 + 4);
  float4 qa = ld4(sums + 128 + kc * 8), qb = ld4(sums + 128 + kc * 8 + 4);
  float4 ga = ld4(gamma + kc * 8), gb = ld4(gamma + kc * 8 + 4);
  float4 ba = ld4(beta + kc * 8), bb = ld4(beta + kc * 8 + 4);
  float sm[8] = {sa.x, sa.y, sa.z, sa.w, sb.x, sb.y, sb.z, sb.w};
  float sq[8] = {qa.x, qa.y, qa.z, qa.w, qb.x, qb.y, qb.z, qb.w};
  float gm[8] = {ga.x, ga.y, ga.z, ga.w, gb.x, gb.y, gb.z, gb.w};
  float bt[8] = {ba.x, ba.y, ba.z, ba.w, bb.x, bb.y, bb.z, bb.w};
#pragma unroll
  for (int j = 0; j < 8; ++j) {
    float mean = sm[j] * (1.0f / NN);
    float var = sq[j] * (1.0f / NN) - mean * mean;  // biased
    float sc = gm[j] * rsqrtf(var + 1e-5f);
    v[j] = (v[j] - mean) * sc + bt[j];
  }
  if (LAST) {
    float* d = out + (size_t)n * EMB + kc * 8;
    *(float4*)d = make_float4(v[0], v[1], v[2], v[3]);
    *(float4*)(d + 4) = make_float4(v[4], v[5], v[6], v[7]);
  } else {
#pragma unroll
    for (int j = 0; j < 8; ++j) v[j] = fmaxf(v[j], 0.f);
    float* df = hf + (size_t)n * EMB + kc * 8;
    *(float4*)df = make_float4(v[0], v[1], v[2], v[3]);
    *(float4*)(df + 4) = make_float4(v[4], v[5], v[6], v[7]);
    u16 o[8];
#pragma unroll
    for (int j = 0; j < 8; ++j) o[j] = f2bf(v[j]);
    *(ulonglong2*)(hb + (size_t)n * EMB + kc * 8) = *(ulonglong2*)o;
  }
}

// ---------------- launch ----------------
extern "C" void kernel_launch(void* const* d_in, const int* in_sizes, int n_in,
                              void* d_out, int out_size, void* d_ws, size_t ws_size,
                              hipStream_t stream) {
  const int* x = (const int*)d_in[0];
  const int* ei = (const int*)d_in[1];
  const int* ea = (const int*)d_in[2];
  const float* x_emb1 = (const float*)d_in[3];
  const float* x_emb2 = (const float*)d_in[4];
  const float* ee1 = (const float*)d_in[5];
  const float* ee2 = (const float*)d_in[6];
  const float* W1 = (const float*)d_in[7];
  const float* b1 = (const float*)d_in[8];
  const float* W2 = (const float*)d_in[9];
  const float* b2 = (const float*)d_in[10];
  const float* eps = (const float*)d_in[11];
  const float* gamma = (const float*)d_in[12];
  const float* beta = (const float*)d_in[13];
  float* out = (float*)d_out;

  // workspace layout (16B-aligned sections)
  float* hpre = (float*)d_ws;                   // NN*128 f32
  float* hf = hpre + (size_t)NN * EMB;          // NN*128 f32
  float* slots = hf + (size_t)NN * EMB;         // 5*32*256 BN partial slots
  float* sums = slots + 5 * 32 * 256;           // 5*256 reduced
  float* combos = sums + 5 * 256;               // 9600
  u16* Ah = (u16*)(combos + 9600);              // NPAD*128 bf16
  u16* Al = Ah + (size_t)NPAD * EMB;            // NPAD*128 bf16
  u16* hb = Al + (size_t)NPAD * EMB;            // NN*128 bf16
  u16* W1h = hb + (size_t)NN * EMB;             // 5*32768
  u16* W1l = W1h + 5 * 32768;                   // 5*32768
  u16* W2h = W1l + 5 * 32768;                   // 5*32768
  u16* W2l = W2h + 5 * 32768;                   // 5*32768
  int* deg = (int*)(W2l + 5 * 32768);           // NN
  int* off = deg + NN;                          // NN+1
  int* csr = off + NN + 1;                      // NE
  int* bsum = csr + NE;                         // 128

  const int NB_SCAN = (NN + 1023) / 1024;

  // one-time per launch: CSR + combo tables + frag-ordered split-bf16 weights
  hipMemsetAsync(deg, 0, NN * sizeof(int), stream);
  hipMemsetAsync(slots, 0, 5 * 32 * 256 * sizeof(float), stream);
  hist_kernel<<<(NE + 255) / 256, 256, 0, stream>>>(ei, deg);
  scan1_kernel<<<NB_SCAN, 256, 0, stream>>>(deg, off, bsum);
  scan2_kernel<<<1, 64, 0, stream>>>(bsum, off, NB_SCAN);
  scan3_kernel<<<(NN + 255) / 256, 256, 0, stream>>>(off, bsum);
  hipMemsetAsync(deg, 0, NN * sizeof(int), stream);
  scatter_kernel<<<(NE + 255) / 256, 256, 0, stream>>>(ei, ea, off, deg, csr);
  combo_kernel<<<(5 * 15 * 128 + 255) / 256, 256, 0, stream>>>(ee1, ee2, combos);
  prep_w_kernel<<<160, 256, 0, stream>>>(W1, W2, W1h, W1l, W2h, W2l);
  node_init_kernel<<<NN * 16 / 256 + 1, 256, 0, stream>>>(x, x_emb1, x_emb2, hf, hb);

  const int NBLK = NPAD / 128;  // 782 blocks x 4 independent waves (32 nodes each)
  for (int i = 0; i < 5; ++i) {
    agg_kernel<<<NPAD * 16 / 256, 256, 0, stream>>>(
        hf, hb, off, csr, combos + (size_t)i * 15 * EMB, eps + i, Ah, Al);
    mlp_kernel<<<NBLK, 256, 0, stream>>>(
        Ah, Al, W1h + (size_t)i * 32768, W1l + (size_t)i * 32768,
        W2h + (size_t)i * 32768, W2l + (size_t)i * 32768,
        b1 + (size_t)i * 256, b2 + (size_t)i * 128, hpre,
        slots + (size_t)i * 32 * 256);
    sums_reduce_kernel<<<1, 256, 0, stream>>>(slots + (size_t)i * 32 * 256,
                                              sums + (size_t)i * 256);
    if (i < 4)
      bn_apply_kernel<false><<<NN * 16 / 256 + 1, 256, 0, stream>>>(
          hpre, sums + (size_t)i * 256, gamma + (size_t)i * EMB, beta + (size_t)i * EMB,
          hf, hb, nullptr);
    else
      bn_apply_kernel<true><<<NN * 16 / 256 + 1, 256, 0, stream>>>(
          hpre, sums + (size_t)i * 256, gamma + (size_t)i * EMB, beta + (size_t)i * EMB,
          nullptr, nullptr, out);
  }
}

// Round 8
// 1042.611 us; speedup vs baseline: 1.6749x; 1.0794x over previous
//
#include <hip/hip_runtime.h>

#define NN 100000
#define NPAD 100096   // 3128 * 32, padded row count for guard-free GEMM
#define NE 600000
#define EMB 128

typedef unsigned short u16;
typedef unsigned int u32;
typedef unsigned long long u64;
typedef short short8 __attribute__((ext_vector_type(8)));
typedef float f32x4 __attribute__((ext_vector_type(4)));

__device__ __forceinline__ float4 ld4(const float* p) { return *(const float4*)p; }
__device__ __forceinline__ u16 f2bf(float x) {  // RTNE f32 -> bf16
  u32 u = __float_as_uint(x);
  u += 0x7FFFu + ((u >> 16) & 1u);
  return (u16)(u >> 16);
}
__device__ __forceinline__ float bf2f(u16 h) { return __uint_as_float(((u32)h) << 16); }

// ---------------- node embedding init: hf(f32) + hb(bf16) = emb1[x0] + emb2[x1] ----------------
__global__ __launch_bounds__(256) void node_init_kernel(
    const int* __restrict__ x, const float* __restrict__ emb1,
    const float* __restrict__ emb2, float* __restrict__ hf, u16* __restrict__ hb) {
  int tid = blockIdx.x * blockDim.x + threadIdx.x;
  int n = tid >> 4;
  if (n >= NN) return;
  int kc = tid & 15;
  int x0 = min(max(x[2 * n], 0), 118);
  int x1 = min(max(x[2 * n + 1], 0), 2);  // x[:,1] sampled 0..118 -> clip to NUM_CHIR-1
  const float* p1 = emb1 + (size_t)x0 * EMB + kc * 8;
  const float* p2 = emb2 + (size_t)x1 * EMB + kc * 8;
  float v[8];
#pragma unroll
  for (int j = 0; j < 8; ++j) v[j] = p1[j] + p2[j];
  float* df = hf + (size_t)n * EMB + kc * 8;
  *(float4*)df = make_float4(v[0], v[1], v[2], v[3]);
  *(float4*)(df + 4) = make_float4(v[4], v[5], v[6], v[7]);
  u16 o[8];
#pragma unroll
  for (int j = 0; j < 8; ++j) o[j] = f2bf(v[j]);
  *(ulonglong2*)(hb + (size_t)n * EMB + kc * 8) = *(ulonglong2*)o;
}

// ---------------- CSR build ----------------
__global__ __launch_bounds__(256) void hist_kernel(const int* __restrict__ ei,
                                                   int* __restrict__ deg) {
  int e = blockIdx.x * blockDim.x + threadIdx.x;
  if (e >= NE) return;
  atomicAdd(&deg[ei[NE + e]], 1);
}

__global__ __launch_bounds__(256) void scan1_kernel(const int* __restrict__ deg,
                                                    int* __restrict__ off,
                                                    int* __restrict__ bsum) {
  __shared__ int s[256];
  int t = threadIdx.x;
  int base = blockIdx.x * 1024 + t * 4;
  int v[4];
#pragma unroll
  for (int j = 0; j < 4; ++j) {
    int idx = base + j;
    v[j] = (idx < NN) ? deg[idx] : 0;
  }
  int tsum = v[0] + v[1] + v[2] + v[3];
  s[t] = tsum;
  __syncthreads();
  for (int d = 1; d < 256; d <<= 1) {
    int add = (t >= d) ? s[t - d] : 0;
    __syncthreads();
    s[t] += add;
    __syncthreads();
  }
  int run = s[t] - tsum;
#pragma unroll
  for (int j = 0; j < 4; ++j) {
    int idx = base + j;
    if (idx < NN) off[idx] = run;
    run += v[j];
  }
  if (t == 255) bsum[blockIdx.x] = s[255];
}

__global__ void scan2_kernel(int* __restrict__ bsum, int* __restrict__ off, int nb) {
  if (threadIdx.x == 0) {
    int run = 0;
    for (int b = 0; b < nb; ++b) {
      int v = bsum[b];
      bsum[b] = run;
      run += v;
    }
    off[NN] = run;
  }
}

__global__ __launch_bounds__(256) void scan3_kernel(int* __restrict__ off,
                                                    const int* __restrict__ bsum) {
  int idx = blockIdx.x * blockDim.x + threadIdx.x;
  if (idx < NN) off[idx] += bsum[idx >> 10];
}

__global__ __launch_bounds__(256) void scatter_kernel(
    const int* __restrict__ ei, const int* __restrict__ ea,
    const int* __restrict__ off, int* __restrict__ cnt, int* __restrict__ csr) {
  int e = blockIdx.x * blockDim.x + threadIdx.x;
  if (e >= NE) return;
  int d = ei[NE + e];
  int s = ei[e];
  int a0 = min(max(ea[2 * e], 0), 4);
  int a1 = min(max(ea[2 * e + 1], 0), 2);
  int code = a0 * 3 + a1;  // [0,14]
  int r = atomicAdd(&cnt[d], 1);
  csr[off[d] + r] = s | (code << 20);
}

// combos[l][code][f] = ee1[l][code/3][f] + ee2[l][code%3][f]
__global__ __launch_bounds__(256) void combo_kernel(const float* __restrict__ ee1,
                                                    const float* __restrict__ ee2,
                                                    float* __restrict__ combos) {
  int idx = blockIdx.x * blockDim.x + threadIdx.x;
  if (idx >= 5 * 15 * 128) return;
  int l = idx / (15 * 128);
  int rem = idx % (15 * 128);
  int code = rem / 128;
  int f = rem % 128;
  combos[idx] = ee1[(l * 5 + code / 3) * 128 + f] + ee2[(l * 3 + code % 3) * 128 + f];
}

// ---------------- weight prep: frag-ordered split-bf16, hi/lo INTERLEAVED 32B pairs ----------------
// Frag-pair f at (f*64+lane)*16: [0..7]=hi, [8..15]=lo  -> both halves on one 128B line.
__global__ __launch_bounds__(256) void prep_w_kernel(
    const float* __restrict__ W1g, const float* __restrict__ W2g,
    u16* __restrict__ W1f, u16* __restrict__ W2f) {
  int idx = blockIdx.x * blockDim.x + threadIdx.x;
  if (idx >= 40960) return;
  u16 oh[8], ol[8];
  if (idx < 20480) {
    int lane = idx & 63;
    int r = idx >> 6;             // l*64 + c*16 + kt*4 + colt
    int nt = r & 3, kt = (r >> 2) & 3, c = (r >> 4) & 3, l = r >> 6;
    int n = c * 64 + nt * 16 + (lane & 15);
    int kb = kt * 32 + (lane >> 4) * 8;
#pragma unroll
    for (int j = 0; j < 8; ++j) {
      float w = W1g[((size_t)l * 128 + kb + j) * 256 + n];
      oh[j] = f2bf(w);
      ol[j] = f2bf(w - bf2f(oh[j]));
    }
    *(ulonglong2*)(W1f + (size_t)idx * 16) = *(ulonglong2*)oh;
    *(ulonglong2*)(W1f + (size_t)idx * 16 + 8) = *(ulonglong2*)ol;
  } else {
    int i2 = idx - 20480;
    int lane = i2 & 63;
    int r = i2 >> 6;              // l*64 + c*16 + ktl*8 + nt
    int nt = r & 7, ktl = (r >> 3) & 1, c = (r >> 4) & 3, l = r >> 6;
    int n = nt * 16 + (lane & 15);
    int kb = c * 64 + ktl * 32 + (lane >> 4) * 8;
#pragma unroll
    for (int j = 0; j < 8; ++j) {
      float w = W2g[((size_t)l * 256 + kb + j) * 128 + n];
      oh[j] = f2bf(w);
      ol[j] = f2bf(w - bf2f(oh[j]));
    }
    *(ulonglong2*)(W2f + (size_t)i2 * 16) = *(ulonglong2*)oh;
    *(ulonglong2*)(W2f + (size_t)i2 * 16 + 8) = *(ulonglong2*)ol;
  }
}

// ---------------- agg: A = (1+eps)*hf + relu(hf+c0) + sum relu(hb[src]+c) ----------------
// Output Af interleaved: node*256 + kc*16: [0..7]=hi, [8..15]=lo (32B contiguous).
__global__ __launch_bounds__(256) void agg_kernel(
    const float* __restrict__ hf, const u16* __restrict__ hb,
    const int* __restrict__ off, const int* __restrict__ csr,
    const float* __restrict__ cb, const float* __restrict__ epsp,
    u16* __restrict__ Af) {
  int tid = blockIdx.x * blockDim.x + threadIdx.x;
  int g = tid >> 4;
  int kc = tid & 15;
  float av[8] = {0.f, 0.f, 0.f, 0.f, 0.f, 0.f, 0.f, 0.f};
  if (g < NN) {
    const float eps1 = 1.0f + *epsp;
    const float* hp = hf + (size_t)g * EMB + kc * 8;
    float4 va = ld4(hp), vb = ld4(hp + 4);
    float hv[8] = {va.x, va.y, va.z, va.w, vb.x, vb.y, vb.z, vb.w};
    float4 ca = ld4(cb + kc * 8), cbv = ld4(cb + kc * 8 + 4);
    float cs[8] = {ca.x, ca.y, ca.z, ca.w, cbv.x, cbv.y, cbv.z, cbv.w};
#pragma unroll
    for (int j = 0; j < 8; ++j) av[j] = eps1 * hv[j] + fmaxf(hv[j] + cs[j], 0.f);
    int s0 = off[g], s1 = off[g + 1];
    int e = s0;
    for (; e + 1 < s1; e += 2) {  // unroll x2: two independent gather chains in flight
      int p0 = csr[e], p1 = csr[e + 1];
      ulonglong2 r0 = *(const ulonglong2*)(hb + (size_t)(p0 & 0xFFFFF) * EMB + kc * 8);
      ulonglong2 r1 = *(const ulonglong2*)(hb + (size_t)(p1 & 0xFFFFF) * EMB + kc * 8);
      const float* c0p = cb + (size_t)(p0 >> 20) * EMB + kc * 8;
      const float* c1p = cb + (size_t)(p1 >> 20) * EMB + kc * 8;
      float4 c0a = ld4(c0p), c0b = ld4(c0p + 4);
      float4 c1a = ld4(c1p), c1b = ld4(c1p + 4);
      float cc0[8] = {c0a.x, c0a.y, c0a.z, c0a.w, c0b.x, c0b.y, c0b.z, c0b.w};
      float cc1[8] = {c1a.x, c1a.y, c1a.z, c1a.w, c1b.x, c1b.y, c1b.z, c1b.w};
      u16* s0p = (u16*)&r0;
      u16* s1p = (u16*)&r1;
#pragma unroll
      for (int j = 0; j < 8; ++j) {
        av[j] += fmaxf(bf2f(s0p[j]) + cc0[j], 0.f);
        av[j] += fmaxf(bf2f(s1p[j]) + cc1[j], 0.f);
      }
    }
    if (e < s1) {
      int p0 = csr[e];
      ulonglong2 r0 = *(const ulonglong2*)(hb + (size_t)(p0 & 0xFFFFF) * EMB + kc * 8);
      const float* c0p = cb + (size_t)(p0 >> 20) * EMB + kc * 8;
      float4 c0a = ld4(c0p), c0b = ld4(c0p + 4);
      float cc0[8] = {c0a.x, c0a.y, c0a.z, c0a.w, c0b.x, c0b.y, c0b.z, c0b.w};
      u16* s0p = (u16*)&r0;
#pragma unroll
      for (int j = 0; j < 8; ++j) av[j] += fmaxf(bf2f(s0p[j]) + cc0[j], 0.f);
    }
  }
  u16 oh[8], ol[8];
#pragma unroll
  for (int j = 0; j < 8; ++j) {
    oh[j] = f2bf(av[j]);
    ol[j] = f2bf(av[j] - bf2f(oh[j]));
  }
  u16* d = Af + (size_t)g * 256 + kc * 16;
  *(ulonglong2*)d = *(ulonglong2*)oh;        // zeros for pad rows
  *(ulonglong2*)(d + 8) = *(ulonglong2*)ol;
}

// ---------------- mlp: barrier-free, LDS-free, register-pipelined W prefetch ----------------
__global__ __launch_bounds__(256) void mlp_kernel(
    const u16* __restrict__ Af, const u16* __restrict__ W1f,
    const u16* __restrict__ W2f,
    const float* __restrict__ b1g, const float* __restrict__ b2g,
    float* __restrict__ hpre, float* __restrict__ slots) {
  const int t = threadIdx.x;
  const int w = t >> 6;
  const int lane = t & 63;
  const int q = lane >> 4, l15 = lane & 15;
  const int gw = blockIdx.x * 4 + w;   // global wave id, 0..3127
  const int n0 = gw * 32;              // 32 nodes per wave
  float* sums = slots + (size_t)(gw & 31) * 256;

  f32x4 oacc[8][2];  // [out col tile][node tile]
#pragma unroll
  for (int a = 0; a < 8; ++a)
#pragma unroll
    for (int b = 0; b < 2; ++b) oacc[a][b] = (f32x4){0.f, 0.f, 0.f, 0.f};

  const int srcA = ((q & 1) * 2) * 16 + l15;  // quad permutation sources
  const int srcB = srcA + 16;
  const bool sel = (q >> 1) != 0;

  for (int c = 0; c < 4; ++c) {
    // ---- stage 1: hmidT[col c*64+colt*16+q*4+r][node l15], pipelined over kt ----
    f32x4 hacc[4][2];  // [colt][mi]
#pragma unroll
    for (int a = 0; a < 4; ++a)
#pragma unroll
      for (int b = 0; b < 2; ++b) hacc[a][b] = (f32x4){0.f, 0.f, 0.f, 0.f};

    short8 cwh[4], cwl[4];
#pragma unroll
    for (int colt = 0; colt < 4; ++colt) {  // preload kt=0 W pairs
      const u16* p = W1f + ((size_t)((c * 4 + 0) * 4 + colt) * 64 + lane) * 16;
      cwh[colt] = *(const short8*)p;
      cwl[colt] = *(const short8*)(p + 8);
    }
#pragma unroll
    for (int kt = 0; kt < 4; ++kt) {
      short8 nh[2], nl[2];
#pragma unroll
      for (int mi = 0; mi < 2; ++mi) {
        const u16* p = Af + (size_t)(n0 + mi * 16 + l15) * 256 + kt * 64 + q * 16;
        nh[mi] = *(const short8*)p;
        nl[mi] = *(const short8*)(p + 8);
      }
      short8 nwh[4];  // prefetch next kt's hi (lo rides the same cache line)
      if (kt < 3) {
#pragma unroll
        for (int colt = 0; colt < 4; ++colt)
          nwh[colt] = *(const short8*)(W1f + ((size_t)((c * 4 + kt + 1) * 4 + colt) * 64 + lane) * 16);
      }
#pragma unroll
      for (int colt = 0; colt < 4; ++colt) {
#pragma unroll
        for (int mi = 0; mi < 2; ++mi) {
          hacc[colt][mi] = __builtin_amdgcn_mfma_f32_16x16x32_bf16(cwh[colt], nh[mi], hacc[colt][mi], 0, 0, 0);
          hacc[colt][mi] = __builtin_amdgcn_mfma_f32_16x16x32_bf16(cwh[colt], nl[mi], hacc[colt][mi], 0, 0, 0);
          hacc[colt][mi] = __builtin_amdgcn_mfma_f32_16x16x32_bf16(cwl[colt], nh[mi], hacc[colt][mi], 0, 0, 0);
        }
      }
      if (kt < 3) {
#pragma unroll
        for (int colt = 0; colt < 4; ++colt) {
          cwh[colt] = nwh[colt];
          cwl[colt] = *(const short8*)(W1f + ((size_t)((c * 4 + kt + 1) * 4 + colt) * 64 + lane) * 16 + 8);
        }
      }
    }
    // prefetch stage-2 first W pair (hides latency behind the pack/shfl phase)
    short8 c2h = *(const short8*)(W2f + ((size_t)((c * 2 + 0) * 8 + 0) * 64 + lane) * 16);
    short8 c2l = *(const short8*)(W2f + ((size_t)((c * 2 + 0) * 8 + 0) * 64 + lane) * 16 + 8);

    // ---- bias + relu + split + pack (2 bf16/dword, k-ascending) ----
    u32 P01h[4][2], P23h[4][2], P01l[4][2], P23l[4][2];  // [colt][mi]
#pragma unroll
    for (int colt = 0; colt < 4; ++colt) {
      float4 b1v = ld4(b1g + c * 64 + colt * 16 + q * 4);
      float bb[4] = {b1v.x, b1v.y, b1v.z, b1v.w};
#pragma unroll
      for (int mi = 0; mi < 2; ++mi) {
        u16 hi[4], lo[4];
#pragma unroll
        for (int r = 0; r < 4; ++r) {
          float v = fmaxf(hacc[colt][mi][r] + bb[r], 0.f);
          hi[r] = f2bf(v);
          lo[r] = f2bf(v - bf2f(hi[r]));
        }
        P01h[colt][mi] = (u32)hi[0] | ((u32)hi[1] << 16);
        P23h[colt][mi] = (u32)hi[2] | ((u32)hi[3] << 16);
        P01l[colt][mi] = (u32)lo[0] | ((u32)lo[1] << 16);
        P23l[colt][mi] = (u32)lo[2] | ((u32)lo[3] << 16);
      }
    }
    // ---- stage 2: quad-permute hmid into B-frags, multiply with W2 (pipelined over nt) ----
#pragma unroll
    for (int ktl = 0; ktl < 2; ++ktl) {
      short8 bh[2], bl[2];
#pragma unroll
      for (int mi = 0; mi < 2; ++mi) {
        union { u32 d[4]; short8 s; } uh, ul;
        int c0 = 2 * ktl, c1 = 2 * ktl + 1;
        u32 a0, a1;
        a0 = (u32)__shfl((int)P01h[c0][mi], srcA); a1 = (u32)__shfl((int)P01h[c1][mi], srcA);
        uh.d[0] = sel ? a1 : a0;
        a0 = (u32)__shfl((int)P23h[c0][mi], srcA); a1 = (u32)__shfl((int)P23h[c1][mi], srcA);
        uh.d[1] = sel ? a1 : a0;
        a0 = (u32)__shfl((int)P01h[c0][mi], srcB); a1 = (u32)__shfl((int)P01h[c1][mi], srcB);
        uh.d[2] = sel ? a1 : a0;
        a0 = (u32)__shfl((int)P23h[c0][mi], srcB); a1 = (u32)__shfl((int)P23h[c1][mi], srcB);
        uh.d[3] = sel ? a1 : a0;
        a0 = (u32)__shfl((int)P01l[c0][mi], srcA); a1 = (u32)__shfl((int)P01l[c1][mi], srcA);
        ul.d[0] = sel ? a1 : a0;
        a0 = (u32)__shfl((int)P23l[c0][mi], srcA); a1 = (u32)__shfl((int)P23l[c1][mi], srcA);
        ul.d[1] = sel ? a1 : a0;
        a0 = (u32)__shfl((int)P01l[c0][mi], srcB); a1 = (u32)__shfl((int)P01l[c1][mi], srcB);
        ul.d[2] = sel ? a1 : a0;
        a0 = (u32)__shfl((int)P23l[c0][mi], srcB); a1 = (u32)__shfl((int)P23l[c1][mi], srcB);
        ul.d[3] = sel ? a1 : a0;
        bh[mi] = uh.s;
        bl[mi] = ul.s;
      }
#pragma unroll
      for (int nt = 0; nt < 8; ++nt) {
        short8 wh = c2h, wl = c2l;
        // prefetch next (ktl,nt) pair
        int nktl = (nt < 7) ? ktl : ktl + 1;
        int nnt = (nt < 7) ? nt + 1 : 0;
        if (!(ktl == 1 && nt == 7) && !(c == 3 && ktl == 1 && nt == 7)) {
          size_t nb = (nktl <= 1)
                          ? ((size_t)((c * 2 + nktl) * 8 + nnt) * 64 + lane) * 16
                          : ((size_t)(((c + 1) & 3) * 2 * 8 + 0) * 64 + lane) * 16;
          c2h = *(const short8*)(W2f + nb);
          c2l = *(const short8*)(W2f + nb + 8);
        }
#pragma unroll
        for (int mi = 0; mi < 2; ++mi) {
          oacc[nt][mi] = __builtin_amdgcn_mfma_f32_16x16x32_bf16(wh, bh[mi], oacc[nt][mi], 0, 0, 0);
          oacc[nt][mi] = __builtin_amdgcn_mfma_f32_16x16x32_bf16(wh, bl[mi], oacc[nt][mi], 0, 0, 0);
          oacc[nt][mi] = __builtin_amdgcn_mfma_f32_16x16x32_bf16(wl, bh[mi], oacc[nt][mi], 0, 0, 0);
        }
      }
    }
  }

  // ---- epilogue: +b2, float4 store, BN partials into slot ----
#pragma unroll
  for (int nt = 0; nt < 8; ++nt) {
    int ocb = nt * 16 + q * 4;  // 4 consecutive out cols per lane
    float4 b2v = ld4(b2g + ocb);
    float bb[4] = {b2v.x, b2v.y, b2v.z, b2v.w};
    f32x4 s = (f32x4){0.f, 0.f, 0.f, 0.f};
    f32x4 s2 = (f32x4){0.f, 0.f, 0.f, 0.f};
#pragma unroll
    for (int mi = 0; mi < 2; ++mi) {
      int node = n0 + mi * 16 + l15;
      if (node < NN) {
        float4 v;
        v.x = oacc[nt][mi][0] + bb[0];
        v.y = oacc[nt][mi][1] + bb[1];
        v.z = oacc[nt][mi][2] + bb[2];
        v.w = oacc[nt][mi][3] + bb[3];
        *(float4*)(hpre + (size_t)node * EMB + ocb) = v;
        s[0] += v.x; s[1] += v.y; s[2] += v.z; s[3] += v.w;
        s2[0] += v.x * v.x; s2[1] += v.y * v.y; s2[2] += v.z * v.z; s2[3] += v.w * v.w;
      }
    }
#pragma unroll
    for (int d = 1; d < 16; d <<= 1) {
#pragma unroll
      for (int r = 0; r < 4; ++r) {
        s[r] += __shfl_xor(s[r], d);
        s2[r] += __shfl_xor(s2[r], d);
      }
    }
    if (l15 == 0) {
#pragma unroll
      for (int r = 0; r < 4; ++r) {
        atomicAdd(&sums[ocb + r], s[r]);
        atomicAdd(&sums[128 + ocb + r], s2[r]);
      }
    }
  }
}

// ---------------- reduce 32 BN slots -> sums[256] ----------------
__global__ void sums_reduce_kernel(const float* __restrict__ slots,
                                   float* __restrict__ sums) {
  int f = threadIdx.x;  // 256
  float s = 0.f;
#pragma unroll 8
  for (int k = 0; k < 32; ++k) s += slots[k * 256 + f];
  sums[f] = s;
}

// ---------------- BN apply (stats recomputed inline from sums; L2-hot) ----------------
template <bool LAST>
__global__ __launch_bounds__(256) void bn_apply_kernel(
    const float* __restrict__ hp, const float* __restrict__ sums,
    const float* __restrict__ gamma, const float* __restrict__ beta,
    float* __restrict__ hf, u16* __restrict__ hb, float* __restrict__ out) {
  int tid = blockIdx.x * blockDim.x + threadIdx.x;
  int n = tid >> 4;
  if (n >= NN) return;
  int kc = tid & 15;
  const float* p = hp + (size_t)n * EMB + kc * 8;
  float4 va = ld4(p), vb = ld4(p + 4);
  float v[8] = {va.x, va.y, va.z, va.w, vb.x, vb.y, vb.z, vb.w};
  float4 sa = ld4(sums + kc * 8), sb = ld4(sums + kc * 8 + 4);
  float4 qa = ld4(sums + 128 + kc * 8), qb = ld4(sums + 128 + kc * 8 + 4);
  float4 ga = ld4(gamma + kc * 8), gb = ld4(gamma + kc * 8 + 4);
  float4 ba = ld4(beta + kc * 8), bb = ld4(beta + kc * 8 + 4);
  float sm[8] = {sa.x, sa.y, sa.z, sa.w, sb.x, sb.y, sb.z, sb.w};
  float sq[8] = {qa.x, qa.y, qa.z, qa.w, qb.x, qb.y, qb.z, qb.w};
  float gm[8] = {ga.x, ga.y, ga.z, ga.w, gb.x, gb.y, gb.z, gb.w};
  float bt[8] = {ba.x, ba.y, ba.z, ba.w, bb.x, bb.y, bb.z, bb.w};
#pragma unroll
  for (int j = 0; j < 8; ++j) {
    float mean = sm[j] * (1.0f / NN);
    float var = sq[j] * (1.0f / NN) - mean * mean;  // biased
    float sc = gm[j] * rsqrtf(var + 1e-5f);
    v[j] = (v[j] - mean) * sc + bt[j];
  }
  if (LAST) {
    float* d = out + (size_t)n * EMB + kc * 8;
    *(float4*)d = make_float4(v[0], v[1], v[2], v[3]);
    *(float4*)(d + 4) = make_float4(v[4], v[5], v[6], v[7]);
  } else {
#pragma unroll
    for (int j = 0; j < 8; ++j) v[j] = fmaxf(v[j], 0.f);
    float* df = hf + (size_t)n * EMB + kc * 8;
    *(float4*)df = make_float4(v[0], v[1], v[2], v[3]);
    *(float4*)(df + 4) = make_float4(v[4], v[5], v[6], v[7]);
    u16 o[8];
#pragma unroll
    for (int j = 0; j < 8; ++j) o[j] = f2bf(v[j]);
    *(ulonglong2*)(hb + (size_t)n * EMB + kc * 8) = *(ulonglong2*)o;
  }
}

// ---------------- launch ----------------
extern "C" void kernel_launch(void* const* d_in, const int* in_sizes, int n_in,
                              void* d_out, int out_size, void* d_ws, size_t ws_size,
                              hipStream_t stream) {
  const int* x = (const int*)d_in[0];
  const int* ei = (const int*)d_in[1];
  const int* ea = (const int*)d_in[2];
  const float* x_emb1 = (const float*)d_in[3];
  const float* x_emb2 = (const float*)d_in[4];
  const float* ee1 = (const float*)d_in[5];
  const float* ee2 = (const float*)d_in[6];
  const float* W1 = (const float*)d_in[7];
  const float* b1 = (const float*)d_in[8];
  const float* W2 = (const float*)d_in[9];
  const float* b2 = (const float*)d_in[10];
  const float* eps = (const float*)d_in[11];
  const float* gamma = (const float*)d_in[12];
  const float* beta = (const float*)d_in[13];
  float* out = (float*)d_out;

  // workspace layout (16B-aligned sections)
  float* hpre = (float*)d_ws;                   // NN*128 f32
  float* hf = hpre + (size_t)NN * EMB;          // NN*128 f32
  float* slots = hf + (size_t)NN * EMB;         // 5*32*256 BN partial slots
  float* sums = slots + 5 * 32 * 256;           // 5*256 reduced
  float* combos = sums + 5 * 256;               // 9600
  u16* Af = (u16*)(combos + 9600);              // NPAD*256 bf16 (hi/lo interleaved)
  u16* hb = Af + (size_t)NPAD * 256;            // NN*128 bf16
  u16* W1f = hb + (size_t)NN * EMB;             // 5*65536 (interleaved pairs)
  u16* W2f = W1f + 5 * 65536;                   // 5*65536
  int* deg = (int*)(W2f + 5 * 65536);           // NN
  int* off = deg + NN;                          // NN+1
  int* csr = off + NN + 1;                      // NE
  int* bsum = csr + NE;                         // 128

  const int NB_SCAN = (NN + 1023) / 1024;

  // one-time per launch: CSR + combo tables + frag-ordered split-bf16 weights
  hipMemsetAsync(deg, 0, NN * sizeof(int), stream);
  hipMemsetAsync(slots, 0, 5 * 32 * 256 * sizeof(float), stream);
  hist_kernel<<<(NE + 255) / 256, 256, 0, stream>>>(ei, deg);
  scan1_kernel<<<NB_SCAN, 256, 0, stream>>>(deg, off, bsum);
  scan2_kernel<<<1, 64, 0, stream>>>(bsum, off, NB_SCAN);
  scan3_kernel<<<(NN + 255) / 256, 256, 0, stream>>>(off, bsum);
  hipMemsetAsync(deg, 0, NN * sizeof(int), stream);
  scatter_kernel<<<(NE + 255) / 256, 256, 0, stream>>>(ei, ea, off, deg, csr);
  combo_kernel<<<(5 * 15 * 128 + 255) / 256, 256, 0, stream>>>(ee1, ee2, combos);
  prep_w_kernel<<<160, 256, 0, stream>>>(W1, W2, W1f, W2f);
  node_init_kernel<<<NN * 16 / 256 + 1, 256, 0, stream>>>(x, x_emb1, x_emb2, hf, hb);

  const int NBLK = NPAD / 128;  // 782 blocks x 4 independent waves (32 nodes each)
  for (int i = 0; i < 5; ++i) {
    agg_kernel<<<NPAD * 16 / 256, 256, 0, stream>>>(
        hf, hb, off, csr, combos + (size_t)i * 15 * EMB, eps + i, Af);
    mlp_kernel<<<NBLK, 256, 0, stream>>>(
        Af, W1f + (size_t)i * 65536, W2f + (size_t)i * 65536,
        b1 + (size_t)i * 256, b2 + (size_t)i * 128, hpre,
        slots + (size_t)i * 32 * 256);
    sums_reduce_kernel<<<1, 256, 0, stream>>>(slots + (size_t)i * 32 * 256,
                                              sums + (size_t)i * 256);
    if (i < 4)
      bn_apply_kernel<false><<<NN * 16 / 256 + 1, 256, 0, stream>>>(
          hpre, sums + (size_t)i * 256, gamma + (size_t)i * EMB, beta + (size_t)i * EMB,
          hf, hb, nullptr);
    else
      bn_apply_kernel<true><<<NN * 16 / 256 + 1, 256, 0, stream>>>(
          hpre, sums + (size_t)i * 256, gamma + (size_t)i * EMB, beta + (size_t)i * EMB,
          nullptr, nullptr, out);
  }
}

// Round 9
// 1038.560 us; speedup vs baseline: 1.6814x; 1.0039x over previous
//
#include <hip/hip_runtime.h>

#define NN 100000
#define NPAD 100096   // 3128 * 32, padded row count for guard-free GEMM
#define NE 600000
#define EMB 128

typedef unsigned short u16;
typedef unsigned int u32;
typedef unsigned long long u64;
typedef short short8 __attribute__((ext_vector_type(8)));
typedef float f32x4 __attribute__((ext_vector_type(4)));

__device__ __forceinline__ float4 ld4(const float* p) { return *(const float4*)p; }
__device__ __forceinline__ u16 f2bf(float x) {  // RTNE f32 -> bf16
  u32 u = __float_as_uint(x);
  u += 0x7FFFu + ((u >> 16) & 1u);
  return (u16)(u >> 16);
}
__device__ __forceinline__ float bf2f(u16 h) { return __uint_as_float(((u32)h) << 16); }

// ---------------- node embedding init: hf(f32) + hb(bf16) = emb1[x0] + emb2[x1] ----------------
__global__ __launch_bounds__(256) void node_init_kernel(
    const int* __restrict__ x, const float* __restrict__ emb1,
    const float* __restrict__ emb2, float* __restrict__ hf, u16* __restrict__ hb) {
  int tid = blockIdx.x * blockDim.x + threadIdx.x;
  int n = tid >> 4;
  if (n >= NN) return;
  int kc = tid & 15;
  int x0 = min(max(x[2 * n], 0), 118);
  int x1 = min(max(x[2 * n + 1], 0), 2);  // x[:,1] sampled 0..118 -> clip to NUM_CHIR-1
  const float* p1 = emb1 + (size_t)x0 * EMB + kc * 8;
  const float* p2 = emb2 + (size_t)x1 * EMB + kc * 8;
  float v[8];
#pragma unroll
  for (int j = 0; j < 8; ++j) v[j] = p1[j] + p2[j];
  float* df = hf + (size_t)n * EMB + kc * 8;
  *(float4*)df = make_float4(v[0], v[1], v[2], v[3]);
  *(float4*)(df + 4) = make_float4(v[4], v[5], v[6], v[7]);
  u16 o[8];
#pragma unroll
  for (int j = 0; j < 8; ++j) o[j] = f2bf(v[j]);
  *(ulonglong2*)(hb + (size_t)n * EMB + kc * 8) = *(ulonglong2*)o;
}

// ---------------- CSR build ----------------
__global__ __launch_bounds__(256) void hist_kernel(const int* __restrict__ ei,
                                                   int* __restrict__ deg) {
  int e = blockIdx.x * blockDim.x + threadIdx.x;
  if (e >= NE) return;
  atomicAdd(&deg[ei[NE + e]], 1);
}

__global__ __launch_bounds__(256) void scan1_kernel(const int* __restrict__ deg,
                                                    int* __restrict__ off,
                                                    int* __restrict__ bsum) {
  __shared__ int s[256];
  int t = threadIdx.x;
  int base = blockIdx.x * 1024 + t * 4;
  int v[4];
#pragma unroll
  for (int j = 0; j < 4; ++j) {
    int idx = base + j;
    v[j] = (idx < NN) ? deg[idx] : 0;
  }
  int tsum = v[0] + v[1] + v[2] + v[3];
  s[t] = tsum;
  __syncthreads();
  for (int d = 1; d < 256; d <<= 1) {
    int add = (t >= d) ? s[t - d] : 0;
    __syncthreads();
    s[t] += add;
    __syncthreads();
  }
  int run = s[t] - tsum;
#pragma unroll
  for (int j = 0; j < 4; ++j) {
    int idx = base + j;
    if (idx < NN) off[idx] = run;
    run += v[j];
  }
  if (t == 255) bsum[blockIdx.x] = s[255];
}

__global__ void scan2_kernel(int* __restrict__ bsum, int* __restrict__ off, int nb) {
  if (threadIdx.x == 0) {
    int run = 0;
    for (int b = 0; b < nb; ++b) {
      int v = bsum[b];
      bsum[b] = run;
      run += v;
    }
    off[NN] = run;
  }
}

__global__ __launch_bounds__(256) void scan3_kernel(int* __restrict__ off,
                                                    const int* __restrict__ bsum) {
  int idx = blockIdx.x * blockDim.x + threadIdx.x;
  if (idx < NN) off[idx] += bsum[idx >> 10];
}

__global__ __launch_bounds__(256) void scatter_kernel(
    const int* __restrict__ ei, const int* __restrict__ ea,
    const int* __restrict__ off, int* __restrict__ cnt, int* __restrict__ csr) {
  int e = blockIdx.x * blockDim.x + threadIdx.x;
  if (e >= NE) return;
  int d = ei[NE + e];
  int s = ei[e];
  int a0 = min(max(ea[2 * e], 0), 4);
  int a1 = min(max(ea[2 * e + 1], 0), 2);
  int code = a0 * 3 + a1;  // [0,14]
  int r = atomicAdd(&cnt[d], 1);
  csr[off[d] + r] = s | (code << 20);
}

// combos[l][code][f] = ee1[l][code/3][f] + ee2[l][code%3][f]
__global__ __launch_bounds__(256) void combo_kernel(const float* __restrict__ ee1,
                                                    const float* __restrict__ ee2,
                                                    float* __restrict__ combos) {
  int idx = blockIdx.x * blockDim.x + threadIdx.x;
  if (idx >= 5 * 15 * 128) return;
  int l = idx / (15 * 128);
  int rem = idx % (15 * 128);
  int code = rem / 128;
  int f = rem % 128;
  combos[idx] = ee1[(l * 5 + code / 3) * 128 + f] + ee2[(l * 3 + code % 3) * 128 + f];
}

// ---------------- weight prep: frag-ordered split-bf16, hi/lo INTERLEAVED 32B pairs ----------------
// Frag-pair f at (f*64+lane)*16: [0..7]=hi, [8..15]=lo.
__global__ __launch_bounds__(256) void prep_w_kernel(
    const float* __restrict__ W1g, const float* __restrict__ W2g,
    u16* __restrict__ W1f, u16* __restrict__ W2f) {
  int idx = blockIdx.x * blockDim.x + threadIdx.x;
  if (idx >= 40960) return;
  u16 oh[8], ol[8];
  if (idx < 20480) {
    int lane = idx & 63;
    int r = idx >> 6;             // l*64 + c*16 + kt*4 + colt
    int nt = r & 3, kt = (r >> 2) & 3, c = (r >> 4) & 3, l = r >> 6;
    int n = c * 64 + nt * 16 + (lane & 15);
    int kb = kt * 32 + (lane >> 4) * 8;
#pragma unroll
    for (int j = 0; j < 8; ++j) {
      float w = W1g[((size_t)l * 128 + kb + j) * 256 + n];
      oh[j] = f2bf(w);
      ol[j] = f2bf(w - bf2f(oh[j]));
    }
    *(ulonglong2*)(W1f + (size_t)idx * 16) = *(ulonglong2*)oh;
    *(ulonglong2*)(W1f + (size_t)idx * 16 + 8) = *(ulonglong2*)ol;
  } else {
    int i2 = idx - 20480;
    int lane = i2 & 63;
    int r = i2 >> 6;              // l*64 + c*16 + ktl*8 + nt
    int nt = r & 7, ktl = (r >> 3) & 1, c = (r >> 4) & 3, l = r >> 6;
    int n = nt * 16 + (lane & 15);
    int kb = c * 64 + ktl * 32 + (lane >> 4) * 8;
#pragma unroll
    for (int j = 0; j < 8; ++j) {
      float w = W2g[((size_t)l * 256 + kb + j) * 128 + n];
      oh[j] = f2bf(w);
      ol[j] = f2bf(w - bf2f(oh[j]));
    }
    *(ulonglong2*)(W2f + (size_t)i2 * 16) = *(ulonglong2*)oh;
    *(ulonglong2*)(W2f + (size_t)i2 * 16 + 8) = *(ulonglong2*)ol;
  }
}

// ---------------- agg: A = (1+eps)*hf + relu(hf+c0) + sum relu(hb[src]+c) ----------------
// Output Af interleaved: node*256 + kc*16: [0..7]=hi, [8..15]=lo (32B contiguous).
__global__ __launch_bounds__(256) void agg_kernel(
    const float* __restrict__ hf, const u16* __restrict__ hb,
    const int* __restrict__ off, const int* __restrict__ csr,
    const float* __restrict__ cb, const float* __restrict__ epsp,
    u16* __restrict__ Af) {
  int tid = blockIdx.x * blockDim.x + threadIdx.x;
  int g = tid >> 4;
  int kc = tid & 15;
  float av[8] = {0.f, 0.f, 0.f, 0.f, 0.f, 0.f, 0.f, 0.f};
  if (g < NN) {
    const float eps1 = 1.0f + *epsp;
    const float* hp = hf + (size_t)g * EMB + kc * 8;
    float4 va = ld4(hp), vb = ld4(hp + 4);
    float hv[8] = {va.x, va.y, va.z, va.w, vb.x, vb.y, vb.z, vb.w};
    float4 ca = ld4(cb + kc * 8), cbv = ld4(cb + kc * 8 + 4);
    float cs[8] = {ca.x, ca.y, ca.z, ca.w, cbv.x, cbv.y, cbv.z, cbv.w};
#pragma unroll
    for (int j = 0; j < 8; ++j) av[j] = eps1 * hv[j] + fmaxf(hv[j] + cs[j], 0.f);
    int s0 = off[g], s1 = off[g + 1];
    int e = s0;
    for (; e + 1 < s1; e += 2) {  // unroll x2: two independent gather chains in flight
      int p0 = csr[e], p1 = csr[e + 1];
      ulonglong2 r0 = *(const ulonglong2*)(hb + (size_t)(p0 & 0xFFFFF) * EMB + kc * 8);
      ulonglong2 r1 = *(const ulonglong2*)(hb + (size_t)(p1 & 0xFFFFF) * EMB + kc * 8);
      const float* c0p = cb + (size_t)(p0 >> 20) * EMB + kc * 8;
      const float* c1p = cb + (size_t)(p1 >> 20) * EMB + kc * 8;
      float4 c0a = ld4(c0p), c0b = ld4(c0p + 4);
      float4 c1a = ld4(c1p), c1b = ld4(c1p + 4);
      float cc0[8] = {c0a.x, c0a.y, c0a.z, c0a.w, c0b.x, c0b.y, c0b.z, c0b.w};
      float cc1[8] = {c1a.x, c1a.y, c1a.z, c1a.w, c1b.x, c1b.y, c1b.z, c1b.w};
      u16* s0p = (u16*)&r0;
      u16* s1p = (u16*)&r1;
#pragma unroll
      for (int j = 0; j < 8; ++j) {
        av[j] += fmaxf(bf2f(s0p[j]) + cc0[j], 0.f);
        av[j] += fmaxf(bf2f(s1p[j]) + cc1[j], 0.f);
      }
    }
    if (e < s1) {
      int p0 = csr[e];
      ulonglong2 r0 = *(const ulonglong2*)(hb + (size_t)(p0 & 0xFFFFF) * EMB + kc * 8);
      const float* c0p = cb + (size_t)(p0 >> 20) * EMB + kc * 8;
      float4 c0a = ld4(c0p), c0b = ld4(c0p + 4);
      float cc0[8] = {c0a.x, c0a.y, c0a.z, c0a.w, c0b.x, c0b.y, c0b.z, c0b.w};
      u16* s0p = (u16*)&r0;
#pragma unroll
      for (int j = 0; j < 8; ++j) av[j] += fmaxf(bf2f(s0p[j]) + cc0[j], 0.f);
    }
  }
  u16 oh[8], ol[8];
#pragma unroll
  for (int j = 0; j < 8; ++j) {
    oh[j] = f2bf(av[j]);
    ol[j] = f2bf(av[j] - bf2f(oh[j]));
  }
  u16* d = Af + (size_t)g * 256 + kc * 16;
  *(ulonglong2*)d = *(ulonglong2*)oh;        // zeros for pad rows
  *(ulonglong2*)(d + 8) = *(ulonglong2*)ol;
}

// ---------------- mlp: block-shared W via LDS (staged per chunk), 32 nodes/wave ----------------
// LDS: Wh/Wl hi-lo planes, 16 frag-pairs x 64 lanes x 16B, lane stride 16B -> conflict-free.
__global__ __launch_bounds__(256) void mlp_kernel(
    const u16* __restrict__ Af, const u16* __restrict__ W1f,
    const u16* __restrict__ W2f,
    const float* __restrict__ b1g, const float* __restrict__ b2g,
    float* __restrict__ hpre, float* __restrict__ slots) {
  __shared__ __align__(16) u16 Wh[16 * 64 * 8];  // 16KB hi plane
  __shared__ __align__(16) u16 Wl[16 * 64 * 8];  // 16KB lo plane

  const int t = threadIdx.x;
  const int w = t >> 6;
  const int lane = t & 63;
  const int q = lane >> 4, l15 = lane & 15;
  const int gw = blockIdx.x * 4 + w;   // global wave id, 0..3127
  const int n0 = gw * 32;              // 32 nodes per wave
  float* sums = slots + (size_t)(gw & 31) * 256;

  f32x4 oacc[8][2];  // [out col tile][node tile]
#pragma unroll
  for (int a = 0; a < 8; ++a)
#pragma unroll
    for (int b = 0; b < 2; ++b) oacc[a][b] = (f32x4){0.f, 0.f, 0.f, 0.f};

  const int srcA = ((q & 1) * 2) * 16 + l15;  // quad permutation sources
  const int srcB = srcA + 16;
  const bool sel = (q >> 1) != 0;

  for (int c = 0; c < 4; ++c) {
    __syncthreads();  // prev chunk's stage-2 LDS reads complete
    // ---- stage W1 chunk c into LDS (wave w covers frag-pairs w*4..w*4+3) ----
    {
      const u16* gb = W1f + ((size_t)(c * 16 + w * 4) * 64 + lane) * 16;
#pragma unroll
      for (int j = 0; j < 4; ++j) {
        ulonglong2 hi = *(const ulonglong2*)(gb + (size_t)j * 1024);
        ulonglong2 lo = *(const ulonglong2*)(gb + (size_t)j * 1024 + 8);
        *(ulonglong2*)&Wh[(w * 4 + j) * 512 + lane * 8] = hi;
        *(ulonglong2*)&Wl[(w * 4 + j) * 512 + lane * 8] = lo;
      }
    }
    __syncthreads();

    // ---- stage 1: hmidT[col c*64+colt*16+q*4+r][node l15] ----
    f32x4 hacc[4][2];  // [colt][mi]
#pragma unroll
    for (int a = 0; a < 4; ++a)
#pragma unroll
      for (int b = 0; b < 2; ++b) hacc[a][b] = (f32x4){0.f, 0.f, 0.f, 0.f};
#pragma unroll
    for (int kt = 0; kt < 4; ++kt) {
      short8 nh[2], nl[2];
#pragma unroll
      for (int mi = 0; mi < 2; ++mi) {
        const u16* p = Af + (size_t)(n0 + mi * 16 + l15) * 256 + kt * 64 + q * 16;
        nh[mi] = *(const short8*)p;
        nl[mi] = *(const short8*)(p + 8);
      }
#pragma unroll
      for (int colt = 0; colt < 4; ++colt) {
        int pp = (kt * 4 + colt) * 512 + lane * 8;
        short8 wh = *(const short8*)&Wh[pp];
        short8 wl = *(const short8*)&Wl[pp];
#pragma unroll
        for (int mi = 0; mi < 2; ++mi) {
          hacc[colt][mi] = __builtin_amdgcn_mfma_f32_16x16x32_bf16(wh, nh[mi], hacc[colt][mi], 0, 0, 0);
          hacc[colt][mi] = __builtin_amdgcn_mfma_f32_16x16x32_bf16(wh, nl[mi], hacc[colt][mi], 0, 0, 0);
          hacc[colt][mi] = __builtin_amdgcn_mfma_f32_16x16x32_bf16(wl, nh[mi], hacc[colt][mi], 0, 0, 0);
        }
      }
    }
    __syncthreads();  // stage-1 LDS reads complete; buffer reusable

    // ---- stage W2 chunk c into LDS ----
    {
      const u16* gb = W2f + ((size_t)(c * 16 + w * 4) * 64 + lane) * 16;
#pragma unroll
      for (int j = 0; j < 4; ++j) {
        ulonglong2 hi = *(const ulonglong2*)(gb + (size_t)j * 1024);
        ulonglong2 lo = *(const ulonglong2*)(gb + (size_t)j * 1024 + 8);
        *(ulonglong2*)&Wh[(w * 4 + j) * 512 + lane * 8] = hi;
        *(ulonglong2*)&Wl[(w * 4 + j) * 512 + lane * 8] = lo;
      }
    }

    // ---- bias + relu + split + pack (2 bf16/dword, k-ascending); overlaps staging ----
    u32 P01h[4][2], P23h[4][2], P01l[4][2], P23l[4][2];  // [colt][mi]
#pragma unroll
    for (int colt = 0; colt < 4; ++colt) {
      float4 b1v = ld4(b1g + c * 64 + colt * 16 + q * 4);
      float bb[4] = {b1v.x, b1v.y, b1v.z, b1v.w};
#pragma unroll
      for (int mi = 0; mi < 2; ++mi) {
        u16 hi[4], lo[4];
#pragma unroll
        for (int r = 0; r < 4; ++r) {
          float v = fmaxf(hacc[colt][mi][r] + bb[r], 0.f);
          hi[r] = f2bf(v);
          lo[r] = f2bf(v - bf2f(hi[r]));
        }
        P01h[colt][mi] = (u32)hi[0] | ((u32)hi[1] << 16);
        P23h[colt][mi] = (u32)hi[2] | ((u32)hi[3] << 16);
        P01l[colt][mi] = (u32)lo[0] | ((u32)lo[1] << 16);
        P23l[colt][mi] = (u32)lo[2] | ((u32)lo[3] << 16);
      }
    }
    __syncthreads();  // W2 staged

    // ---- stage 2: quad-permute hmid into B-frags, multiply with W2 from LDS ----
#pragma unroll
    for (int ktl = 0; ktl < 2; ++ktl) {
      short8 bh[2], bl[2];
#pragma unroll
      for (int mi = 0; mi < 2; ++mi) {
        union { u32 d[4]; short8 s; } uh, ul;
        int c0 = 2 * ktl, c1 = 2 * ktl + 1;
        u32 a0, a1;
        a0 = (u32)__shfl((int)P01h[c0][mi], srcA); a1 = (u32)__shfl((int)P01h[c1][mi], srcA);
        uh.d[0] = sel ? a1 : a0;
        a0 = (u32)__shfl((int)P23h[c0][mi], srcA); a1 = (u32)__shfl((int)P23h[c1][mi], srcA);
        uh.d[1] = sel ? a1 : a0;
        a0 = (u32)__shfl((int)P01h[c0][mi], srcB); a1 = (u32)__shfl((int)P01h[c1][mi], srcB);
        uh.d[2] = sel ? a1 : a0;
        a0 = (u32)__shfl((int)P23h[c0][mi], srcB); a1 = (u32)__shfl((int)P23h[c1][mi], srcB);
        uh.d[3] = sel ? a1 : a0;
        a0 = (u32)__shfl((int)P01l[c0][mi], srcA); a1 = (u32)__shfl((int)P01l[c1][mi], srcA);
        ul.d[0] = sel ? a1 : a0;
        a0 = (u32)__shfl((int)P23l[c0][mi], srcA); a1 = (u32)__shfl((int)P23l[c1][mi], srcA);
        ul.d[1] = sel ? a1 : a0;
        a0 = (u32)__shfl((int)P01l[c0][mi], srcB); a1 = (u32)__shfl((int)P01l[c1][mi], srcB);
        ul.d[2] = sel ? a1 : a0;
        a0 = (u32)__shfl((int)P23l[c0][mi], srcB); a1 = (u32)__shfl((int)P23l[c1][mi], srcB);
        ul.d[3] = sel ? a1 : a0;
        bh[mi] = uh.s;
        bl[mi] = ul.s;
      }
#pragma unroll
      for (int nt = 0; nt < 8; ++nt) {
        int pp = (ktl * 8 + nt) * 512 + lane * 8;
        short8 wh = *(const short8*)&Wh[pp];
        short8 wl = *(const short8*)&Wl[pp];
#pragma unroll
        for (int mi = 0; mi < 2; ++mi) {
          oacc[nt][mi] = __builtin_amdgcn_mfma_f32_16x16x32_bf16(wh, bh[mi], oacc[nt][mi], 0, 0, 0);
          oacc[nt][mi] = __builtin_amdgcn_mfma_f32_16x16x32_bf16(wh, bl[mi], oacc[nt][mi], 0, 0, 0);
          oacc[nt][mi] = __builtin_amdgcn_mfma_f32_16x16x32_bf16(wl, bh[mi], oacc[nt][mi], 0, 0, 0);
        }
      }
    }
  }

  // ---- epilogue: +b2, float4 store, BN partials into slot ----
#pragma unroll
  for (int nt = 0; nt < 8; ++nt) {
    int ocb = nt * 16 + q * 4;  // 4 consecutive out cols per lane
    float4 b2v = ld4(b2g + ocb);
    float bb[4] = {b2v.x, b2v.y, b2v.z, b2v.w};
    f32x4 s = (f32x4){0.f, 0.f, 0.f, 0.f};
    f32x4 s2 = (f32x4){0.f, 0.f, 0.f, 0.f};
#pragma unroll
    for (int mi = 0; mi < 2; ++mi) {
      int node = n0 + mi * 16 + l15;
      if (node < NN) {
        float4 v;
        v.x = oacc[nt][mi][0] + bb[0];
        v.y = oacc[nt][mi][1] + bb[1];
        v.z = oacc[nt][mi][2] + bb[2];
        v.w = oacc[nt][mi][3] + bb[3];
        *(float4*)(hpre + (size_t)node * EMB + ocb) = v;
        s[0] += v.x; s[1] += v.y; s[2] += v.z; s[3] += v.w;
        s2[0] += v.x * v.x; s2[1] += v.y * v.y; s2[2] += v.z * v.z; s2[3] += v.w * v.w;
      }
    }
#pragma unroll
    for (int d = 1; d < 16; d <<= 1) {
#pragma unroll
      for (int r = 0; r < 4; ++r) {
        s[r] += __shfl_xor(s[r], d);
        s2[r] += __shfl_xor(s2[r], d);
      }
    }
    if (l15 == 0) {
#pragma unroll
      for (int r = 0; r < 4; ++r) {
        atomicAdd(&sums[ocb + r], s[r]);
        atomicAdd(&sums[128 + ocb + r], s2[r]);
      }
    }
  }
}

// ---------------- reduce 32 BN slots -> sums[256] ----------------
__global__ void sums_reduce_kernel(const float* __restrict__ slots,
                                   float* __restrict__ sums) {
  int f = threadIdx.x;  // 256
  float s = 0.f;
#pragma unroll 8
  for (int k = 0; k < 32; ++k) s += slots[k * 256 + f];
  sums[f] = s;
}

// ---------------- BN apply (stats recomputed inline from sums; L2-hot) ----------------
template <bool LAST>
__global__ __launch_bounds__(256) void bn_apply_kernel(
    const float* __restrict__ hp, const float* __restrict__ sums,
    const float* __restrict__ gamma, const float* __restrict__ beta,
    float* __restrict__ hf, u16* __restrict__ hb, float* __restrict__ out) {
  int tid = blockIdx.x * blockDim.x + threadIdx.x;
  int n = tid >> 4;
  if (n >= NN) return;
  int kc = tid & 15;
  const float* p = hp + (size_t)n * EMB + kc * 8;
  float4 va = ld4(p), vb = ld4(p + 4);
  float v[8] = {va.x, va.y, va.z, va.w, vb.x, vb.y, vb.z, vb.w};
  float4 sa = ld4(sums + kc * 8), sb = ld4(sums + kc * 8 + 4);
  float4 qa = ld4(sums + 128 + kc * 8), qb = ld4(sums + 128 + kc * 8 + 4);
  float4 ga = ld4(gamma + kc * 8), gb = ld4(gamma + kc * 8 + 4);
  float4 ba = ld4(beta + kc * 8), bb = ld4(beta + kc * 8 + 4);
  float sm[8] = {sa.x, sa.y, sa.z, sa.w, sb.x, sb.y, sb.z, sb.w};
  float sq[8] = {qa.x, qa.y, qa.z, qa.w, qb.x, qb.y, qb.z, qb.w};
  float gm[8] = {ga.x, ga.y, ga.z, ga.w, gb.x, gb.y, gb.z, gb.w};
  float bt[8] = {ba.x, ba.y, ba.z, ba.w, bb.x, bb.y, bb.z, bb.w};
#pragma unroll
  for (int j = 0; j < 8; ++j) {
    float mean = sm[j] * (1.0f / NN);
    float var = sq[j] * (1.0f / NN) - mean * mean;  // biased
    float sc = gm[j] * rsqrtf(var + 1e-5f);
    v[j] = (v[j] - mean) * sc + bt[j];
  }
  if (LAST) {
    float* d = out + (size_t)n * EMB + kc * 8;
    *(float4*)d = make_float4(v[0], v[1], v[2], v[3]);
    *(float4*)(d + 4) = make_float4(v[4], v[5], v[6], v[7]);
  } else {
#pragma unroll
    for (int j = 0; j < 8; ++j) v[j] = fmaxf(v[j], 0.f);
    float* df = hf + (size_t)n * EMB + kc * 8;
    *(float4*)df = make_float4(v[0], v[1], v[2], v[3]);
    *(float4*)(df + 4) = make_float4(v[4], v[5], v[6], v[7]);
    u16 o[8];
#pragma unroll
    for (int j = 0; j < 8; ++j) o[j] = f2bf(v[j]);
    *(ulonglong2*)(hb + (size_t)n * EMB + kc * 8) = *(ulonglong2*)o;
  }
}

// ---------------- launch ----------------
extern "C" void kernel_launch(void* const* d_in, const int* in_sizes, int n_in,
                              void* d_out, int out_size, void* d_ws, size_t ws_size,
                              hipStream_t stream) {
  const int* x = (const int*)d_in[0];
  const int* ei = (const int*)d_in[1];
  const int* ea = (const int*)d_in[2];
  const float* x_emb1 = (const float*)d_in[3];
  const float* x_emb2 = (const float*)d_in[4];
  const float* ee1 = (const float*)d_in[5];
  const float* ee2 = (const float*)d_in[6];
  const float* W1 = (const float*)d_in[7];
  const float* b1 = (const float*)d_in[8];
  const float* W2 = (const float*)d_in[9];
  const float* b2 = (const float*)d_in[10];
  const float* eps = (const float*)d_in[11];
  const float* gamma = (const float*)d_in[12];
  const float* beta = (const float*)d_in[13];
  float* out = (float*)d_out;

  // workspace layout (16B-aligned sections)
  float* hpre = (float*)d_ws;                   // NN*128 f32
  float* hf = hpre + (size_t)NN * EMB;          // NN*128 f32
  float* slots = hf + (size_t)NN * EMB;         // 5*32*256 BN partial slots
  float* sums = slots + 5 * 32 * 256;           // 5*256 reduced
  float* combos = sums + 5 * 256;               // 9600
  u16* Af = (u16*)(combos + 9600);              // NPAD*256 bf16 (hi/lo interleaved)
  u16* hb = Af + (size_t)NPAD * 256;            // NN*128 bf16
  u16* W1f = hb + (size_t)NN * EMB;             // 5*65536 (interleaved pairs)
  u16* W2f = W1f + 5 * 65536;                   // 5*65536
  int* deg = (int*)(W2f + 5 * 65536);           // NN
  int* off = deg + NN;                          // NN+1
  int* csr = off + NN + 1;                      // NE
  int* bsum = csr + NE;                         // 128

  const int NB_SCAN = (NN + 1023) / 1024;

  // one-time per launch: CSR + combo tables + frag-ordered split-bf16 weights
  hipMemsetAsync(deg, 0, NN * sizeof(int), stream);
  hipMemsetAsync(slots, 0, 5 * 32 * 256 * sizeof(float), stream);
  hist_kernel<<<(NE + 255) / 256, 256, 0, stream>>>(ei, deg);
  scan1_kernel<<<NB_SCAN, 256, 0, stream>>>(deg, off, bsum);
  scan2_kernel<<<1, 64, 0, stream>>>(bsum, off, NB_SCAN);
  scan3_kernel<<<(NN + 255) / 256, 256, 0, stream>>>(off, bsum);
  hipMemsetAsync(deg, 0, NN * sizeof(int), stream);
  scatter_kernel<<<(NE + 255) / 256, 256, 0, stream>>>(ei, ea, off, deg, csr);
  combo_kernel<<<(5 * 15 * 128 + 255) / 256, 256, 0, stream>>>(ee1, ee2, combos);
  prep_w_kernel<<<160, 256, 0, stream>>>(W1, W2, W1f, W2f);
  node_init_kernel<<<NN * 16 / 256 + 1, 256, 0, stream>>>(x, x_emb1, x_emb2, hf, hb);

  const int NBLK = NPAD / 128;  // 782 blocks x 4 waves (32 nodes each)
  for (int i = 0; i < 5; ++i) {
    agg_kernel<<<NPAD * 16 / 256, 256, 0, stream>>>(
        hf, hb, off, csr, combos + (size_t)i * 15 * EMB, eps + i, Af);
    mlp_kernel<<<NBLK, 256, 0, stream>>>(
        Af, W1f + (size_t)i * 65536, W2f + (size_t)i * 65536,
        b1 + (size_t)i * 256, b2 + (size_t)i * 128, hpre,
        slots + (size_t)i * 32 * 256);
    sums_reduce_kernel<<<1, 256, 0, stream>>>(slots + (size_t)i * 32 * 256,
                                              sums + (size_t)i * 256);
    if (i < 4)
      bn_apply_kernel<false><<<NN * 16 / 256 + 1, 256, 0, stream>>>(
          hpre, sums + (size_t)i * 256, gamma + (size_t)i * EMB, beta + (size_t)i * EMB,
          hf, hb, nullptr);
    else
      bn_apply_kernel<true><<<NN * 16 / 256 + 1, 256, 0, stream>>>(
          hpre, sums + (size_t)i * 256, gamma + (size_t)i * EMB, beta + (size_t)i * EMB,
          nullptr, nullptr, out);
  }
}

// Round 10
// 950.590 us; speedup vs baseline: 1.8370x; 1.0925x over previous
//
#include <hip/hip_runtime.h>

#define NN 100000
#define NPAD 100096   // 6256 * 16, padded row count for guard-free GEMM
#define NE 600000
#define EMB 128

typedef unsigned short u16;
typedef unsigned int u32;
typedef unsigned long long u64;
typedef short short8 __attribute__((ext_vector_type(8)));
typedef float f32x4 __attribute__((ext_vector_type(4)));

__device__ __forceinline__ float4 ld4(const float* p) { return *(const float4*)p; }
__device__ __forceinline__ u16 f2bf(float x) {  // RTNE f32 -> bf16
  u32 u = __float_as_uint(x);
  u += 0x7FFFu + ((u >> 16) & 1u);
  return (u16)(u >> 16);
}
__device__ __forceinline__ float bf2f(u16 h) { return __uint_as_float(((u32)h) << 16); }

// ---------------- node embedding init: hf(f32) + hb(bf16) = emb1[x0] + emb2[x1] ----------------
__global__ __launch_bounds__(256) void node_init_kernel(
    const int* __restrict__ x, const float* __restrict__ emb1,
    const float* __restrict__ emb2, float* __restrict__ hf, u16* __restrict__ hb) {
  int tid = blockIdx.x * blockDim.x + threadIdx.x;
  int n = tid >> 4;
  if (n >= NN) return;
  int kc = tid & 15;
  int x0 = min(max(x[2 * n], 0), 118);
  int x1 = min(max(x[2 * n + 1], 0), 2);  // x[:,1] sampled 0..118 -> clip to NUM_CHIR-1
  const float* p1 = emb1 + (size_t)x0 * EMB + kc * 8;
  const float* p2 = emb2 + (size_t)x1 * EMB + kc * 8;
  float v[8];
#pragma unroll
  for (int j = 0; j < 8; ++j) v[j] = p1[j] + p2[j];
  float* df = hf + (size_t)n * EMB + kc * 8;
  *(float4*)df = make_float4(v[0], v[1], v[2], v[3]);
  *(float4*)(df + 4) = make_float4(v[4], v[5], v[6], v[7]);
  u16 o[8];
#pragma unroll
  for (int j = 0; j < 8; ++j) o[j] = f2bf(v[j]);
  *(ulonglong2*)(hb + (size_t)n * EMB + kc * 8) = *(ulonglong2*)o;
}

// ---------------- CSR build ----------------
__global__ __launch_bounds__(256) void hist_kernel(const int* __restrict__ ei,
                                                   int* __restrict__ deg) {
  int e = blockIdx.x * blockDim.x + threadIdx.x;
  if (e >= NE) return;
  atomicAdd(&deg[ei[NE + e]], 1);
}

__global__ __launch_bounds__(256) void scan1_kernel(const int* __restrict__ deg,
                                                    int* __restrict__ off,
                                                    int* __restrict__ bsum) {
  __shared__ int s[256];
  int t = threadIdx.x;
  int base = blockIdx.x * 1024 + t * 4;
  int v[4];
#pragma unroll
  for (int j = 0; j < 4; ++j) {
    int idx = base + j;
    v[j] = (idx < NN) ? deg[idx] : 0;
  }
  int tsum = v[0] + v[1] + v[2] + v[3];
  s[t] = tsum;
  __syncthreads();
  for (int d = 1; d < 256; d <<= 1) {
    int add = (t >= d) ? s[t - d] : 0;
    __syncthreads();
    s[t] += add;
    __syncthreads();
  }
  int run = s[t] - tsum;
#pragma unroll
  for (int j = 0; j < 4; ++j) {
    int idx = base + j;
    if (idx < NN) off[idx] = run;
    run += v[j];
  }
  if (t == 255) bsum[blockIdx.x] = s[255];
}

__global__ void scan2_kernel(int* __restrict__ bsum, int* __restrict__ off, int nb) {
  if (threadIdx.x == 0) {
    int run = 0;
    for (int b = 0; b < nb; ++b) {
      int v = bsum[b];
      bsum[b] = run;
      run += v;
    }
    off[NN] = run;
  }
}

__global__ __launch_bounds__(256) void scan3_kernel(int* __restrict__ off,
                                                    const int* __restrict__ bsum) {
  int idx = blockIdx.x * blockDim.x + threadIdx.x;
  if (idx < NN) off[idx] += bsum[idx >> 10];
}

__global__ __launch_bounds__(256) void scatter_kernel(
    const int* __restrict__ ei, const int* __restrict__ ea,
    const int* __restrict__ off, int* __restrict__ cnt, int* __restrict__ csr) {
  int e = blockIdx.x * blockDim.x + threadIdx.x;
  if (e >= NE) return;
  int d = ei[NE + e];
  int s = ei[e];
  int a0 = min(max(ea[2 * e], 0), 4);
  int a1 = min(max(ea[2 * e + 1], 0), 2);
  int code = a0 * 3 + a1;  // [0,14]
  int r = atomicAdd(&cnt[d], 1);
  csr[off[d] + r] = s | (code << 20);
}

// combos[l][code][f] = ee1[l][code/3][f] + ee2[l][code%3][f]
__global__ __launch_bounds__(256) void combo_kernel(const float* __restrict__ ee1,
                                                    const float* __restrict__ ee2,
                                                    float* __restrict__ combos) {
  int idx = blockIdx.x * blockDim.x + threadIdx.x;
  if (idx >= 5 * 15 * 128) return;
  int l = idx / (15 * 128);
  int rem = idx % (15 * 128);
  int code = rem / 128;
  int f = rem % 128;
  combos[idx] = ee1[(l * 5 + code / 3) * 128 + f] + ee2[(l * 3 + code % 3) * 128 + f];
}

// ---------------- weight prep: frag-ordered split-bf16, hi/lo INTERLEAVED 32B pairs ----------------
__global__ __launch_bounds__(256) void prep_w_kernel(
    const float* __restrict__ W1g, const float* __restrict__ W2g,
    u16* __restrict__ W1f, u16* __restrict__ W2f) {
  int idx = blockIdx.x * blockDim.x + threadIdx.x;
  if (idx >= 40960) return;
  u16 oh[8], ol[8];
  if (idx < 20480) {
    int lane = idx & 63;
    int r = idx >> 6;             // l*64 + c*16 + kt*4 + colt
    int nt = r & 3, kt = (r >> 2) & 3, c = (r >> 4) & 3, l = r >> 6;
    int n = c * 64 + nt * 16 + (lane & 15);
    int kb = kt * 32 + (lane >> 4) * 8;
#pragma unroll
    for (int j = 0; j < 8; ++j) {
      float w = W1g[((size_t)l * 128 + kb + j) * 256 + n];
      oh[j] = f2bf(w);
      ol[j] = f2bf(w - bf2f(oh[j]));
    }
    *(ulonglong2*)(W1f + (size_t)idx * 16) = *(ulonglong2*)oh;
    *(ulonglong2*)(W1f + (size_t)idx * 16 + 8) = *(ulonglong2*)ol;
  } else {
    int i2 = idx - 20480;
    int lane = i2 & 63;
    int r = i2 >> 6;              // l*64 + c*16 + ktl*8 + nt
    int nt = r & 7, ktl = (r >> 3) & 1, c = (r >> 4) & 3, l = r >> 6;
    int n = nt * 16 + (lane & 15);
    int kb = c * 64 + ktl * 32 + (lane >> 4) * 8;
#pragma unroll
    for (int j = 0; j < 8; ++j) {
      float w = W2g[((size_t)l * 256 + kb + j) * 128 + n];
      oh[j] = f2bf(w);
      ol[j] = f2bf(w - bf2f(oh[j]));
    }
    *(ulonglong2*)(W2f + (size_t)i2 * 16) = *(ulonglong2*)oh;
    *(ulonglong2*)(W2f + (size_t)i2 * 16 + 8) = *(ulonglong2*)ol;
  }
}

// ---------------- agg: A = (1+eps)*hf + relu(hf+c0) + sum relu(hb[src]+c) ----------------
// Output Af interleaved: node*256 + kc*16: [0..7]=hi, [8..15]=lo (32B contiguous).
__global__ __launch_bounds__(256) void agg_kernel(
    const float* __restrict__ hf, const u16* __restrict__ hb,
    const int* __restrict__ off, const int* __restrict__ csr,
    const float* __restrict__ cb, const float* __restrict__ epsp,
    u16* __restrict__ Af) {
  int tid = blockIdx.x * blockDim.x + threadIdx.x;
  int g = tid >> 4;
  int kc = tid & 15;
  float av[8] = {0.f, 0.f, 0.f, 0.f, 0.f, 0.f, 0.f, 0.f};
  if (g < NN) {
    const float eps1 = 1.0f + *epsp;
    const float* hp = hf + (size_t)g * EMB + kc * 8;
    float4 va = ld4(hp), vb = ld4(hp + 4);
    float hv[8] = {va.x, va.y, va.z, va.w, vb.x, vb.y, vb.z, vb.w};
    float4 ca = ld4(cb + kc * 8), cbv = ld4(cb + kc * 8 + 4);
    float cs[8] = {ca.x, ca.y, ca.z, ca.w, cbv.x, cbv.y, cbv.z, cbv.w};
#pragma unroll
    for (int j = 0; j < 8; ++j) av[j] = eps1 * hv[j] + fmaxf(hv[j] + cs[j], 0.f);
    int s0 = off[g], s1 = off[g + 1];
    int e = s0;
    for (; e + 1 < s1; e += 2) {  // unroll x2: two independent gather chains in flight
      int p0 = csr[e], p1 = csr[e + 1];
      ulonglong2 r0 = *(const ulonglong2*)(hb + (size_t)(p0 & 0xFFFFF) * EMB + kc * 8);
      ulonglong2 r1 = *(const ulonglong2*)(hb + (size_t)(p1 & 0xFFFFF) * EMB + kc * 8);
      const float* c0p = cb + (size_t)(p0 >> 20) * EMB + kc * 8;
      const float* c1p = cb + (size_t)(p1 >> 20) * EMB + kc * 8;
      float4 c0a = ld4(c0p), c0b = ld4(c0p + 4);
      float4 c1a = ld4(c1p), c1b = ld4(c1p + 4);
      float cc0[8] = {c0a.x, c0a.y, c0a.z, c0a.w, c0b.x, c0b.y, c0b.z, c0b.w};
      float cc1[8] = {c1a.x, c1a.y, c1a.z, c1a.w, c1b.x, c1b.y, c1b.z, c1b.w};
      u16* s0p = (u16*)&r0;
      u16* s1p = (u16*)&r1;
#pragma unroll
      for (int j = 0; j < 8; ++j) {
        av[j] += fmaxf(bf2f(s0p[j]) + cc0[j], 0.f);
        av[j] += fmaxf(bf2f(s1p[j]) + cc1[j], 0.f);
      }
    }
    if (e < s1) {
      int p0 = csr[e];
      ulonglong2 r0 = *(const ulonglong2*)(hb + (size_t)(p0 & 0xFFFFF) * EMB + kc * 8);
      const float* c0p = cb + (size_t)(p0 >> 20) * EMB + kc * 8;
      float4 c0a = ld4(c0p), c0b = ld4(c0p + 4);
      float cc0[8] = {c0a.x, c0a.y, c0a.z, c0a.w, c0b.x, c0b.y, c0b.z, c0b.w};
      u16* s0p = (u16*)&r0;
#pragma unroll
      for (int j = 0; j < 8; ++j) av[j] += fmaxf(bf2f(s0p[j]) + cc0[j], 0.f);
    }
  }
  u16 oh[8], ol[8];
#pragma unroll
  for (int j = 0; j < 8; ++j) {
    oh[j] = f2bf(av[j]);
    ol[j] = f2bf(av[j] - bf2f(oh[j]));
  }
  u16* d = Af + (size_t)g * 256 + kc * 16;
  *(ulonglong2*)d = *(ulonglong2*)oh;        // zeros for pad rows
  *(ulonglong2*)(d + 8) = *(ulonglong2*)ol;
}

// ---------------- mlp: 16 nodes/wave (high TLP), A in regs, W via LDS ----------------
// 6256 independent waves; __launch_bounds__(256,4) caps VGPR at 128 -> 4 waves/SIMD.
__global__ __launch_bounds__(256, 4) void mlp_kernel(
    const u16* __restrict__ Af, const u16* __restrict__ W1f,
    const u16* __restrict__ W2f,
    const float* __restrict__ b1g, const float* __restrict__ b2g,
    float* __restrict__ hpre, float* __restrict__ slots) {
  __shared__ __align__(16) u16 Wh[16 * 64 * 8];  // 16KB hi plane
  __shared__ __align__(16) u16 Wl[16 * 64 * 8];  // 16KB lo plane

  const int t = threadIdx.x;
  const int w = t >> 6;
  const int lane = t & 63;
  const int q = lane >> 4, l15 = lane & 15;
  const int gw = blockIdx.x * 4 + w;   // global wave id, 0..6255
  const int n0 = gw * 16;              // 16 nodes per wave
  float* sums = slots + (size_t)(gw & 31) * 256;

  // ---- A fragments loaded ONCE, held across all chunks (8 loads in flight) ----
  short8 nh[4], nl[4];
#pragma unroll
  for (int kt = 0; kt < 4; ++kt) {
    const u16* p = Af + (size_t)(n0 + l15) * 256 + kt * 64 + q * 16;
    nh[kt] = *(const short8*)p;
    nl[kt] = *(const short8*)(p + 8);
  }

  f32x4 oacc[8];  // [out col tile]
#pragma unroll
  for (int a = 0; a < 8; ++a) oacc[a] = (f32x4){0.f, 0.f, 0.f, 0.f};

  const int srcA = ((q & 1) * 2) * 16 + l15;  // quad permutation sources
  const int srcB = srcA + 16;
  const bool sel = (q >> 1) != 0;

  for (int c = 0; c < 4; ++c) {
    __syncthreads();  // prev chunk's stage-2 LDS reads complete
    // ---- stage W1 chunk c into LDS (wave w covers frag-pairs w*4..w*4+3) ----
    {
      const u16* gb = W1f + ((size_t)(c * 16 + w * 4) * 64 + lane) * 16;
#pragma unroll
      for (int j = 0; j < 4; ++j) {
        ulonglong2 hi = *(const ulonglong2*)(gb + (size_t)j * 1024);
        ulonglong2 lo = *(const ulonglong2*)(gb + (size_t)j * 1024 + 8);
        *(ulonglong2*)&Wh[(w * 4 + j) * 512 + lane * 8] = hi;
        *(ulonglong2*)&Wl[(w * 4 + j) * 512 + lane * 8] = lo;
      }
    }
    __syncthreads();

    // ---- stage 1: hmidT[col c*64+colt*16+q*4+r][node l15] ----
    f32x4 hacc[4];
#pragma unroll
    for (int a = 0; a < 4; ++a) hacc[a] = (f32x4){0.f, 0.f, 0.f, 0.f};
#pragma unroll
    for (int kt = 0; kt < 4; ++kt) {
#pragma unroll
      for (int colt = 0; colt < 4; ++colt) {
        int pp = (kt * 4 + colt) * 512 + lane * 8;
        short8 wh = *(const short8*)&Wh[pp];
        short8 wl = *(const short8*)&Wl[pp];
        hacc[colt] = __builtin_amdgcn_mfma_f32_16x16x32_bf16(wh, nh[kt], hacc[colt], 0, 0, 0);
        hacc[colt] = __builtin_amdgcn_mfma_f32_16x16x32_bf16(wh, nl[kt], hacc[colt], 0, 0, 0);
        hacc[colt] = __builtin_amdgcn_mfma_f32_16x16x32_bf16(wl, nh[kt], hacc[colt], 0, 0, 0);
      }
    }
    __syncthreads();  // stage-1 LDS reads complete; buffer reusable

    // ---- stage W2 chunk c into LDS ----
    {
      const u16* gb = W2f + ((size_t)(c * 16 + w * 4) * 64 + lane) * 16;
#pragma unroll
      for (int j = 0; j < 4; ++j) {
        ulonglong2 hi = *(const ulonglong2*)(gb + (size_t)j * 1024);
        ulonglong2 lo = *(const ulonglong2*)(gb + (size_t)j * 1024 + 8);
        *(ulonglong2*)&Wh[(w * 4 + j) * 512 + lane * 8] = hi;
        *(ulonglong2*)&Wl[(w * 4 + j) * 512 + lane * 8] = lo;
      }
    }

    // ---- bias + relu + split + pack (2 bf16/dword, k-ascending); overlaps staging ----
    u32 P01h[4], P23h[4], P01l[4], P23l[4];  // [colt]
#pragma unroll
    for (int colt = 0; colt < 4; ++colt) {
      float4 b1v = ld4(b1g + c * 64 + colt * 16 + q * 4);
      float bb[4] = {b1v.x, b1v.y, b1v.z, b1v.w};
      u16 hi[4], lo[4];
#pragma unroll
      for (int r = 0; r < 4; ++r) {
        float v = fmaxf(hacc[colt][r] + bb[r], 0.f);
        hi[r] = f2bf(v);
        lo[r] = f2bf(v - bf2f(hi[r]));
      }
      P01h[colt] = (u32)hi[0] | ((u32)hi[1] << 16);
      P23h[colt] = (u32)hi[2] | ((u32)hi[3] << 16);
      P01l[colt] = (u32)lo[0] | ((u32)lo[1] << 16);
      P23l[colt] = (u32)lo[2] | ((u32)lo[3] << 16);
    }
    __syncthreads();  // W2 staged

    // ---- stage 2: quad-permute hmid into B-frags, multiply with W2 from LDS ----
#pragma unroll
    for (int ktl = 0; ktl < 2; ++ktl) {
      short8 bh, bl;
      {
        union { u32 d[4]; short8 s; } uh, ul;
        int c0 = 2 * ktl, c1 = 2 * ktl + 1;
        u32 a0, a1;
        a0 = (u32)__shfl((int)P01h[c0], srcA); a1 = (u32)__shfl((int)P01h[c1], srcA);
        uh.d[0] = sel ? a1 : a0;
        a0 = (u32)__shfl((int)P23h[c0], srcA); a1 = (u32)__shfl((int)P23h[c1], srcA);
        uh.d[1] = sel ? a1 : a0;
        a0 = (u32)__shfl((int)P01h[c0], srcB); a1 = (u32)__shfl((int)P01h[c1], srcB);
        uh.d[2] = sel ? a1 : a0;
        a0 = (u32)__shfl((int)P23h[c0], srcB); a1 = (u32)__shfl((int)P23h[c1], srcB);
        uh.d[3] = sel ? a1 : a0;
        a0 = (u32)__shfl((int)P01l[c0], srcA); a1 = (u32)__shfl((int)P01l[c1], srcA);
        ul.d[0] = sel ? a1 : a0;
        a0 = (u32)__shfl((int)P23l[c0], srcA); a1 = (u32)__shfl((int)P23l[c1], srcA);
        ul.d[1] = sel ? a1 : a0;
        a0 = (u32)__shfl((int)P01l[c0], srcB); a1 = (u32)__shfl((int)P01l[c1], srcB);
        ul.d[2] = sel ? a1 : a0;
        a0 = (u32)__shfl((int)P23l[c0], srcB); a1 = (u32)__shfl((int)P23l[c1], srcB);
        ul.d[3] = sel ? a1 : a0;
        bh = uh.s;
        bl = ul.s;
      }
#pragma unroll
      for (int nt = 0; nt < 8; ++nt) {
        int pp = (ktl * 8 + nt) * 512 + lane * 8;
        short8 wh = *(const short8*)&Wh[pp];
        short8 wl = *(const short8*)&Wl[pp];
        oacc[nt] = __builtin_amdgcn_mfma_f32_16x16x32_bf16(wh, bh, oacc[nt], 0, 0, 0);
        oacc[nt] = __builtin_amdgcn_mfma_f32_16x16x32_bf16(wh, bl, oacc[nt], 0, 0, 0);
        oacc[nt] = __builtin_amdgcn_mfma_f32_16x16x32_bf16(wl, bh, oacc[nt], 0, 0, 0);
      }
    }
  }

  // ---- epilogue: +b2, float4 store, BN partials into slot ----
  const int node = n0 + l15;
#pragma unroll
  for (int nt = 0; nt < 8; ++nt) {
    int ocb = nt * 16 + q * 4;  // 4 consecutive out cols per lane
    float4 b2v = ld4(b2g + ocb);
    f32x4 s = (f32x4){0.f, 0.f, 0.f, 0.f};
    f32x4 s2 = (f32x4){0.f, 0.f, 0.f, 0.f};
    if (node < NN) {
      float4 v;
      v.x = oacc[nt][0] + b2v.x;
      v.y = oacc[nt][1] + b2v.y;
      v.z = oacc[nt][2] + b2v.z;
      v.w = oacc[nt][3] + b2v.w;
      *(float4*)(hpre + (size_t)node * EMB + ocb) = v;
      s[0] = v.x; s[1] = v.y; s[2] = v.z; s[3] = v.w;
      s2[0] = v.x * v.x; s2[1] = v.y * v.y; s2[2] = v.z * v.z; s2[3] = v.w * v.w;
    }
#pragma unroll
    for (int d = 1; d < 16; d <<= 1) {
#pragma unroll
      for (int r = 0; r < 4; ++r) {
        s[r] += __shfl_xor(s[r], d);
        s2[r] += __shfl_xor(s2[r], d);
      }
    }
    if (l15 == 0) {
#pragma unroll
      for (int r = 0; r < 4; ++r) {
        atomicAdd(&sums[ocb + r], s[r]);
        atomicAdd(&sums[128 + ocb + r], s2[r]);
      }
    }
  }
}

// ---------------- reduce 32 BN slots -> sums[256] ----------------
__global__ void sums_reduce_kernel(const float* __restrict__ slots,
                                   float* __restrict__ sums) {
  int f = threadIdx.x;  // 256
  float s = 0.f;
#pragma unroll 8
  for (int k = 0; k < 32; ++k) s += slots[k * 256 + f];
  sums[f] = s;
}

// ---------------- BN apply (stats recomputed inline from sums; L2-hot) ----------------
template <bool LAST>
__global__ __launch_bounds__(256) void bn_apply_kernel(
    const float* __restrict__ hp, const float* __restrict__ sums,
    const float* __restrict__ gamma, const float* __restrict__ beta,
    float* __restrict__ hf, u16* __restrict__ hb, float* __restrict__ out) {
  int tid = blockIdx.x * blockDim.x + threadIdx.x;
  int n = tid >> 4;
  if (n >= NN) return;
  int kc = tid & 15;
  const float* p = hp + (size_t)n * EMB + kc * 8;
  float4 va = ld4(p), vb = ld4(p + 4);
  float v[8] = {va.x, va.y, va.z, va.w, vb.x, vb.y, vb.z, vb.w};
  float4 sa = ld4(sums + kc * 8), sb = ld4(sums + kc * 8 + 4);
  float4 qa = ld4(sums + 128 + kc * 8), qb = ld4(sums + 128 + kc * 8 + 4);
  float4 ga = ld4(gamma + kc * 8), gb = ld4(gamma + kc * 8 + 4);
  float4 ba = ld4(beta + kc * 8), bb = ld4(beta + kc * 8 + 4);
  float sm[8] = {sa.x, sa.y, sa.z, sa.w, sb.x, sb.y, sb.z, sb.w};
  float sq[8] = {qa.x, qa.y, qa.z, qa.w, qb.x, qb.y, qb.z, qb.w};
  float gm[8] = {ga.x, ga.y, ga.z, ga.w, gb.x, gb.y, gb.z, gb.w};
  float bt[8] = {ba.x, ba.y, ba.z, ba.w, bb.x, bb.y, bb.z, bb.w};
#pragma unroll
  for (int j = 0; j < 8; ++j) {
    float mean = sm[j] * (1.0f / NN);
    float var = sq[j] * (1.0f / NN) - mean * mean;  // biased
    float sc = gm[j] * rsqrtf(var + 1e-5f);
    v[j] = (v[j] - mean) * sc + bt[j];
  }
  if (LAST) {
    float* d = out + (size_t)n * EMB + kc * 8;
    *(float4*)d = make_float4(v[0], v[1], v[2], v[3]);
    *(float4*)(d + 4) = make_float4(v[4], v[5], v[6], v[7]);
  } else {
#pragma unroll
    for (int j = 0; j < 8; ++j) v[j] = fmaxf(v[j], 0.f);
    float* df = hf + (size_t)n * EMB + kc * 8;
    *(float4*)df = make_float4(v[0], v[1], v[2], v[3]);
    *(float4*)(df + 4) = make_float4(v[4], v[5], v[6], v[7]);
    u16 o[8];
#pragma unroll
    for (int j = 0; j < 8; ++j) o[j] = f2bf(v[j]);
    *(ulonglong2*)(hb + (size_t)n * EMB + kc * 8) = *(ulonglong2*)o;
  }
}

// ---------------- launch ----------------
extern "C" void kernel_launch(void* const* d_in, const int* in_sizes, int n_in,
                              void* d_out, int out_size, void* d_ws, size_t ws_size,
                              hipStream_t stream) {
  const int* x = (const int*)d_in[0];
  const int* ei = (const int*)d_in[1];
  const int* ea = (const int*)d_in[2];
  const float* x_emb1 = (const float*)d_in[3];
  const float* x_emb2 = (const float*)d_in[4];
  const float* ee1 = (const float*)d_in[5];
  const float* ee2 = (const float*)d_in[6];
  const float* W1 = (const float*)d_in[7];
  const float* b1 = (const float*)d_in[8];
  const float* W2 = (const float*)d_in[9];
  const float* b2 = (const float*)d_in[10];
  const float* eps = (const float*)d_in[11];
  const float* gamma = (const float*)d_in[12];
  const float* beta = (const float*)d_in[13];
  float* out = (float*)d_out;

  // workspace layout (16B-aligned sections)
  float* hpre = (float*)d_ws;                   // NN*128 f32
  float* hf = hpre + (size_t)NN * EMB;          // NN*128 f32
  float* slots = hf + (size_t)NN * EMB;         // 5*32*256 BN partial slots
  float* sums = slots + 5 * 32 * 256;           // 5*256 reduced
  float* combos = sums + 5 * 256;               // 9600
  u16* Af = (u16*)(combos + 9600);              // NPAD*256 bf16 (hi/lo interleaved)
  u16* hb = Af + (size_t)NPAD * 256;            // NN*128 bf16
  u16* W1f = hb + (size_t)NN * EMB;             // 5*65536 (interleaved pairs)
  u16* W2f = W1f + 5 * 65536;                   // 5*65536
  int* deg = (int*)(W2f + 5 * 65536);           // NN
  int* off = deg + NN;                          // NN+1
  int* csr = off + NN + 1;                      // NE
  int* bsum = csr + NE;                         // 128

  const int NB_SCAN = (NN + 1023) / 1024;

  // one-time per launch: CSR + combo tables + frag-ordered split-bf16 weights
  hipMemsetAsync(deg, 0, NN * sizeof(int), stream);
  hipMemsetAsync(slots, 0, 5 * 32 * 256 * sizeof(float), stream);
  hist_kernel<<<(NE + 255) / 256, 256, 0, stream>>>(ei, deg);
  scan1_kernel<<<NB_SCAN, 256, 0, stream>>>(deg, off, bsum);
  scan2_kernel<<<1, 64, 0, stream>>>(bsum, off, NB_SCAN);
  scan3_kernel<<<(NN + 255) / 256, 256, 0, stream>>>(off, bsum);
  hipMemsetAsync(deg, 0, NN * sizeof(int), stream);
  scatter_kernel<<<(NE + 255) / 256, 256, 0, stream>>>(ei, ea, off, deg, csr);
  combo_kernel<<<(5 * 15 * 128 + 255) / 256, 256, 0, stream>>>(ee1, ee2, combos);
  prep_w_kernel<<<160, 256, 0, stream>>>(W1, W2, W1f, W2f);
  node_init_kernel<<<NN * 16 / 256 + 1, 256, 0, stream>>>(x, x_emb1, x_emb2, hf, hb);

  const int NBLK = NPAD / 64;  // 1564 blocks x 4 waves (16 nodes each)
  for (int i = 0; i < 5; ++i) {
    agg_kernel<<<NPAD * 16 / 256, 256, 0, stream>>>(
        hf, hb, off, csr, combos + (size_t)i * 15 * EMB, eps + i, Af);
    mlp_kernel<<<NBLK, 256, 0, stream>>>(
        Af, W1f + (size_t)i * 65536, W2f + (size_t)i * 65536,
        b1 + (size_t)i * 256, b2 + (size_t)i * 128, hpre,
        slots + (size_t)i * 32 * 256);
    sums_reduce_kernel<<<1, 256, 0, stream>>>(slots + (size_t)i * 32 * 256,
                                              sums + (size_t)i * 256);
    if (i < 4)
      bn_apply_kernel<false><<<NN * 16 / 256 + 1, 256, 0, stream>>>(
          hpre, sums + (size_t)i * 256, gamma + (size_t)i * EMB, beta + (size_t)i * EMB,
          hf, hb, nullptr);
    else
      bn_apply_kernel<true><<<NN * 16 / 256 + 1, 256, 0, stream>>>(
          hpre, sums + (size_t)i * 256, gamma + (size_t)i * EMB, beta + (size_t)i * EMB,
          nullptr, nullptr, out);
  }
}

// Round 11
// 694.338 us; speedup vs baseline: 2.5149x; 1.3691x over previous
//
#include <hip/hip_runtime.h>

#define NN 100000
#define NPAD 100096   // 6256 * 16, padded row count for guard-free GEMM
#define NE 600000
#define EMB 128

typedef unsigned short u16;
typedef unsigned int u32;
typedef _Float16 half8 __attribute__((ext_vector_type(8)));
typedef float f32x4 __attribute__((ext_vector_type(4)));

__device__ __forceinline__ float4 ld4(const float* p) { return *(const float4*)p; }
__device__ __forceinline__ u32 packh2(float a, float b) {  // two f32 -> packed f16 pair
  union { _Float16 h[2]; u32 d; } u;
  u.h[0] = (_Float16)a;
  u.h[1] = (_Float16)b;
  return u.d;
}

// ---------------- node embedding init: hb(f16) = emb1[x0] + emb2[x1] ----------------
__global__ __launch_bounds__(256) void node_init_kernel(
    const int* __restrict__ x, const float* __restrict__ emb1,
    const float* __restrict__ emb2, _Float16* __restrict__ hb) {
  int tid = blockIdx.x * blockDim.x + threadIdx.x;
  int n = tid >> 4;
  if (n >= NN) return;
  int kc = tid & 15;
  int x0 = min(max(x[2 * n], 0), 118);
  int x1 = min(max(x[2 * n + 1], 0), 2);  // x[:,1] sampled 0..118 -> clip to NUM_CHIR-1
  const float* p1 = emb1 + (size_t)x0 * EMB + kc * 8;
  const float* p2 = emb2 + (size_t)x1 * EMB + kc * 8;
  _Float16 o[8];
#pragma unroll
  for (int j = 0; j < 8; ++j) o[j] = (_Float16)(p1[j] + p2[j]);
  *(ulonglong2*)(hb + (size_t)n * EMB + kc * 8) = *(ulonglong2*)o;
}

// ---------------- CSR build ----------------
__global__ __launch_bounds__(256) void hist_kernel(const int* __restrict__ ei,
                                                   int* __restrict__ deg) {
  int e = blockIdx.x * blockDim.x + threadIdx.x;
  if (e >= NE) return;
  atomicAdd(&deg[ei[NE + e]], 1);
}

__global__ __launch_bounds__(256) void scan1_kernel(const int* __restrict__ deg,
                                                    int* __restrict__ off,
                                                    int* __restrict__ bsum) {
  __shared__ int s[256];
  int t = threadIdx.x;
  int base = blockIdx.x * 1024 + t * 4;
  int v[4];
#pragma unroll
  for (int j = 0; j < 4; ++j) {
    int idx = base + j;
    v[j] = (idx < NN) ? deg[idx] : 0;
  }
  int tsum = v[0] + v[1] + v[2] + v[3];
  s[t] = tsum;
  __syncthreads();
  for (int d = 1; d < 256; d <<= 1) {
    int add = (t >= d) ? s[t - d] : 0;
    __syncthreads();
    s[t] += add;
    __syncthreads();
  }
  int run = s[t] - tsum;
#pragma unroll
  for (int j = 0; j < 4; ++j) {
    int idx = base + j;
    if (idx < NN) off[idx] = run;
    run += v[j];
  }
  if (t == 255) bsum[blockIdx.x] = s[255];
}

__global__ void scan2_kernel(int* __restrict__ bsum, int* __restrict__ off, int nb) {
  if (threadIdx.x == 0) {
    int run = 0;
    for (int b = 0; b < nb; ++b) {
      int v = bsum[b];
      bsum[b] = run;
      run += v;
    }
    off[NN] = run;
  }
}

__global__ __launch_bounds__(256) void scan3_kernel(int* __restrict__ off,
                                                    const int* __restrict__ bsum) {
  int idx = blockIdx.x * blockDim.x + threadIdx.x;
  if (idx < NN) off[idx] += bsum[idx >> 10];
}

__global__ __launch_bounds__(256) void scatter_kernel(
    const int* __restrict__ ei, const int* __restrict__ ea,
    const int* __restrict__ off, int* __restrict__ cnt, int* __restrict__ csr) {
  int e = blockIdx.x * blockDim.x + threadIdx.x;
  if (e >= NE) return;
  int d = ei[NE + e];
  int s = ei[e];
  int a0 = min(max(ea[2 * e], 0), 4);
  int a1 = min(max(ea[2 * e + 1], 0), 2);
  int code = a0 * 3 + a1;  // [0,14]
  int r = atomicAdd(&cnt[d], 1);
  csr[off[d] + r] = s | (code << 20);
}

// combos[l][code][f] = ee1[l][code/3][f] + ee2[l][code%3][f]
__global__ __launch_bounds__(256) void combo_kernel(const float* __restrict__ ee1,
                                                    const float* __restrict__ ee2,
                                                    float* __restrict__ combos) {
  int idx = blockIdx.x * blockDim.x + threadIdx.x;
  if (idx >= 5 * 15 * 128) return;
  int l = idx / (15 * 128);
  int rem = idx % (15 * 128);
  int code = rem / 128;
  int f = rem % 128;
  combos[idx] = ee1[(l * 5 + code / 3) * 128 + f] + ee2[(l * 3 + code % 3) * 128 + f];
}

// ---------------- weight prep: frag-ordered f16 copies of W1/W2 (single plane) ----------------
__global__ __launch_bounds__(256) void prep_w_kernel(
    const float* __restrict__ W1g, const float* __restrict__ W2g,
    _Float16* __restrict__ W1f, _Float16* __restrict__ W2f) {
  int idx = blockIdx.x * blockDim.x + threadIdx.x;
  if (idx >= 40960) return;
  _Float16 o[8];
  if (idx < 20480) {
    int lane = idx & 63;
    int r = idx >> 6;             // l*64 + c*16 + kt*4 + colt
    int nt = r & 3, kt = (r >> 2) & 3, c = (r >> 4) & 3, l = r >> 6;
    int n = c * 64 + nt * 16 + (lane & 15);
    int kb = kt * 32 + (lane >> 4) * 8;
#pragma unroll
    for (int j = 0; j < 8; ++j) o[j] = (_Float16)W1g[((size_t)l * 128 + kb + j) * 256 + n];
    *(ulonglong2*)(W1f + (size_t)idx * 8) = *(ulonglong2*)o;
  } else {
    int i2 = idx - 20480;
    int lane = i2 & 63;
    int r = i2 >> 6;              // l*64 + c*16 + ktl*8 + nt
    int nt = r & 7, ktl = (r >> 3) & 1, c = (r >> 4) & 3, l = r >> 6;
    int n = nt * 16 + (lane & 15);
    int kb = c * 64 + ktl * 32 + (lane >> 4) * 8;
#pragma unroll
    for (int j = 0; j < 8; ++j) o[j] = (_Float16)W2g[((size_t)l * 256 + kb + j) * 128 + n];
    *(ulonglong2*)(W2f + (size_t)i2 * 8) = *(ulonglong2*)o;
  }
}

// ---------------- agg: Af(f16) = (1+eps)*h + relu(h+c0) + sum relu(h[src]+c) ----------------
__global__ __launch_bounds__(256) void agg_kernel(
    const _Float16* __restrict__ hb, const int* __restrict__ off,
    const int* __restrict__ csr, const float* __restrict__ cb,
    const float* __restrict__ epsp, _Float16* __restrict__ Af) {
  int tid = blockIdx.x * blockDim.x + threadIdx.x;
  int g = tid >> 4;
  int kc = tid & 15;
  float av[8] = {0.f, 0.f, 0.f, 0.f, 0.f, 0.f, 0.f, 0.f};
  if (g < NN) {
    const float eps1 = 1.0f + *epsp;
    ulonglong2 hraw = *(const ulonglong2*)(hb + (size_t)g * EMB + kc * 8);
    _Float16* hr = (_Float16*)&hraw;
    float4 ca = ld4(cb + kc * 8), cbv = ld4(cb + kc * 8 + 4);
    float cs[8] = {ca.x, ca.y, ca.z, ca.w, cbv.x, cbv.y, cbv.z, cbv.w};
#pragma unroll
    for (int j = 0; j < 8; ++j) {
      float hv = (float)hr[j];
      av[j] = eps1 * hv + fmaxf(hv + cs[j], 0.f);
    }
    int s0 = off[g], s1 = off[g + 1];
    int e = s0;
    for (; e + 1 < s1; e += 2) {  // unroll x2: two independent gather chains in flight
      int p0 = csr[e], p1 = csr[e + 1];
      ulonglong2 r0 = *(const ulonglong2*)(hb + (size_t)(p0 & 0xFFFFF) * EMB + kc * 8);
      ulonglong2 r1 = *(const ulonglong2*)(hb + (size_t)(p1 & 0xFFFFF) * EMB + kc * 8);
      const float* c0p = cb + (size_t)(p0 >> 20) * EMB + kc * 8;
      const float* c1p = cb + (size_t)(p1 >> 20) * EMB + kc * 8;
      float4 c0a = ld4(c0p), c0b = ld4(c0p + 4);
      float4 c1a = ld4(c1p), c1b = ld4(c1p + 4);
      float cc0[8] = {c0a.x, c0a.y, c0a.z, c0a.w, c0b.x, c0b.y, c0b.z, c0b.w};
      float cc1[8] = {c1a.x, c1a.y, c1a.z, c1a.w, c1b.x, c1b.y, c1b.z, c1b.w};
      _Float16* s0p = (_Float16*)&r0;
      _Float16* s1p = (_Float16*)&r1;
#pragma unroll
      for (int j = 0; j < 8; ++j) {
        av[j] += fmaxf((float)s0p[j] + cc0[j], 0.f);
        av[j] += fmaxf((float)s1p[j] + cc1[j], 0.f);
      }
    }
    if (e < s1) {
      int p0 = csr[e];
      ulonglong2 r0 = *(const ulonglong2*)(hb + (size_t)(p0 & 0xFFFFF) * EMB + kc * 8);
      const float* c0p = cb + (size_t)(p0 >> 20) * EMB + kc * 8;
      float4 c0a = ld4(c0p), c0b = ld4(c0p + 4);
      float cc0[8] = {c0a.x, c0a.y, c0a.z, c0a.w, c0b.x, c0b.y, c0b.z, c0b.w};
      _Float16* s0p = (_Float16*)&r0;
#pragma unroll
      for (int j = 0; j < 8; ++j) av[j] += fmaxf((float)s0p[j] + cc0[j], 0.f);
    }
  }
  _Float16 o[8];
#pragma unroll
  for (int j = 0; j < 8; ++j) o[j] = (_Float16)av[j];
  *(ulonglong2*)(Af + (size_t)g * EMB + kc * 8) = *(ulonglong2*)o;  // zeros for pad rows
}

// ---------------- mlp: f16 single-product, 16 nodes/wave, A in regs, W via LDS ----------------
__global__ __launch_bounds__(256, 4) void mlp_kernel(
    const _Float16* __restrict__ Af, const _Float16* __restrict__ W1f,
    const _Float16* __restrict__ W2f,
    const float* __restrict__ b1g, const float* __restrict__ b2g,
    float* __restrict__ hpre, float* __restrict__ slots) {
  __shared__ __align__(16) _Float16 Ws[16 * 64 * 8];  // 16KB, W1 then W2 per chunk

  const int t = threadIdx.x;
  const int w = t >> 6;
  const int lane = t & 63;
  const int q = lane >> 4, l15 = lane & 15;
  const int gw = blockIdx.x * 4 + w;   // global wave id, 0..6255
  const int n0 = gw * 16;              // 16 nodes per wave
  float* sums = slots + (size_t)(gw & 31) * 256;

  // ---- A fragments loaded ONCE, held across all chunks ----
  half8 nh[4];
#pragma unroll
  for (int kt = 0; kt < 4; ++kt)
    nh[kt] = *(const half8*)(Af + (size_t)(n0 + l15) * EMB + kt * 32 + q * 8);

  f32x4 oacc[8];  // [out col tile]
#pragma unroll
  for (int a = 0; a < 8; ++a) oacc[a] = (f32x4){0.f, 0.f, 0.f, 0.f};

  const int srcA = ((q & 1) * 2) * 16 + l15;  // quad permutation sources
  const int srcB = srcA + 16;
  const bool sel = (q >> 1) != 0;

  for (int c = 0; c < 4; ++c) {
    __syncthreads();  // prev chunk's stage-2 LDS reads complete
    // ---- stage W1 chunk c (wave w covers frags w*4..w*4+3) ----
    {
      const _Float16* gb = W1f + ((size_t)(c * 16 + w * 4) * 64 + lane) * 8;
#pragma unroll
      for (int j = 0; j < 4; ++j)
        *(ulonglong2*)&Ws[(w * 4 + j) * 512 + lane * 8] =
            *(const ulonglong2*)(gb + (size_t)j * 512);
    }
    __syncthreads();

    // ---- stage 1: hmidT[col c*64+colt*16+q*4+r][node l15] ----
    f32x4 hacc[4];
#pragma unroll
    for (int a = 0; a < 4; ++a) hacc[a] = (f32x4){0.f, 0.f, 0.f, 0.f};
#pragma unroll
    for (int kt = 0; kt < 4; ++kt) {
#pragma unroll
      for (int colt = 0; colt < 4; ++colt) {
        half8 wh = *(const half8*)&Ws[(kt * 4 + colt) * 512 + lane * 8];
        hacc[colt] = __builtin_amdgcn_mfma_f32_16x16x32_f16(wh, nh[kt], hacc[colt], 0, 0, 0);
      }
    }
    __syncthreads();  // stage-1 LDS reads complete; buffer reusable

    // ---- stage W2 chunk c ----
    {
      const _Float16* gb = W2f + ((size_t)(c * 16 + w * 4) * 64 + lane) * 8;
#pragma unroll
      for (int j = 0; j < 4; ++j)
        *(ulonglong2*)&Ws[(w * 4 + j) * 512 + lane * 8] =
            *(const ulonglong2*)(gb + (size_t)j * 512);
    }

    // ---- bias + relu + pack to f16 pairs (overlaps staging) ----
    u32 P01[4], P23[4];  // [colt]
#pragma unroll
    for (int colt = 0; colt < 4; ++colt) {
      float4 b1v = ld4(b1g + c * 64 + colt * 16 + q * 4);
      float v0 = fmaxf(hacc[colt][0] + b1v.x, 0.f);
      float v1 = fmaxf(hacc[colt][1] + b1v.y, 0.f);
      float v2 = fmaxf(hacc[colt][2] + b1v.z, 0.f);
      float v3 = fmaxf(hacc[colt][3] + b1v.w, 0.f);
      P01[colt] = packh2(v0, v1);
      P23[colt] = packh2(v2, v3);
    }
    __syncthreads();  // W2 staged

    // ---- stage 2: quad-permute hmid into B-frags, multiply with W2 from LDS ----
#pragma unroll
    for (int ktl = 0; ktl < 2; ++ktl) {
      half8 bh;
      {
        union { u32 d[4]; half8 s; } uh;
        int c0 = 2 * ktl, c1 = 2 * ktl + 1;
        u32 a0, a1;
        a0 = (u32)__shfl((int)P01[c0], srcA); a1 = (u32)__shfl((int)P01[c1], srcA);
        uh.d[0] = sel ? a1 : a0;
        a0 = (u32)__shfl((int)P23[c0], srcA); a1 = (u32)__shfl((int)P23[c1], srcA);
        uh.d[1] = sel ? a1 : a0;
        a0 = (u32)__shfl((int)P01[c0], srcB); a1 = (u32)__shfl((int)P01[c1], srcB);
        uh.d[2] = sel ? a1 : a0;
        a0 = (u32)__shfl((int)P23[c0], srcB); a1 = (u32)__shfl((int)P23[c1], srcB);
        uh.d[3] = sel ? a1 : a0;
        bh = uh.s;
      }
#pragma unroll
      for (int nt = 0; nt < 8; ++nt) {
        half8 wh = *(const half8*)&Ws[(ktl * 8 + nt) * 512 + lane * 8];
        oacc[nt] = __builtin_amdgcn_mfma_f32_16x16x32_f16(wh, bh, oacc[nt], 0, 0, 0);
      }
    }
  }

  // ---- epilogue: +b2, float4 store, BN partials into slot ----
  const int node = n0 + l15;
#pragma unroll
  for (int nt = 0; nt < 8; ++nt) {
    int ocb = nt * 16 + q * 4;  // 4 consecutive out cols per lane
    float4 b2v = ld4(b2g + ocb);
    f32x4 s = (f32x4){0.f, 0.f, 0.f, 0.f};
    f32x4 s2 = (f32x4){0.f, 0.f, 0.f, 0.f};
    if (node < NN) {
      float4 v;
      v.x = oacc[nt][0] + b2v.x;
      v.y = oacc[nt][1] + b2v.y;
      v.z = oacc[nt][2] + b2v.z;
      v.w = oacc[nt][3] + b2v.w;
      *(float4*)(hpre + (size_t)node * EMB + ocb) = v;
      s[0] = v.x; s[1] = v.y; s[2] = v.z; s[3] = v.w;
      s2[0] = v.x * v.x; s2[1] = v.y * v.y; s2[2] = v.z * v.z; s2[3] = v.w * v.w;
    }
#pragma unroll
    for (int d = 1; d < 16; d <<= 1) {
#pragma unroll
      for (int r = 0; r < 4; ++r) {
        s[r] += __shfl_xor(s[r], d);
        s2[r] += __shfl_xor(s2[r], d);
      }
    }
    if (l15 == 0) {
#pragma unroll
      for (int r = 0; r < 4; ++r) {
        atomicAdd(&sums[ocb + r], s[r]);
        atomicAdd(&sums[128 + ocb + r], s2[r]);
      }
    }
  }
}

// ---------------- BN apply: reduce 32 slots in LDS, then normalize ----------------
template <bool LAST>
__global__ __launch_bounds__(256) void bn_apply_kernel(
    const float* __restrict__ hp, const float* __restrict__ slots,
    const float* __restrict__ gamma, const float* __restrict__ beta,
    _Float16* __restrict__ hb, float* __restrict__ out) {
  __shared__ float ssc[128], ssh[128];
  int t = threadIdx.x;
  if (t < 128) {
    float s = 0.f, s2 = 0.f;
#pragma unroll 8
    for (int k = 0; k < 32; ++k) {
      s += slots[k * 256 + t];
      s2 += slots[k * 256 + 128 + t];
    }
    float mean = s * (1.0f / NN);
    float var = s2 * (1.0f / NN) - mean * mean;  // biased
    float sc = gamma[t] * rsqrtf(var + 1e-5f);
    ssc[t] = sc;
    ssh[t] = beta[t] - mean * sc;
  }
  __syncthreads();
  int tid = blockIdx.x * blockDim.x + t;
  int n = tid >> 4;
  if (n >= NN) return;
  int kc = tid & 15;
  const float* p = hp + (size_t)n * EMB + kc * 8;
  float4 va = ld4(p), vb = ld4(p + 4);
  float v[8] = {va.x, va.y, va.z, va.w, vb.x, vb.y, vb.z, vb.w};
#pragma unroll
  for (int j = 0; j < 8; ++j) v[j] = v[j] * ssc[kc * 8 + j] + ssh[kc * 8 + j];
  if (LAST) {
    float* d = out + (size_t)n * EMB + kc * 8;
    *(float4*)d = make_float4(v[0], v[1], v[2], v[3]);
    *(float4*)(d + 4) = make_float4(v[4], v[5], v[6], v[7]);
  } else {
    _Float16 o[8];
#pragma unroll
    for (int j = 0; j < 8; ++j) o[j] = (_Float16)fmaxf(v[j], 0.f);
    *(ulonglong2*)(hb + (size_t)n * EMB + kc * 8) = *(ulonglong2*)o;
  }
}

// ---------------- launch ----------------
extern "C" void kernel_launch(void* const* d_in, const int* in_sizes, int n_in,
                              void* d_out, int out_size, void* d_ws, size_t ws_size,
                              hipStream_t stream) {
  const int* x = (const int*)d_in[0];
  const int* ei = (const int*)d_in[1];
  const int* ea = (const int*)d_in[2];
  const float* x_emb1 = (const float*)d_in[3];
  const float* x_emb2 = (const float*)d_in[4];
  const float* ee1 = (const float*)d_in[5];
  const float* ee2 = (const float*)d_in[6];
  const float* W1 = (const float*)d_in[7];
  const float* b1 = (const float*)d_in[8];
  const float* W2 = (const float*)d_in[9];
  const float* b2 = (const float*)d_in[10];
  const float* eps = (const float*)d_in[11];
  const float* gamma = (const float*)d_in[12];
  const float* beta = (const float*)d_in[13];
  float* out = (float*)d_out;

  // workspace layout (16B-aligned sections)
  float* hpre = (float*)d_ws;                   // NN*128 f32
  float* slots = hpre + (size_t)NN * EMB;       // 5*32*256 BN partial slots
  float* combos = slots + 5 * 32 * 256;         // 9600
  _Float16* Af = (_Float16*)(combos + 9600);    // NPAD*128 f16
  _Float16* hb = Af + (size_t)NPAD * EMB;       // NN*128 f16
  _Float16* W1f = hb + (size_t)NN * EMB;        // 5*32768 f16
  _Float16* W2f = W1f + 5 * 32768;              // 5*32768 f16
  int* deg = (int*)(W2f + 5 * 32768);           // NN
  int* off = deg + NN;                          // NN+1
  int* csr = off + NN + 1;                      // NE
  int* bsum = csr + NE;                         // 128

  const int NB_SCAN = (NN + 1023) / 1024;

  // one-time per launch: CSR + combo tables + frag-ordered f16 weights
  hipMemsetAsync(deg, 0, NN * sizeof(int), stream);
  hipMemsetAsync(slots, 0, 5 * 32 * 256 * sizeof(float), stream);
  hist_kernel<<<(NE + 255) / 256, 256, 0, stream>>>(ei, deg);
  scan1_kernel<<<NB_SCAN, 256, 0, stream>>>(deg, off, bsum);
  scan2_kernel<<<1, 64, 0, stream>>>(bsum, off, NB_SCAN);
  scan3_kernel<<<(NN + 255) / 256, 256, 0, stream>>>(off, bsum);
  hipMemsetAsync(deg, 0, NN * sizeof(int), stream);
  scatter_kernel<<<(NE + 255) / 256, 256, 0, stream>>>(ei, ea, off, deg, csr);
  combo_kernel<<<(5 * 15 * 128 + 255) / 256, 256, 0, stream>>>(ee1, ee2, combos);
  prep_w_kernel<<<160, 256, 0, stream>>>(W1, W2, W1f, W2f);
  node_init_kernel<<<NN * 16 / 256 + 1, 256, 0, stream>>>(x, x_emb1, x_emb2, hb);

  const int NBLK = NPAD / 64;  // 1564 blocks x 4 waves (16 nodes each)
  for (int i = 0; i < 5; ++i) {
    agg_kernel<<<NPAD * 16 / 256, 256, 0, stream>>>(
        hb, off, csr, combos + (size_t)i * 15 * EMB, eps + i, Af);
    mlp_kernel<<<NBLK, 256, 0, stream>>>(
        Af, W1f + (size_t)i * 32768, W2f + (size_t)i * 32768,
        b1 + (size_t)i * 256, b2 + (size_t)i * 128, hpre,
        slots + (size_t)i * 32 * 256);
    if (i < 4)
      bn_apply_kernel<false><<<NN * 16 / 256 + 1, 256, 0, stream>>>(
          hpre, slots + (size_t)i * 32 * 256, gamma + (size_t)i * EMB,
          beta + (size_t)i * EMB, hb, nullptr);
    else
      bn_apply_kernel<true><<<NN * 16 / 256 + 1, 256, 0, stream>>>(
          hpre, slots + (size_t)i * 32 * 256, gamma + (size_t)i * EMB,
          beta + (size_t)i * EMB, nullptr, out);
  }
}

// Round 12
// 692.196 us; speedup vs baseline: 2.5227x; 1.0031x over previous
//
#include <hip/hip_runtime.h>

#define NN 100000
#define NPAD 100096   // 6256 * 16, padded row count for guard-free GEMM
#define NE 600000
#define EMB 128

typedef unsigned short u16;
typedef unsigned int u32;
typedef unsigned long long u64;
typedef _Float16 half8 __attribute__((ext_vector_type(8)));
typedef float f32x4 __attribute__((ext_vector_type(4)));

__device__ __forceinline__ float4 ld4(const float* p) { return *(const float4*)p; }
__device__ __forceinline__ u32 packh2(float a, float b) {  // two f32 -> packed f16 pair
  union { _Float16 h[2]; u32 d; } u;
  u.h[0] = (_Float16)a;
  u.h[1] = (_Float16)b;
  return u.d;
}

// ---------------- node embedding init: hb(f16) = emb1[x0] + emb2[x1] ----------------
__global__ __launch_bounds__(256) void node_init_kernel(
    const int* __restrict__ x, const float* __restrict__ emb1,
    const float* __restrict__ emb2, _Float16* __restrict__ hb) {
  int tid = blockIdx.x * blockDim.x + threadIdx.x;
  int n = tid >> 4;
  if (n >= NN) return;
  int kc = tid & 15;
  int x0 = min(max(x[2 * n], 0), 118);
  int x1 = min(max(x[2 * n + 1], 0), 2);  // x[:,1] sampled 0..118 -> clip to NUM_CHIR-1
  const float* p1 = emb1 + (size_t)x0 * EMB + kc * 8;
  const float* p2 = emb2 + (size_t)x1 * EMB + kc * 8;
  _Float16 o[8];
#pragma unroll
  for (int j = 0; j < 8; ++j) o[j] = (_Float16)(p1[j] + p2[j]);
  *(ulonglong2*)(hb + (size_t)n * EMB + kc * 8) = *(ulonglong2*)o;
}

// ---------------- CSR build ----------------
__global__ __launch_bounds__(256) void hist_kernel(const int* __restrict__ ei,
                                                   int* __restrict__ deg) {
  int e = blockIdx.x * blockDim.x + threadIdx.x;
  if (e >= NE) return;
  atomicAdd(&deg[ei[NE + e]], 1);
}

__global__ __launch_bounds__(256) void scan1_kernel(const int* __restrict__ deg,
                                                    int* __restrict__ off,
                                                    int* __restrict__ bsum) {
  __shared__ int s[256];
  int t = threadIdx.x;
  int base = blockIdx.x * 1024 + t * 4;
  int v[4];
#pragma unroll
  for (int j = 0; j < 4; ++j) {
    int idx = base + j;
    v[j] = (idx < NN) ? deg[idx] : 0;
  }
  int tsum = v[0] + v[1] + v[2] + v[3];
  s[t] = tsum;
  __syncthreads();
  for (int d = 1; d < 256; d <<= 1) {
    int add = (t >= d) ? s[t - d] : 0;
    __syncthreads();
    s[t] += add;
    __syncthreads();
  }
  int run = s[t] - tsum;
#pragma unroll
  for (int j = 0; j < 4; ++j) {
    int idx = base + j;
    if (idx < NN) off[idx] = run;
    run += v[j];
  }
  if (t == 255) bsum[blockIdx.x] = s[255];
}

__global__ void scan2_kernel(int* __restrict__ bsum, int* __restrict__ off, int nb) {
  if (threadIdx.x == 0) {
    int run = 0;
    for (int b = 0; b < nb; ++b) {
      int v = bsum[b];
      bsum[b] = run;
      run += v;
    }
    off[NN] = run;
  }
}

__global__ __launch_bounds__(256) void scan3_kernel(int* __restrict__ off,
                                                    const int* __restrict__ bsum) {
  int idx = blockIdx.x * blockDim.x + threadIdx.x;
  if (idx < NN) off[idx] += bsum[idx >> 10];
}

__global__ __launch_bounds__(256) void scatter_kernel(
    const int* __restrict__ ei, const int* __restrict__ ea,
    const int* __restrict__ off, int* __restrict__ cnt, int* __restrict__ csr) {
  int e = blockIdx.x * blockDim.x + threadIdx.x;
  if (e >= NE) return;
  int d = ei[NE + e];
  int s = ei[e];
  int a0 = min(max(ea[2 * e], 0), 4);
  int a1 = min(max(ea[2 * e + 1], 0), 2);
  int code = a0 * 3 + a1;  // [0,14]
  int r = atomicAdd(&cnt[d], 1);
  csr[off[d] + r] = s | (code << 20);
}

// combos[l][code][f] = ee1[l][code/3][f] + ee2[l][code%3][f]
__global__ __launch_bounds__(256) void combo_kernel(const float* __restrict__ ee1,
                                                    const float* __restrict__ ee2,
                                                    float* __restrict__ combos) {
  int idx = blockIdx.x * blockDim.x + threadIdx.x;
  if (idx >= 5 * 15 * 128) return;
  int l = idx / (15 * 128);
  int rem = idx % (15 * 128);
  int code = rem / 128;
  int f = rem % 128;
  combos[idx] = ee1[(l * 5 + code / 3) * 128 + f] + ee2[(l * 3 + code % 3) * 128 + f];
}

// ---------------- weight prep: frag-ordered f16 copies of W1/W2 ----------------
__global__ __launch_bounds__(256) void prep_w_kernel(
    const float* __restrict__ W1g, const float* __restrict__ W2g,
    _Float16* __restrict__ W1f, _Float16* __restrict__ W2f) {
  int idx = blockIdx.x * blockDim.x + threadIdx.x;
  if (idx >= 40960) return;
  _Float16 o[8];
  if (idx < 20480) {
    int lane = idx & 63;
    int r = idx >> 6;             // l*64 + c*16 + kt*4 + colt
    int nt = r & 3, kt = (r >> 2) & 3, c = (r >> 4) & 3, l = r >> 6;
    int n = c * 64 + nt * 16 + (lane & 15);
    int kb = kt * 32 + (lane >> 4) * 8;
#pragma unroll
    for (int j = 0; j < 8; ++j) o[j] = (_Float16)W1g[((size_t)l * 128 + kb + j) * 256 + n];
    *(ulonglong2*)(W1f + (size_t)idx * 8) = *(ulonglong2*)o;
  } else {
    int i2 = idx - 20480;
    int lane = i2 & 63;
    int r = i2 >> 6;              // l*64 + c*16 + ktl*8 + nt
    int nt = r & 7, ktl = (r >> 3) & 1, c = (r >> 4) & 3, l = r >> 6;
    int n = nt * 16 + (lane & 15);
    int kb = c * 64 + ktl * 32 + (lane >> 4) * 8;
#pragma unroll
    for (int j = 0; j < 8; ++j) o[j] = (_Float16)W2g[((size_t)l * 256 + kb + j) * 128 + n];
    *(ulonglong2*)(W2f + (size_t)i2 * 8) = *(ulonglong2*)o;
  }
}

// ---------------- agg: Af = (1+eps)*h + relu(h+c0) + sum relu(h[src]+c) ----------------
// NORM: h = relu(hsrc*sc + sh)  (BN of previous layer fused into the gather).
template <bool NORM>
__global__ __launch_bounds__(256) void agg_kernel(
    const _Float16* __restrict__ hsrc, const float* __restrict__ scsh,
    const int* __restrict__ off, const int* __restrict__ csr,
    const float* __restrict__ cb, const float* __restrict__ epsp,
    _Float16* __restrict__ Af) {
  int tid = blockIdx.x * blockDim.x + threadIdx.x;
  int g = tid >> 4;
  int kc = tid & 15;
  float av[8] = {0.f, 0.f, 0.f, 0.f, 0.f, 0.f, 0.f, 0.f};
  float scv[8], shv[8];
  if (NORM) {
    float4 sa = ld4(scsh + kc * 8), sb = ld4(scsh + kc * 8 + 4);
    float4 ha = ld4(scsh + 128 + kc * 8), hbv = ld4(scsh + 128 + kc * 8 + 4);
    scv[0] = sa.x; scv[1] = sa.y; scv[2] = sa.z; scv[3] = sa.w;
    scv[4] = sb.x; scv[5] = sb.y; scv[6] = sb.z; scv[7] = sb.w;
    shv[0] = ha.x; shv[1] = ha.y; shv[2] = ha.z; shv[3] = ha.w;
    shv[4] = hbv.x; shv[5] = hbv.y; shv[6] = hbv.z; shv[7] = hbv.w;
  }
  if (g < NN) {
    const float eps1 = 1.0f + *epsp;
    ulonglong2 hraw = *(const ulonglong2*)(hsrc + (size_t)g * EMB + kc * 8);
    _Float16* hr = (_Float16*)&hraw;
    float4 ca = ld4(cb + kc * 8), cbv = ld4(cb + kc * 8 + 4);
    float cs[8] = {ca.x, ca.y, ca.z, ca.w, cbv.x, cbv.y, cbv.z, cbv.w};
#pragma unroll
    for (int j = 0; j < 8; ++j) {
      float hv = (float)hr[j];
      if (NORM) hv = fmaxf(hv * scv[j] + shv[j], 0.f);
      av[j] = eps1 * hv + fmaxf(hv + cs[j], 0.f);
    }
    int s0 = off[g], s1 = off[g + 1];
    int e = s0;
    for (; e + 3 < s1; e += 4) {  // unroll x4: four gather chains in flight
      int p0 = csr[e], p1 = csr[e + 1], p2 = csr[e + 2], p3 = csr[e + 3];
      ulonglong2 r0 = *(const ulonglong2*)(hsrc + (size_t)(p0 & 0xFFFFF) * EMB + kc * 8);
      ulonglong2 r1 = *(const ulonglong2*)(hsrc + (size_t)(p1 & 0xFFFFF) * EMB + kc * 8);
      ulonglong2 r2 = *(const ulonglong2*)(hsrc + (size_t)(p2 & 0xFFFFF) * EMB + kc * 8);
      ulonglong2 r3 = *(const ulonglong2*)(hsrc + (size_t)(p3 & 0xFFFFF) * EMB + kc * 8);
      ulonglong2 rr[4] = {r0, r1, r2, r3};
      int pp[4] = {p0, p1, p2, p3};
#pragma unroll
      for (int u = 0; u < 4; ++u) {
        const float* cp = cb + (size_t)(pp[u] >> 20) * EMB + kc * 8;
        float4 c0 = ld4(cp), c1 = ld4(cp + 4);
        float cc[8] = {c0.x, c0.y, c0.z, c0.w, c1.x, c1.y, c1.z, c1.w};
        _Float16* sp = (_Float16*)&rr[u];
#pragma unroll
        for (int j = 0; j < 8; ++j) {
          float v = (float)sp[j];
          if (NORM) v = fmaxf(v * scv[j] + shv[j], 0.f);
          av[j] += fmaxf(v + cc[j], 0.f);
        }
      }
    }
    for (; e < s1; ++e) {
      int p0 = csr[e];
      ulonglong2 r0 = *(const ulonglong2*)(hsrc + (size_t)(p0 & 0xFFFFF) * EMB + kc * 8);
      const float* cp = cb + (size_t)(p0 >> 20) * EMB + kc * 8;
      float4 c0 = ld4(cp), c1 = ld4(cp + 4);
      float cc[8] = {c0.x, c0.y, c0.z, c0.w, c1.x, c1.y, c1.z, c1.w};
      _Float16* sp = (_Float16*)&r0;
#pragma unroll
      for (int j = 0; j < 8; ++j) {
        float v = (float)sp[j];
        if (NORM) v = fmaxf(v * scv[j] + shv[j], 0.f);
        av[j] += fmaxf(v + cc[j], 0.f);
      }
    }
  }
  _Float16 o[8];
#pragma unroll
  for (int j = 0; j < 8; ++j) o[j] = (_Float16)av[j];
  *(ulonglong2*)(Af + (size_t)g * EMB + kc * 8) = *(ulonglong2*)o;  // zeros for pad rows
}

// ---------------- mlp: f16, 16 nodes/wave, A in regs, W1+W2 staged together (2 barriers/chunk) ----------------
__global__ __launch_bounds__(256, 4) void mlp_kernel(
    const _Float16* __restrict__ Af, const _Float16* __restrict__ W1f,
    const _Float16* __restrict__ W2f,
    const float* __restrict__ b1g, const float* __restrict__ b2g,
    _Float16* __restrict__ hpre, float* __restrict__ slots) {
  __shared__ __align__(16) _Float16 Ws[2 * 16 * 64 * 8];  // 32KB: W1 chunk | W2 chunk

  const int t = threadIdx.x;
  const int w = t >> 6;
  const int lane = t & 63;
  const int q = lane >> 4, l15 = lane & 15;
  const int gw = blockIdx.x * 4 + w;   // global wave id, 0..6255
  const int n0 = gw * 16;              // 16 nodes per wave
  float* sums = slots + (size_t)(gw & 31) * 256;

  // ---- A fragments loaded ONCE, held across all chunks ----
  half8 nh[4];
#pragma unroll
  for (int kt = 0; kt < 4; ++kt)
    nh[kt] = *(const half8*)(Af + (size_t)(n0 + l15) * EMB + kt * 32 + q * 8);

  f32x4 oacc[8];  // [out col tile]
#pragma unroll
  for (int a = 0; a < 8; ++a) oacc[a] = (f32x4){0.f, 0.f, 0.f, 0.f};

  const int srcA = ((q & 1) * 2) * 16 + l15;  // quad permutation sources
  const int srcB = srcA + 16;
  const bool sel = (q >> 1) != 0;

  for (int c = 0; c < 4; ++c) {
    __syncthreads();  // prev chunk's LDS reads complete
    // ---- stage W1 chunk (-> Ws[0:8192]) and W2 chunk (-> Ws[8192:]) ----
    {
      const _Float16* g1 = W1f + ((size_t)(c * 16 + w * 4) * 64 + lane) * 8;
      const _Float16* g2 = W2f + ((size_t)(c * 16 + w * 4) * 64 + lane) * 8;
#pragma unroll
      for (int j = 0; j < 4; ++j) {
        *(ulonglong2*)&Ws[(w * 4 + j) * 512 + lane * 8] =
            *(const ulonglong2*)(g1 + (size_t)j * 512);
        *(ulonglong2*)&Ws[8192 + (w * 4 + j) * 512 + lane * 8] =
            *(const ulonglong2*)(g2 + (size_t)j * 512);
      }
    }
    __syncthreads();

    // ---- stage 1: hmidT[col c*64+colt*16+q*4+r][node l15] ----
    f32x4 hacc[4];
#pragma unroll
    for (int a = 0; a < 4; ++a) hacc[a] = (f32x4){0.f, 0.f, 0.f, 0.f};
#pragma unroll
    for (int kt = 0; kt < 4; ++kt) {
#pragma unroll
      for (int colt = 0; colt < 4; ++colt) {
        half8 wh = *(const half8*)&Ws[(kt * 4 + colt) * 512 + lane * 8];
        hacc[colt] = __builtin_amdgcn_mfma_f32_16x16x32_f16(wh, nh[kt], hacc[colt], 0, 0, 0);
      }
    }

    // ---- bias + relu + pack to f16 pairs ----
    u32 P01[4], P23[4];  // [colt]
#pragma unroll
    for (int colt = 0; colt < 4; ++colt) {
      float4 b1v = ld4(b1g + c * 64 + colt * 16 + q * 4);
      float v0 = fmaxf(hacc[colt][0] + b1v.x, 0.f);
      float v1 = fmaxf(hacc[colt][1] + b1v.y, 0.f);
      float v2 = fmaxf(hacc[colt][2] + b1v.z, 0.f);
      float v3 = fmaxf(hacc[colt][3] + b1v.w, 0.f);
      P01[colt] = packh2(v0, v1);
      P23[colt] = packh2(v2, v3);
    }

    // ---- stage 2: quad-permute hmid into B-frags, multiply with W2 from LDS ----
#pragma unroll
    for (int ktl = 0; ktl < 2; ++ktl) {
      half8 bh;
      {
        union { u32 d[4]; half8 s; } uh;
        int c0 = 2 * ktl, c1 = 2 * ktl + 1;
        u32 a0, a1;
        a0 = (u32)__shfl((int)P01[c0], srcA); a1 = (u32)__shfl((int)P01[c1], srcA);
        uh.d[0] = sel ? a1 : a0;
        a0 = (u32)__shfl((int)P23[c0], srcA); a1 = (u32)__shfl((int)P23[c1], srcA);
        uh.d[1] = sel ? a1 : a0;
        a0 = (u32)__shfl((int)P01[c0], srcB); a1 = (u32)__shfl((int)P01[c1], srcB);
        uh.d[2] = sel ? a1 : a0;
        a0 = (u32)__shfl((int)P23[c0], srcB); a1 = (u32)__shfl((int)P23[c1], srcB);
        uh.d[3] = sel ? a1 : a0;
        bh = uh.s;
      }
#pragma unroll
      for (int nt = 0; nt < 8; ++nt) {
        half8 wh = *(const half8*)&Ws[8192 + (ktl * 8 + nt) * 512 + lane * 8];
        oacc[nt] = __builtin_amdgcn_mfma_f32_16x16x32_f16(wh, bh, oacc[nt], 0, 0, 0);
      }
    }
  }

  // ---- epilogue: +b2, f16 store (8B), BN partials into slot ----
  const int node = n0 + l15;
#pragma unroll
  for (int nt = 0; nt < 8; ++nt) {
    int ocb = nt * 16 + q * 4;  // 4 consecutive out cols per lane
    float4 b2v = ld4(b2g + ocb);
    f32x4 s = (f32x4){0.f, 0.f, 0.f, 0.f};
    f32x4 s2 = (f32x4){0.f, 0.f, 0.f, 0.f};
    if (node < NN) {
      float v0 = oacc[nt][0] + b2v.x;
      float v1 = oacc[nt][1] + b2v.y;
      float v2 = oacc[nt][2] + b2v.z;
      float v3 = oacc[nt][3] + b2v.w;
      u64 pk = (u64)packh2(v0, v1) | ((u64)packh2(v2, v3) << 32);
      *(u64*)(hpre + (size_t)node * EMB + ocb) = pk;
      s[0] = v0; s[1] = v1; s[2] = v2; s[3] = v3;
      s2[0] = v0 * v0; s2[1] = v1 * v1; s2[2] = v2 * v2; s2[3] = v3 * v3;
    }
#pragma unroll
    for (int d = 1; d < 16; d <<= 1) {
#pragma unroll
      for (int r = 0; r < 4; ++r) {
        s[r] += __shfl_xor(s[r], d);
        s2[r] += __shfl_xor(s2[r], d);
      }
    }
    if (l15 == 0) {
#pragma unroll
      for (int r = 0; r < 4; ++r) {
        atomicAdd(&sums[ocb + r], s[r]);
        atomicAdd(&sums[128 + ocb + r], s2[r]);
      }
    }
  }
}

// ---------------- stats: reduce 32 slots -> scale/shift (sc, sh) ----------------
__global__ void stats_kernel(const float* __restrict__ slots,
                             const float* __restrict__ gamma,
                             const float* __restrict__ beta,
                             float* __restrict__ scsh) {
  int f = threadIdx.x;  // 128
  float s = 0.f, s2 = 0.f;
#pragma unroll 8
  for (int k = 0; k < 32; ++k) {
    s += slots[k * 256 + f];
    s2 += slots[k * 256 + 128 + f];
  }
  float mean = s * (1.0f / NN);
  float var = s2 * (1.0f / NN) - mean * mean;  // biased
  float sc = gamma[f] * rsqrtf(var + 1e-5f);
  scsh[f] = sc;
  scsh[128 + f] = beta[f] - mean * sc;
}

// ---------------- final output: out = hpre*sc + sh (f32, no relu) ----------------
__global__ __launch_bounds__(256) void out_kernel(
    const _Float16* __restrict__ hpre, const float* __restrict__ scsh,
    float* __restrict__ out) {
  int tid = blockIdx.x * blockDim.x + threadIdx.x;
  int n = tid >> 4;
  if (n >= NN) return;
  int kc = tid & 15;
  ulonglong2 raw = *(const ulonglong2*)(hpre + (size_t)n * EMB + kc * 8);
  _Float16* hr = (_Float16*)&raw;
  float4 sa = ld4(scsh + kc * 8), sb = ld4(scsh + kc * 8 + 4);
  float4 ha = ld4(scsh + 128 + kc * 8), hbv = ld4(scsh + 128 + kc * 8 + 4);
  float scv[8] = {sa.x, sa.y, sa.z, sa.w, sb.x, sb.y, sb.z, sb.w};
  float shv[8] = {ha.x, ha.y, ha.z, ha.w, hbv.x, hbv.y, hbv.z, hbv.w};
  float v[8];
#pragma unroll
  for (int j = 0; j < 8; ++j) v[j] = (float)hr[j] * scv[j] + shv[j];
  float* d = out + (size_t)n * EMB + kc * 8;
  *(float4*)d = make_float4(v[0], v[1], v[2], v[3]);
  *(float4*)(d + 4) = make_float4(v[4], v[5], v[6], v[7]);
}

// ---------------- launch ----------------
extern "C" void kernel_launch(void* const* d_in, const int* in_sizes, int n_in,
                              void* d_out, int out_size, void* d_ws, size_t ws_size,
                              hipStream_t stream) {
  const int* x = (const int*)d_in[0];
  const int* ei = (const int*)d_in[1];
  const int* ea = (const int*)d_in[2];
  const float* x_emb1 = (const float*)d_in[3];
  const float* x_emb2 = (const float*)d_in[4];
  const float* ee1 = (const float*)d_in[5];
  const float* ee2 = (const float*)d_in[6];
  const float* W1 = (const float*)d_in[7];
  const float* b1 = (const float*)d_in[8];
  const float* W2 = (const float*)d_in[9];
  const float* b2 = (const float*)d_in[10];
  const float* eps = (const float*)d_in[11];
  const float* gamma = (const float*)d_in[12];
  const float* beta = (const float*)d_in[13];
  float* out = (float*)d_out;

  // workspace layout (16B-aligned sections)
  float* slots = (float*)d_ws;                  // 5*32*256 BN partial slots
  float* scsh = slots + 5 * 32 * 256;           // 5*256 scale/shift
  float* combos = scsh + 5 * 256;               // 9600
  _Float16* hpre = (_Float16*)(combos + 9600);  // NN*128 f16
  _Float16* Af = hpre + (size_t)NN * EMB;       // NPAD*128 f16
  _Float16* hb = Af + (size_t)NPAD * EMB;       // NN*128 f16
  _Float16* W1f = hb + (size_t)NN * EMB;        // 5*32768 f16
  _Float16* W2f = W1f + 5 * 32768;              // 5*32768 f16
  int* deg = (int*)(W2f + 5 * 32768);           // NN
  int* off = deg + NN;                          // NN+1
  int* csr = off + NN + 1;                      // NE
  int* bsum = csr + NE;                         // 128

  const int NB_SCAN = (NN + 1023) / 1024;

  // one-time per launch: CSR + combo tables + frag-ordered f16 weights
  hipMemsetAsync(deg, 0, NN * sizeof(int), stream);
  hipMemsetAsync(slots, 0, 5 * 32 * 256 * sizeof(float), stream);
  hist_kernel<<<(NE + 255) / 256, 256, 0, stream>>>(ei, deg);
  scan1_kernel<<<NB_SCAN, 256, 0, stream>>>(deg, off, bsum);
  scan2_kernel<<<1, 64, 0, stream>>>(bsum, off, NB_SCAN);
  scan3_kernel<<<(NN + 255) / 256, 256, 0, stream>>>(off, bsum);
  hipMemsetAsync(deg, 0, NN * sizeof(int), stream);
  scatter_kernel<<<(NE + 255) / 256, 256, 0, stream>>>(ei, ea, off, deg, csr);
  combo_kernel<<<(5 * 15 * 128 + 255) / 256, 256, 0, stream>>>(ee1, ee2, combos);
  prep_w_kernel<<<160, 256, 0, stream>>>(W1, W2, W1f, W2f);
  node_init_kernel<<<NN * 16 / 256 + 1, 256, 0, stream>>>(x, x_emb1, x_emb2, hb);

  const int NBLK = NPAD / 64;  // 1564 blocks x 4 waves (16 nodes each)
  for (int i = 0; i < 5; ++i) {
    if (i == 0)
      agg_kernel<false><<<NPAD * 16 / 256, 256, 0, stream>>>(
          hb, nullptr, off, csr, combos + (size_t)i * 15 * EMB, eps + i, Af);
    else
      agg_kernel<true><<<NPAD * 16 / 256, 256, 0, stream>>>(
          hpre, scsh + (size_t)(i - 1) * 256, off, csr,
          combos + (size_t)i * 15 * EMB, eps + i, Af);
    mlp_kernel<<<NBLK, 256, 0, stream>>>(
        Af, W1f + (size_t)i * 32768, W2f + (size_t)i * 32768,
        b1 + (size_t)i * 256, b2 + (size_t)i * 128, hpre,
        slots + (size_t)i * 32 * 256);
    stats_kernel<<<1, 128, 0, stream>>>(slots + (size_t)i * 32 * 256,
                                        gamma + (size_t)i * EMB,
                                        beta + (size_t)i * EMB,
                                        scsh + (size_t)i * 256);
  }
  out_kernel<<<NN * 16 / 256 + 1, 256, 0, stream>>>(hpre, scsh + 4 * 256, out);
}

// Round 13
// 671.735 us; speedup vs baseline: 2.5996x; 1.0305x over previous
//
#include <hip/hip_runtime.h>

#define NN 100000
#define NPAD 100096   // 6256 * 16, padded row count for guard-free GEMM
#define NE 600000
#define EMB 128

typedef unsigned short u16;
typedef unsigned int u32;
typedef unsigned long long u64;
typedef _Float16 half8 __attribute__((ext_vector_type(8)));
typedef float f32x4 __attribute__((ext_vector_type(4)));

__device__ __forceinline__ float4 ld4(const float* p) { return *(const float4*)p; }
__device__ __forceinline__ u32 packh2(float a, float b) {  // two f32 -> packed f16 pair
  union { _Float16 h[2]; u32 d; } u;
  u.h[0] = (_Float16)a;
  u.h[1] = (_Float16)b;
  return u.d;
}

// ---------------- node embedding init: hb(f16) = emb1[x0] + emb2[x1] ----------------
__global__ __launch_bounds__(256) void node_init_kernel(
    const int* __restrict__ x, const float* __restrict__ emb1,
    const float* __restrict__ emb2, _Float16* __restrict__ hb) {
  int tid = blockIdx.x * blockDim.x + threadIdx.x;
  int n = tid >> 4;
  if (n >= NN) return;
  int kc = tid & 15;
  int x0 = min(max(x[2 * n], 0), 118);
  int x1 = min(max(x[2 * n + 1], 0), 2);  // x[:,1] sampled 0..118 -> clip to NUM_CHIR-1
  const float* p1 = emb1 + (size_t)x0 * EMB + kc * 8;
  const float* p2 = emb2 + (size_t)x1 * EMB + kc * 8;
  _Float16 o[8];
#pragma unroll
  for (int j = 0; j < 8; ++j) o[j] = (_Float16)(p1[j] + p2[j]);
  *(ulonglong2*)(hb + (size_t)n * EMB + kc * 8) = *(ulonglong2*)o;
}

// ---------------- CSR build ----------------
__global__ __launch_bounds__(256) void hist_kernel(const int* __restrict__ ei,
                                                   int* __restrict__ deg) {
  int e = blockIdx.x * blockDim.x + threadIdx.x;
  if (e >= NE) return;
  atomicAdd(&deg[ei[NE + e]], 1);
}

__global__ __launch_bounds__(256) void scan1_kernel(const int* __restrict__ deg,
                                                    int* __restrict__ off,
                                                    int* __restrict__ bsum) {
  __shared__ int s[256];
  int t = threadIdx.x;
  int base = blockIdx.x * 1024 + t * 4;
  int v[4];
#pragma unroll
  for (int j = 0; j < 4; ++j) {
    int idx = base + j;
    v[j] = (idx < NN) ? deg[idx] : 0;
  }
  int tsum = v[0] + v[1] + v[2] + v[3];
  s[t] = tsum;
  __syncthreads();
  for (int d = 1; d < 256; d <<= 1) {
    int add = (t >= d) ? s[t - d] : 0;
    __syncthreads();
    s[t] += add;
    __syncthreads();
  }
  int run = s[t] - tsum;
#pragma unroll
  for (int j = 0; j < 4; ++j) {
    int idx = base + j;
    if (idx < NN) off[idx] = run;
    run += v[j];
  }
  if (t == 255) bsum[blockIdx.x] = s[255];
}

__global__ void scan2_kernel(int* __restrict__ bsum, int* __restrict__ off, int nb) {
  if (threadIdx.x == 0) {
    int run = 0;
    for (int b = 0; b < nb; ++b) {
      int v = bsum[b];
      bsum[b] = run;
      run += v;
    }
    off[NN] = run;
  }
}

__global__ __launch_bounds__(256) void scan3_kernel(int* __restrict__ off,
                                                    const int* __restrict__ bsum) {
  int idx = blockIdx.x * blockDim.x + threadIdx.x;
  if (idx < NN) off[idx] += bsum[idx >> 10];
}

__global__ __launch_bounds__(256) void scatter_kernel(
    const int* __restrict__ ei, const int* __restrict__ ea,
    const int* __restrict__ off, int* __restrict__ cnt, int* __restrict__ csr) {
  int e = blockIdx.x * blockDim.x + threadIdx.x;
  if (e >= NE) return;
  int d = ei[NE + e];
  int s = ei[e];
  int a0 = min(max(ea[2 * e], 0), 4);
  int a1 = min(max(ea[2 * e + 1], 0), 2);
  int code = a0 * 3 + a1;  // [0,14]
  int r = atomicAdd(&cnt[d], 1);
  csr[off[d] + r] = s | (code << 20);
}

// combos[l][code][f] = ee1[l][code/3][f] + ee2[l][code%3][f]
__global__ __launch_bounds__(256) void combo_kernel(const float* __restrict__ ee1,
                                                    const float* __restrict__ ee2,
                                                    float* __restrict__ combos) {
  int idx = blockIdx.x * blockDim.x + threadIdx.x;
  if (idx >= 5 * 15 * 128) return;
  int l = idx / (15 * 128);
  int rem = idx % (15 * 128);
  int code = rem / 128;
  int f = rem % 128;
  combos[idx] = ee1[(l * 5 + code / 3) * 128 + f] + ee2[(l * 3 + code % 3) * 128 + f];
}

// ---------------- weight prep: frag-ordered f16 copies of W1/W2 ----------------
__global__ __launch_bounds__(256) void prep_w_kernel(
    const float* __restrict__ W1g, const float* __restrict__ W2g,
    _Float16* __restrict__ W1f, _Float16* __restrict__ W2f) {
  int idx = blockIdx.x * blockDim.x + threadIdx.x;
  if (idx >= 40960) return;
  _Float16 o[8];
  if (idx < 20480) {
    int lane = idx & 63;
    int r = idx >> 6;             // l*64 + c*16 + kt*4 + colt
    int nt = r & 3, kt = (r >> 2) & 3, c = (r >> 4) & 3, l = r >> 6;
    int n = c * 64 + nt * 16 + (lane & 15);
    int kb = kt * 32 + (lane >> 4) * 8;
#pragma unroll
    for (int j = 0; j < 8; ++j) o[j] = (_Float16)W1g[((size_t)l * 128 + kb + j) * 256 + n];
    *(ulonglong2*)(W1f + (size_t)idx * 8) = *(ulonglong2*)o;
  } else {
    int i2 = idx - 20480;
    int lane = i2 & 63;
    int r = i2 >> 6;              // l*64 + c*16 + ktl*8 + nt
    int nt = r & 7, ktl = (r >> 3) & 1, c = (r >> 4) & 3, l = r >> 6;
    int n = nt * 16 + (lane & 15);
    int kb = c * 64 + ktl * 32 + (lane >> 4) * 8;
#pragma unroll
    for (int j = 0; j < 8; ++j) o[j] = (_Float16)W2g[((size_t)l * 256 + kb + j) * 128 + n];
    *(ulonglong2*)(W2f + (size_t)i2 * 8) = *(ulonglong2*)o;
  }
}

// ---------------- agg: Af = (1+eps)*h + relu(h+c0) + sum relu(h[src]+c) ----------------
// NORM: h = relu(hsrc*sc + sh)  (BN of previous layer fused into the gather).
template <bool NORM>
__global__ __launch_bounds__(256) void agg_kernel(
    const _Float16* __restrict__ hsrc, const float* __restrict__ scsh,
    const int* __restrict__ off, const int* __restrict__ csr,
    const float* __restrict__ cb, const float* __restrict__ epsp,
    _Float16* __restrict__ Af) {
  int tid = blockIdx.x * blockDim.x + threadIdx.x;
  int g = tid >> 4;
  int kc = tid & 15;
  float av[8] = {0.f, 0.f, 0.f, 0.f, 0.f, 0.f, 0.f, 0.f};
  float scv[8], shv[8];
  if (NORM) {
    float4 sa = ld4(scsh + kc * 8), sb = ld4(scsh + kc * 8 + 4);
    float4 ha = ld4(scsh + 128 + kc * 8), hbv = ld4(scsh + 128 + kc * 8 + 4);
    scv[0] = sa.x; scv[1] = sa.y; scv[2] = sa.z; scv[3] = sa.w;
    scv[4] = sb.x; scv[5] = sb.y; scv[6] = sb.z; scv[7] = sb.w;
    shv[0] = ha.x; shv[1] = ha.y; shv[2] = ha.z; shv[3] = ha.w;
    shv[4] = hbv.x; shv[5] = hbv.y; shv[6] = hbv.z; shv[7] = hbv.w;
  }
  if (g < NN) {
    const float eps1 = 1.0f + *epsp;
    ulonglong2 hraw = *(const ulonglong2*)(hsrc + (size_t)g * EMB + kc * 8);
    _Float16* hr = (_Float16*)&hraw;
    float4 ca = ld4(cb + kc * 8), cbv = ld4(cb + kc * 8 + 4);
    float cs[8] = {ca.x, ca.y, ca.z, ca.w, cbv.x, cbv.y, cbv.z, cbv.w};
#pragma unroll
    for (int j = 0; j < 8; ++j) {
      float hv = (float)hr[j];
      if (NORM) hv = fmaxf(hv * scv[j] + shv[j], 0.f);
      av[j] = eps1 * hv + fmaxf(hv + cs[j], 0.f);
    }
    int s0 = off[g], s1 = off[g + 1];
    int e = s0;
    for (; e + 3 < s1; e += 4) {  // unroll x4: four gather chains in flight
      int p0 = csr[e], p1 = csr[e + 1], p2 = csr[e + 2], p3 = csr[e + 3];
      ulonglong2 r0 = *(const ulonglong2*)(hsrc + (size_t)(p0 & 0xFFFFF) * EMB + kc * 8);
      ulonglong2 r1 = *(const ulonglong2*)(hsrc + (size_t)(p1 & 0xFFFFF) * EMB + kc * 8);
      ulonglong2 r2 = *(const ulonglong2*)(hsrc + (size_t)(p2 & 0xFFFFF) * EMB + kc * 8);
      ulonglong2 r3 = *(const ulonglong2*)(hsrc + (size_t)(p3 & 0xFFFFF) * EMB + kc * 8);
      ulonglong2 rr[4] = {r0, r1, r2, r3};
      int pp[4] = {p0, p1, p2, p3};
#pragma unroll
      for (int u = 0; u < 4; ++u) {
        const float* cp = cb + (size_t)(pp[u] >> 20) * EMB + kc * 8;
        float4 c0 = ld4(cp), c1 = ld4(cp + 4);
        float cc[8] = {c0.x, c0.y, c0.z, c0.w, c1.x, c1.y, c1.z, c1.w};
        _Float16* sp = (_Float16*)&rr[u];
#pragma unroll
        for (int j = 0; j < 8; ++j) {
          float v = (float)sp[j];
          if (NORM) v = fmaxf(v * scv[j] + shv[j], 0.f);
          av[j] += fmaxf(v + cc[j], 0.f);
        }
      }
    }
    for (; e < s1; ++e) {
      int p0 = csr[e];
      ulonglong2 r0 = *(const ulonglong2*)(hsrc + (size_t)(p0 & 0xFFFFF) * EMB + kc * 8);
      const float* cp = cb + (size_t)(p0 >> 20) * EMB + kc * 8;
      float4 c0 = ld4(cp), c1 = ld4(cp + 4);
      float cc[8] = {c0.x, c0.y, c0.z, c0.w, c1.x, c1.y, c1.z, c1.w};
      _Float16* sp = (_Float16*)&r0;
#pragma unroll
      for (int j = 0; j < 8; ++j) {
        float v = (float)sp[j];
        if (NORM) v = fmaxf(v * scv[j] + shv[j], 0.f);
        av[j] += fmaxf(v + cc[j], 0.f);
      }
    }
  }
  _Float16 o[8];
#pragma unroll
  for (int j = 0; j < 8; ++j) o[j] = (_Float16)av[j];
  *(ulonglong2*)(Af + (size_t)g * EMB + kc * 8) = *(ulonglong2*)o;  // zeros for pad rows
}

// ---------------- mlp: EXACT R11 structure (16KB Ws, 4-barrier, pack overlaps W2 staging) ----------------
// Only change vs R11: epilogue stores hpre as packed f16 (u64).
__global__ __launch_bounds__(256, 4) void mlp_kernel(
    const _Float16* __restrict__ Af, const _Float16* __restrict__ W1f,
    const _Float16* __restrict__ W2f,
    const float* __restrict__ b1g, const float* __restrict__ b2g,
    _Float16* __restrict__ hpre, float* __restrict__ slots) {
  __shared__ __align__(16) _Float16 Ws[16 * 64 * 8];  // 16KB, W1 then W2 per chunk

  const int t = threadIdx.x;
  const int w = t >> 6;
  const int lane = t & 63;
  const int q = lane >> 4, l15 = lane & 15;
  const int gw = blockIdx.x * 4 + w;   // global wave id, 0..6255
  const int n0 = gw * 16;              // 16 nodes per wave
  float* sums = slots + (size_t)(gw & 31) * 256;

  // ---- A fragments loaded ONCE, held across all chunks ----
  half8 nh[4];
#pragma unroll
  for (int kt = 0; kt < 4; ++kt)
    nh[kt] = *(const half8*)(Af + (size_t)(n0 + l15) * EMB + kt * 32 + q * 8);

  f32x4 oacc[8];  // [out col tile]
#pragma unroll
  for (int a = 0; a < 8; ++a) oacc[a] = (f32x4){0.f, 0.f, 0.f, 0.f};

  const int srcA = ((q & 1) * 2) * 16 + l15;  // quad permutation sources
  const int srcB = srcA + 16;
  const bool sel = (q >> 1) != 0;

  for (int c = 0; c < 4; ++c) {
    __syncthreads();  // prev chunk's stage-2 LDS reads complete
    // ---- stage W1 chunk c (wave w covers frags w*4..w*4+3) ----
    {
      const _Float16* gb = W1f + ((size_t)(c * 16 + w * 4) * 64 + lane) * 8;
#pragma unroll
      for (int j = 0; j < 4; ++j)
        *(ulonglong2*)&Ws[(w * 4 + j) * 512 + lane * 8] =
            *(const ulonglong2*)(gb + (size_t)j * 512);
    }
    __syncthreads();

    // ---- stage 1: hmidT[col c*64+colt*16+q*4+r][node l15] ----
    f32x4 hacc[4];
#pragma unroll
    for (int a = 0; a < 4; ++a) hacc[a] = (f32x4){0.f, 0.f, 0.f, 0.f};
#pragma unroll
    for (int kt = 0; kt < 4; ++kt) {
#pragma unroll
      for (int colt = 0; colt < 4; ++colt) {
        half8 wh = *(const half8*)&Ws[(kt * 4 + colt) * 512 + lane * 8];
        hacc[colt] = __builtin_amdgcn_mfma_f32_16x16x32_f16(wh, nh[kt], hacc[colt], 0, 0, 0);
      }
    }
    __syncthreads();  // stage-1 LDS reads complete; buffer reusable

    // ---- stage W2 chunk c ----
    {
      const _Float16* gb = W2f + ((size_t)(c * 16 + w * 4) * 64 + lane) * 8;
#pragma unroll
      for (int j = 0; j < 4; ++j)
        *(ulonglong2*)&Ws[(w * 4 + j) * 512 + lane * 8] =
            *(const ulonglong2*)(gb + (size_t)j * 512);
    }

    // ---- bias + relu + pack to f16 pairs (overlaps staging) ----
    u32 P01[4], P23[4];  // [colt]
#pragma unroll
    for (int colt = 0; colt < 4; ++colt) {
      float4 b1v = ld4(b1g + c * 64 + colt * 16 + q * 4);
      float v0 = fmaxf(hacc[colt][0] + b1v.x, 0.f);
      float v1 = fmaxf(hacc[colt][1] + b1v.y, 0.f);
      float v2 = fmaxf(hacc[colt][2] + b1v.z, 0.f);
      float v3 = fmaxf(hacc[colt][3] + b1v.w, 0.f);
      P01[colt] = packh2(v0, v1);
      P23[colt] = packh2(v2, v3);
    }
    __syncthreads();  // W2 staged

    // ---- stage 2: quad-permute hmid into B-frags, multiply with W2 from LDS ----
#pragma unroll
    for (int ktl = 0; ktl < 2; ++ktl) {
      half8 bh;
      {
        union { u32 d[4]; half8 s; } uh;
        int c0 = 2 * ktl, c1 = 2 * ktl + 1;
        u32 a0, a1;
        a0 = (u32)__shfl((int)P01[c0], srcA); a1 = (u32)__shfl((int)P01[c1], srcA);
        uh.d[0] = sel ? a1 : a0;
        a0 = (u32)__shfl((int)P23[c0], srcA); a1 = (u32)__shfl((int)P23[c1], srcA);
        uh.d[1] = sel ? a1 : a0;
        a0 = (u32)__shfl((int)P01[c0], srcB); a1 = (u32)__shfl((int)P01[c1], srcB);
        uh.d[2] = sel ? a1 : a0;
        a0 = (u32)__shfl((int)P23[c0], srcB); a1 = (u32)__shfl((int)P23[c1], srcB);
        uh.d[3] = sel ? a1 : a0;
        bh = uh.s;
      }
#pragma unroll
      for (int nt = 0; nt < 8; ++nt) {
        half8 wh = *(const half8*)&Ws[(ktl * 8 + nt) * 512 + lane * 8];
        oacc[nt] = __builtin_amdgcn_mfma_f32_16x16x32_f16(wh, bh, oacc[nt], 0, 0, 0);
      }
    }
  }

  // ---- epilogue: +b2, packed f16 store (8B), BN partials into slot ----
  const int node = n0 + l15;
#pragma unroll
  for (int nt = 0; nt < 8; ++nt) {
    int ocb = nt * 16 + q * 4;  // 4 consecutive out cols per lane
    float4 b2v = ld4(b2g + ocb);
    f32x4 s = (f32x4){0.f, 0.f, 0.f, 0.f};
    f32x4 s2 = (f32x4){0.f, 0.f, 0.f, 0.f};
    if (node < NN) {
      float v0 = oacc[nt][0] + b2v.x;
      float v1 = oacc[nt][1] + b2v.y;
      float v2 = oacc[nt][2] + b2v.z;
      float v3 = oacc[nt][3] + b2v.w;
      u64 pk = (u64)packh2(v0, v1) | ((u64)packh2(v2, v3) << 32);
      *(u64*)(hpre + (size_t)node * EMB + ocb) = pk;
      s[0] = v0; s[1] = v1; s[2] = v2; s[3] = v3;
      s2[0] = v0 * v0; s2[1] = v1 * v1; s2[2] = v2 * v2; s2[3] = v3 * v3;
    }
#pragma unroll
    for (int d = 1; d < 16; d <<= 1) {
#pragma unroll
      for (int r = 0; r < 4; ++r) {
        s[r] += __shfl_xor(s[r], d);
        s2[r] += __shfl_xor(s2[r], d);
      }
    }
    if (l15 == 0) {
#pragma unroll
      for (int r = 0; r < 4; ++r) {
        atomicAdd(&sums[ocb + r], s[r]);
        atomicAdd(&sums[128 + ocb + r], s2[r]);
      }
    }
  }
}

// ---------------- stats: reduce 32 slots -> scale/shift (sc, sh) ----------------
__global__ void stats_kernel(const float* __restrict__ slots,
                             const float* __restrict__ gamma,
                             const float* __restrict__ beta,
                             float* __restrict__ scsh) {
  int f = threadIdx.x;  // 128
  float s = 0.f, s2 = 0.f;
#pragma unroll 8
  for (int k = 0; k < 32; ++k) {
    s += slots[k * 256 + f];
    s2 += slots[k * 256 + 128 + f];
  }
  float mean = s * (1.0f / NN);
  float var = s2 * (1.0f / NN) - mean * mean;  // biased
  float sc = gamma[f] * rsqrtf(var + 1e-5f);
  scsh[f] = sc;
  scsh[128 + f] = beta[f] - mean * sc;
}

// ---------------- final output: out = hpre*sc + sh (f32, no relu) ----------------
__global__ __launch_bounds__(256) void out_kernel(
    const _Float16* __restrict__ hpre, const float* __restrict__ scsh,
    float* __restrict__ out) {
  int tid = blockIdx.x * blockDim.x + threadIdx.x;
  int n = tid >> 4;
  if (n >= NN) return;
  int kc = tid & 15;
  ulonglong2 raw = *(const ulonglong2*)(hpre + (size_t)n * EMB + kc * 8);
  _Float16* hr = (_Float16*)&raw;
  float4 sa = ld4(scsh + kc * 8), sb = ld4(scsh + kc * 8 + 4);
  float4 ha = ld4(scsh + 128 + kc * 8), hbv = ld4(scsh + 128 + kc * 8 + 4);
  float scv[8] = {sa.x, sa.y, sa.z, sa.w, sb.x, sb.y, sb.z, sb.w};
  float shv[8] = {ha.x, ha.y, ha.z, ha.w, hbv.x, hbv.y, hbv.z, hbv.w};
  float v[8];
#pragma unroll
  for (int j = 0; j < 8; ++j) v[j] = (float)hr[j] * scv[j] + shv[j];
  float* d = out + (size_t)n * EMB + kc * 8;
  *(float4*)d = make_float4(v[0], v[1], v[2], v[3]);
  *(float4*)(d + 4) = make_float4(v[4], v[5], v[6], v[7]);
}

// ---------------- launch ----------------
extern "C" void kernel_launch(void* const* d_in, const int* in_sizes, int n_in,
                              void* d_out, int out_size, void* d_ws, size_t ws_size,
                              hipStream_t stream) {
  const int* x = (const int*)d_in[0];
  const int* ei = (const int*)d_in[1];
  const int* ea = (const int*)d_in[2];
  const float* x_emb1 = (const float*)d_in[3];
  const float* x_emb2 = (const float*)d_in[4];
  const float* ee1 = (const float*)d_in[5];
  const float* ee2 = (const float*)d_in[6];
  const float* W1 = (const float*)d_in[7];
  const float* b1 = (const float*)d_in[8];
  const float* W2 = (const float*)d_in[9];
  const float* b2 = (const float*)d_in[10];
  const float* eps = (const float*)d_in[11];
  const float* gamma = (const float*)d_in[12];
  const float* beta = (const float*)d_in[13];
  float* out = (float*)d_out;

  // workspace layout (16B-aligned sections)
  float* slots = (float*)d_ws;                  // 5*32*256 BN partial slots
  float* scsh = slots + 5 * 32 * 256;           // 5*256 scale/shift
  float* combos = scsh + 5 * 256;               // 9600
  _Float16* hpre = (_Float16*)(combos + 9600);  // NN*128 f16
  _Float16* Af = hpre + (size_t)NN * EMB;       // NPAD*128 f16
  _Float16* hb = Af + (size_t)NPAD * EMB;       // NN*128 f16
  _Float16* W1f = hb + (size_t)NN * EMB;        // 5*32768 f16
  _Float16* W2f = W1f + 5 * 32768;              // 5*32768 f16
  int* deg = (int*)(W2f + 5 * 32768);           // NN
  int* off = deg + NN;                          // NN+1
  int* csr = off + NN + 1;                      // NE
  int* bsum = csr + NE;                         // 128

  const int NB_SCAN = (NN + 1023) / 1024;

  // one-time per launch: CSR + combo tables + frag-ordered f16 weights
  hipMemsetAsync(deg, 0, NN * sizeof(int), stream);
  hipMemsetAsync(slots, 0, 5 * 32 * 256 * sizeof(float), stream);
  hist_kernel<<<(NE + 255) / 256, 256, 0, stream>>>(ei, deg);
  scan1_kernel<<<NB_SCAN, 256, 0, stream>>>(deg, off, bsum);
  scan2_kernel<<<1, 64, 0, stream>>>(bsum, off, NB_SCAN);
  scan3_kernel<<<(NN + 255) / 256, 256, 0, stream>>>(off, bsum);
  hipMemsetAsync(deg, 0, NN * sizeof(int), stream);
  scatter_kernel<<<(NE + 255) / 256, 256, 0, stream>>>(ei, ea, off, deg, csr);
  combo_kernel<<<(5 * 15 * 128 + 255) / 256, 256, 0, stream>>>(ee1, ee2, combos);
  prep_w_kernel<<<160, 256, 0, stream>>>(W1, W2, W1f, W2f);
  node_init_kernel<<<NN * 16 / 256 + 1, 256, 0, stream>>>(x, x_emb1, x_emb2, hb);

  const int NBLK = NPAD / 64;  // 1564 blocks x 4 waves (16 nodes each)
  for (int i = 0; i < 5; ++i) {
    if (i == 0)
      agg_kernel<false><<<NPAD * 16 / 256, 256, 0, stream>>>(
          hb, nullptr, off, csr, combos + (size_t)i * 15 * EMB, eps + i, Af);
    else
      agg_kernel<true><<<NPAD * 16 / 256, 256, 0, stream>>>(
          hpre, scsh + (size_t)(i - 1) * 256, off, csr,
          combos + (size_t)i * 15 * EMB, eps + i, Af);
    mlp_kernel<<<NBLK, 256, 0, stream>>>(
        Af, W1f + (size_t)i * 32768, W2f + (size_t)i * 32768,
        b1 + (size_t)i * 256, b2 + (size_t)i * 128, hpre,
        slots + (size_t)i * 32 * 256);
    stats_kernel<<<1, 128, 0, stream>>>(slots + (size_t)i * 32 * 256,
                                        gamma + (size_t)i * EMB,
                                        beta + (size_t)i * EMB,
                                        scsh + (size_t)i * 256);
  }
  out_kernel<<<NN * 16 / 256 + 1, 256, 0, stream>>>(hpre, scsh + 4 * 256, out);
}